// Round 4
// baseline (719.128 us; speedup 1.0000x reference)
//
#include <hip/hip_runtime.h>

// ---------------------------------------------------------------------------
// GraphMambaConv: N=32768 nodes, C=128, G=64 graphs x L=512, E=524288 edges,
// D_INNER=256, D_STATE=16, DT_RANK=8, D_CONV=4.  All fp32.
//
// Round 4: k_scan was issue/latency-bound at 1 wave/SIMD (740 cyc/step,
// VALUBusy 24%). Remap to 1 state/lane: 1024 blocks x 256 thr = 4 waves/SIMD
// (full 262144 lane-state parallelism), h fits in 1 VGPR, y-reduce = 4-shfl
// tree over 16 state lanes. Same chunked LDS double-buffer pipeline.
// ---------------------------------------------------------------------------

#define NROWS 32768
#define CDIM  128
#define EDGES 524288
#define GL    512
#define SCH   32          // scan chunk (timesteps)
#define NCH   (GL / SCH)  // 16 chunks

// ------------------------- CSR build: histogram ----------------------------
__global__ __launch_bounds__(256) void k_hist(const int* __restrict__ ei,
                                              int* __restrict__ deg)
{
    const int e = blockIdx.x * 1024 + threadIdx.x * 4;
    const int4 d4 = *(const int4*)&ei[EDGES + e];
    atomicAdd(&deg[d4.x], 1);
    atomicAdd(&deg[d4.y], 1);
    atomicAdd(&deg[d4.z], 1);
    atomicAdd(&deg[d4.w], 1);
}

// ---------------- CSR build: exclusive prefix scan (1 block) ---------------
__global__ __launch_bounds__(1024) void k_scanidx(const int* __restrict__ deg,
                                                  int* __restrict__ base,
                                                  int* __restrict__ cursor)
{
    __shared__ int ps[1024];
    const int tid = threadIdx.x;
    int loc[32];
    int s = 0;
#pragma unroll
    for (int i = 0; i < 32; ++i) { loc[i] = deg[tid * 32 + i]; s += loc[i]; }
    ps[tid] = s;
    __syncthreads();
    for (int off = 1; off < 1024; off <<= 1) {
        int v = (tid >= off) ? ps[tid - off] : 0;
        __syncthreads();
        ps[tid] += v;
        __syncthreads();
    }
    int run = tid ? ps[tid - 1] : 0;
#pragma unroll
    for (int i = 0; i < 32; ++i) {
        base[tid * 32 + i] = run;
        cursor[tid * 32 + i] = run;
        run += loc[i];
    }
    if (tid == 0) base[32768] = EDGES;
}

// ------------------------- CSR build: fill src lists -----------------------
__global__ __launch_bounds__(256) void k_fill(const int* __restrict__ ei,
                                              int* __restrict__ cursor,
                                              int* __restrict__ srcs)
{
    const int e = blockIdx.x * 1024 + threadIdx.x * 4;
    const int4 s4 = *(const int4*)&ei[e];
    const int4 d4 = *(const int4*)&ei[EDGES + e];
    int p;
    p = atomicAdd(&cursor[d4.x], 1); srcs[p] = s4.x;
    p = atomicAdd(&cursor[d4.y], 1); srcs[p] = s4.y;
    p = atomicAdd(&cursor[d4.z], 1); srcs[p] = s4.z;
    p = atomicAdd(&cursor[d4.w], 1); srcs[p] = s4.w;
}

// ------------------------- gather: one wave per node ------------------------
__global__ __launch_bounds__(256) void k_gather(const float* __restrict__ x,
                                                const int* __restrict__ base,
                                                const int* __restrict__ srcs,
                                                float* __restrict__ agg)
{
    const int node = blockIdx.x * 4 + (threadIdx.x >> 6);
    const int lane = threadIdx.x & 63;
    const int b0 = base[node], b1 = base[node + 1];
    float2 a0 = make_float2(0.f, 0.f), a1 = make_float2(0.f, 0.f);
    int i = b0;
    for (; i + 2 <= b1; i += 2) {
        const int s0 = srcs[i], s1 = srcs[i + 1];
        const float2 v0 = *(const float2*)&x[(size_t)s0 * 128 + lane * 2];
        const float2 v1 = *(const float2*)&x[(size_t)s1 * 128 + lane * 2];
        a0.x += v0.x; a0.y += v0.y;
        a1.x += v1.x; a1.y += v1.y;
    }
    if (i < b1) {
        const int s0 = srcs[i];
        const float2 v0 = *(const float2*)&x[(size_t)s0 * 128 + lane * 2];
        a0.x += v0.x; a0.y += v0.y;
    }
    a0.x += a1.x; a0.y += a1.y;
    *(float2*)&agg[(size_t)node * 128 + lane * 2] = a0;
}

// ------------------------------ GEMM core ---------------------------------
// out = epi( A0@W0 [+ A1@W1] [+bias] [+resid] ), optional column stats.
// A is MxK row-major (lda=K), W is KxN row-major (ldw), tile 64x64, 4x4/thread.
#define TM 64
#define TN 64
#define KB 32

template<bool DUAL, int ACT, bool STAT>
__global__ __launch_bounds__(256)
void gemm_k(const float* __restrict__ A0, const float* __restrict__ W0,
            const float* __restrict__ A1p, const float* __restrict__ W1p,
            int M, int N, int K, int ldw, int ldo,
            const float* __restrict__ bias,
            const float* __restrict__ resid, int ldr,
            float* __restrict__ outp,
            float* __restrict__ sumP, float* __restrict__ sqP)
{
    __shared__ __align__(16) float As[KB][TM];
    __shared__ __align__(16) float Bs[KB][TN];
    __shared__ float sB[2][TN];

    const int m0 = blockIdx.x * TM;
    const int n0 = blockIdx.y * TN;
    const int tid = threadIdx.x;
    const int tx = tid & 15;         // -> 4 cols
    const int ty = tid >> 4;         // -> 4 rows

    float acc[4][4];
#pragma unroll
    for (int i = 0; i < 4; ++i)
#pragma unroll
        for (int j = 0; j < 4; ++j) acc[i][j] = 0.f;

    const int npass = DUAL ? 2 : 1;
    for (int pass = 0; pass < npass; ++pass) {
        const float* A = (DUAL && pass) ? A1p : A0;
        const float* W = (DUAL && pass) ? W1p : W0;
        for (int k0 = 0; k0 < K; k0 += KB) {
            {   // A tile: rows m0..+64, cols k0..+32 ; store transposed
                int m = tid & 63, kg = tid >> 6;
                const float* src = A + (size_t)(m0 + m) * K + k0 + kg * 8;
                float4 v0 = *(const float4*)(src);
                float4 v1 = *(const float4*)(src + 4);
                int kb = kg * 8;
                As[kb + 0][m] = v0.x; As[kb + 1][m] = v0.y;
                As[kb + 2][m] = v0.z; As[kb + 3][m] = v0.w;
                As[kb + 4][m] = v1.x; As[kb + 5][m] = v1.y;
                As[kb + 6][m] = v1.z; As[kb + 7][m] = v1.w;
            }
            {   // W tile: rows k0..+32, cols n0..+64 (zero-pad n>=N)
                int n = tid & 63, kg = tid >> 6;
                int nn = n0 + n;
#pragma unroll
                for (int j = 0; j < 8; ++j) {
                    int k = k0 + kg * 8 + j;
                    Bs[kg * 8 + j][n] = (nn < N) ? W[(size_t)k * ldw + nn] : 0.f;
                }
            }
            __syncthreads();
#pragma unroll
            for (int kb = 0; kb < KB; ++kb) {
                const float4 av = *(const float4*)&As[kb][ty * 4];
                const float4 bv = *(const float4*)&Bs[kb][tx * 4];
                const float aa[4] = {av.x, av.y, av.z, av.w};
                const float bb[4] = {bv.x, bv.y, bv.z, bv.w};
#pragma unroll
                for (int i = 0; i < 4; ++i)
#pragma unroll
                    for (int j = 0; j < 4; ++j) acc[i][j] += aa[i] * bb[j];
            }
            __syncthreads();
        }
    }

    // ------------------------------ epilogue ------------------------------
    const int r0 = m0 + ty * 4;
    const int c0 = n0 + tx * 4;
    const bool cok = (c0 + 4 <= N);
    float cs[4] = {0.f, 0.f, 0.f, 0.f}, cq[4] = {0.f, 0.f, 0.f, 0.f};
    if (cok) {
        float bv[4] = {0.f, 0.f, 0.f, 0.f};
        if (bias) { float4 t = *(const float4*)&bias[c0];
                    bv[0] = t.x; bv[1] = t.y; bv[2] = t.z; bv[3] = t.w; }
#pragma unroll
        for (int i = 0; i < 4; ++i) {
            float v[4];
#pragma unroll
            for (int j = 0; j < 4; ++j) v[j] = acc[i][j] + bv[j];
            if (resid) {
                float4 rv = *(const float4*)&resid[(size_t)(r0 + i) * ldr + c0];
                v[0] += rv.x; v[1] += rv.y; v[2] += rv.z; v[3] += rv.w;
            }
            if (ACT == 1) {   // exact GELU
#pragma unroll
                for (int j = 0; j < 4; ++j)
                    v[j] = 0.5f * v[j] * (1.f + erff(v[j] * 0.7071067811865475f));
            }
            *(float4*)&outp[(size_t)(r0 + i) * ldo + c0] =
                make_float4(v[0], v[1], v[2], v[3]);
            if (STAT) {
#pragma unroll
                for (int j = 0; j < 4; ++j) { cs[j] += v[j]; cq[j] += v[j] * v[j]; }
            }
        }
    }
    if (STAT) {
        if (tid < TN) { sB[0][tid] = 0.f; sB[1][tid] = 0.f; }
        __syncthreads();
        if (cok) {
#pragma unroll
            for (int j = 0; j < 4; ++j) {
                atomicAdd(&sB[0][tx * 4 + j], cs[j]);
                atomicAdd(&sB[1][tx * 4 + j], cq[j]);
            }
        }
        __syncthreads();
        if (tid < TN && (n0 + tid) < N) {
            atomicAdd(&sumP[n0 + tid], sB[0][tid]);
            atomicAdd(&sqP[n0 + tid],  sB[1][tid]);
        }
    }
}

// --------------------------- causal conv + SiLU ----------------------------
__global__ __launch_bounds__(256) void k_conv(const float* __restrict__ xz,
                                              const float* __restrict__ cw,
                                              const float* __restrict__ cb,
                                              float* __restrict__ xc)
{
    const int r = blockIdx.x;        // global row
    const int l = r & (GL - 1);      // position within graph
    const int d = threadIdx.x;       // 0..255
    float4 w4 = *(const float4*)&cw[d * 4];
    const float taps[4] = {w4.x, w4.y, w4.z, w4.w};
    float acc = cb[d];
#pragma unroll
    for (int k = 0; k < 4; ++k) {
        int ll = l - 3 + k;
        if (ll >= 0) acc += xz[(size_t)(r - 3 + k) * 512 + d] * taps[k];
    }
    float s = 1.f / (1.f + __expf(-acc));
    xc[(size_t)r * 256 + d] = acc * s;
}

// ---------------- dt = softplus(proj[:,:8] @ dt_W + dt_b); B,C slices ------
__global__ __launch_bounds__(256) void k_dtbc(const float* __restrict__ proj,
                                              const float* __restrict__ dt_W,
                                              const float* __restrict__ dt_b,
                                              float* __restrict__ dtb,
                                              float* __restrict__ Bc,
                                              float* __restrict__ Cc)
{
    __shared__ float dtWS[8 * 256];
    __shared__ float dt_bS[256];
    __shared__ float projS[32 * 8];
    const int tid = threadIdx.x;
    const int r0 = blockIdx.x * 32;
    for (int i = tid; i < 2048; i += 256) dtWS[i] = dt_W[i];
    dt_bS[tid] = dt_b[tid];
    projS[tid] = proj[(size_t)(r0 + (tid >> 3)) * 40 + (tid & 7)];
    __syncthreads();

    const int c = tid;
    for (int rr = 0; rr < 32; ++rr) {
        float acc = dt_bS[c];
        const float* pr = &projS[rr * 8];
#pragma unroll
        for (int q = 0; q < 8; ++q) acc += pr[q] * dtWS[q * 256 + c];
        float sp = fmaxf(acc, 0.f) + log1pf(__expf(-fabsf(acc)));
        dtb[(size_t)(r0 + rr) * 256 + c] = sp;
    }
    // B = proj[:, 8:24], C = proj[:, 24:40]
    for (int e = tid; e < 1024; e += 256) {
        int rr = e >> 5, cc = e & 31;
        float v = proj[(size_t)(r0 + rr) * 40 + 8 + cc];
        if (cc < 16) Bc[(size_t)(r0 + rr) * 16 + cc] = v;
        else         Cc[(size_t)(r0 + rr) * 16 + cc - 16] = v;
    }
}

// ------------------------------ selective scan -----------------------------
// 1 state per lane. Block = (g, dblk16): 16 d-channels x 16 states = 256 thr
// = 4 waves; 1024 blocks -> 4 waves/SIMD (full TLP). Chunked LDS double
// buffer: per 32-step chunk wave0 stages dt, wave1 xc, wave2 z, wave3 B+C
// (register-staged, issued one chunk ahead). y-reduce: shfl_xor tree over the
// 16 state lanes. One __syncthreads per chunk (buf reuse is 2 barriers away).
// NOTE: yg aliases dtb — chunk c+1's dtb rows are loaded to regs before any
// chunk-c yg writes; each block touches only its own (g, d-slice) rows.
__global__ __launch_bounds__(256) void k_scan(const float* __restrict__ dtb,
                                              const float* __restrict__ xcb,
                                              const float* __restrict__ xzb,
                                              const float* __restrict__ Bb,
                                              const float* __restrict__ Cb,
                                              const float* __restrict__ A_log,
                                              const float* __restrict__ Dp,
                                              float* __restrict__ yg)
{
    // per buffer (floats): dt[32][16] @0 | xc @512 | z @1024 | B @1536 | C @2048
    __shared__ __align__(16) float buf[2][SCH * 80];

    const int g    = blockIdx.x >> 4;
    const int dblk = blockIdx.x & 15;
    const int tid  = threadIdx.x;
    const int wave = tid >> 6, lane = tid & 63;
    const int s    = tid & 15;          // state index
    const int dl   = tid >> 4;          // local d (0..15)
    const int d0   = dblk * 16;
    const int d    = d0 + dl;
    const size_t rbase = (size_t)g * GL;

    const float aA  = -__expf(A_log[d * 16 + s]);
    const float Dpd = Dp[d];
    float h = 0.f;

    float4 rg[4];
    const int srow = lane >> 2, sq = lane & 3;   // dt/xc/z staging coords

    // ---- load chunk 0 into registers ----
    {
        const size_t r0 = rbase;
        if (wave == 0) {
            rg[0] = *(const float4*)&dtb[(r0 + srow) * 256 + d0 + sq * 4];
            rg[1] = *(const float4*)&dtb[(r0 + 16 + srow) * 256 + d0 + sq * 4];
        } else if (wave == 1) {
            rg[0] = *(const float4*)&xcb[(r0 + srow) * 256 + d0 + sq * 4];
            rg[1] = *(const float4*)&xcb[(r0 + 16 + srow) * 256 + d0 + sq * 4];
        } else if (wave == 2) {
            rg[0] = *(const float4*)&xzb[(r0 + srow) * 512 + 256 + d0 + sq * 4];
            rg[1] = *(const float4*)&xzb[(r0 + 16 + srow) * 512 + 256 + d0 + sq * 4];
        } else {
            rg[0] = *(const float4*)&Bb[r0 * 16 + lane * 4];
            rg[1] = *(const float4*)&Bb[r0 * 16 + 256 + lane * 4];
            rg[2] = *(const float4*)&Cb[r0 * 16 + lane * 4];
            rg[3] = *(const float4*)&Cb[r0 * 16 + 256 + lane * 4];
        }
    }

    for (int c = 0; c < NCH; ++c) {
        float* bufc = buf[c & 1];
        // ---- commit staged registers to LDS ----
        if (wave == 0) {
            *(float4*)&bufc[lane * 4]       = rg[0];
            *(float4*)&bufc[256 + lane * 4] = rg[1];
        } else if (wave == 1) {
            *(float4*)&bufc[512 + lane * 4] = rg[0];
            *(float4*)&bufc[768 + lane * 4] = rg[1];
        } else if (wave == 2) {
            *(float4*)&bufc[1024 + lane * 4] = rg[0];
            *(float4*)&bufc[1280 + lane * 4] = rg[1];
        } else {
            *(float4*)&bufc[1536 + lane * 4] = rg[0];
            *(float4*)&bufc[1792 + lane * 4] = rg[1];
            *(float4*)&bufc[2048 + lane * 4] = rg[2];
            *(float4*)&bufc[2304 + lane * 4] = rg[3];
        }
        __syncthreads();

        // ---- issue next chunk's loads (consumed after 32 steps) ----
        if (c + 1 < NCH) {
            const size_t r0 = rbase + (size_t)(c + 1) * SCH;
            if (wave == 0) {
                rg[0] = *(const float4*)&dtb[(r0 + srow) * 256 + d0 + sq * 4];
                rg[1] = *(const float4*)&dtb[(r0 + 16 + srow) * 256 + d0 + sq * 4];
            } else if (wave == 1) {
                rg[0] = *(const float4*)&xcb[(r0 + srow) * 256 + d0 + sq * 4];
                rg[1] = *(const float4*)&xcb[(r0 + 16 + srow) * 256 + d0 + sq * 4];
            } else if (wave == 2) {
                rg[0] = *(const float4*)&xzb[(r0 + srow) * 512 + 256 + d0 + sq * 4];
                rg[1] = *(const float4*)&xzb[(r0 + 16 + srow) * 512 + 256 + d0 + sq * 4];
            } else {
                rg[0] = *(const float4*)&Bb[r0 * 16 + lane * 4];
                rg[1] = *(const float4*)&Bb[r0 * 16 + 256 + lane * 4];
                rg[2] = *(const float4*)&Cb[r0 * 16 + lane * 4];
                rg[3] = *(const float4*)&Cb[r0 * 16 + 256 + lane * 4];
            }
        }

        // ---- 32 scan steps from LDS ----
        const float* pdt = bufc;
        const float* pxc = bufc + 512;
        const float* pz  = bufc + 1024;
        const float* pB  = bufc + 1536;
        const float* pC  = bufc + 2048;
        const size_t rr0 = rbase + (size_t)c * SCH;
#pragma unroll 8
        for (int t = 0; t < SCH; ++t) {
            const float dt = pdt[t * 16 + dl];
            const float xc = pxc[t * 16 + dl];
            const float Bv = pB[t * 16 + s];
            const float Cv = pC[t * 16 + s];
            h = h * __expf(dt * aA) + dt * xc * Bv;
            float y = h * Cv;
            y += __shfl_xor(y, 1);
            y += __shfl_xor(y, 2);
            y += __shfl_xor(y, 4);
            y += __shfl_xor(y, 8);
            if (s == 0) {
                const float z = pz[t * 16 + dl];
                const float sz = z / (1.f + __expf(-z));
                yg[(rr0 + t) * 256 + d] = (y + xc * Dpd) * sz;
            }
        }
        // no trailing barrier needed: buf[c&1] is rewritten only at chunk c+2,
        // whose ds_writes are preceded by chunk c+1's barrier.
    }
}

// -------------------------- BN finalize / fold / add -----------------------
__global__ __launch_bounds__(256) void k_fin12(const float* __restrict__ st,
                                               const float* g1, const float* be1,
                                               const float* g2, const float* be2,
                                               float* __restrict__ ab)
{
    const int tid = threadIdx.x;
    const float inv = 1.f / 32768.f;
    if (tid < 128) {
        float m = st[tid] * inv, v = st[128 + tid] * inv - m * m;
        float a = g1[tid] * rsqrtf(v + 1e-5f);
        ab[tid] = a; ab[256 + tid] = be1[tid] - m * a;
    } else {
        int c = tid - 128;
        float m = st[256 + c] * inv, v = st[384 + c] * inv - m * m;
        float a = g2[c] * rsqrtf(v + 1e-5f);
        ab[512 + c] = a; ab[768 + c] = be2[c] - m * a;
    }
}

__global__ __launch_bounds__(256) void k_add(const float* __restrict__ h1p,
                                             const float* __restrict__ p2,
                                             const float* __restrict__ ab,
                                             float* __restrict__ outp,
                                             float* __restrict__ sumP,
                                             float* __restrict__ sqP)
{
    const int c = threadIdx.x & 127, half = threadIdx.x >> 7;
    const int rbase = blockIdx.x * 64 + half * 32;
    const float a1 = ab[c], b1 = ab[256 + c], a2 = ab[512 + c], b2 = ab[768 + c];
    float s = 0.f, q = 0.f;
    for (int i = 0; i < 32; ++i) {
        size_t idx = (size_t)(rbase + i) * 128 + c;
        float v = h1p[idx] * a1 + b1 + p2[idx] * a2 + b2;
        outp[idx] = v; s += v; q += v * v;
    }
    __shared__ float sh[2][2][128];
    sh[0][half][c] = s; sh[1][half][c] = q;
    __syncthreads();
    if (threadIdx.x < 128) {
        atomicAdd(&sumP[c], sh[0][0][c] + sh[0][1][c]);
        atomicAdd(&sqP[c],  sh[1][0][c] + sh[1][1][c]);
    }
}

__global__ __launch_bounds__(256) void k_fin3_fold1(
    const float* __restrict__ sumP, const float* __restrict__ sqP,
    const float* __restrict__ gam, const float* __restrict__ bet,
    const float* __restrict__ W1, const float* __restrict__ b1in,
    float* __restrict__ W1e, float* __restrict__ b1e)
{
    __shared__ float aS[128], bS[128];
    const int tid = threadIdx.x;
    const float inv = 1.f / 32768.f;
    if (tid < 128) {
        float m = sumP[tid] * inv, v = sqP[tid] * inv - m * m;
        float a = gam[tid] * rsqrtf(v + 1e-5f);
        aS[tid] = a; bS[tid] = bet[tid] - m * a;
    }
    __syncthreads();
    for (int e = tid; e < 128 * 256; e += 256) W1e[e] = aS[e >> 8] * W1[e];
    float acc = b1in[tid];
    for (int k = 0; k < 128; ++k) acc += bS[k] * W1[k * 256 + tid];
    b1e[tid] = acc;
}

__global__ __launch_bounds__(256) void k_fin4_fold2(
    const float* __restrict__ sumP, const float* __restrict__ sqP,
    const float* __restrict__ gam, const float* __restrict__ bet,
    const float* __restrict__ W2, const float* __restrict__ b2in,
    float* __restrict__ W2e, float* __restrict__ b2e)
{
    __shared__ float aS[256], bS[256];
    const int tid = threadIdx.x;
    const float inv = 1.f / 32768.f;
    {
        float m = sumP[tid] * inv, v = sqP[tid] * inv - m * m;
        float a = gam[tid] * rsqrtf(v + 1e-5f);
        aS[tid] = a; bS[tid] = bet[tid] - m * a;
    }
    __syncthreads();
    for (int e = tid; e < 256 * 128; e += 256) W2e[e] = aS[e >> 7] * W2[e];
    if (tid < 128) {
        float acc = b2in[tid];
        for (int k = 0; k < 256; ++k) acc += bS[k] * W2[k * 128 + tid];
        b2e[tid] = acc;
    }
}

__global__ __launch_bounds__(128) void k_fin5(const float* __restrict__ sumP,
                                              const float* __restrict__ sqP,
                                              const float* gam, const float* bet,
                                              float* __restrict__ ab)
{
    const int tid = threadIdx.x;
    if (tid < 128) {
        const float inv = 1.f / 32768.f;
        float m = sumP[tid] * inv, v = sqP[tid] * inv - m * m;
        float a = gam[tid] * rsqrtf(v + 1e-5f);
        ab[2048 + tid] = a; ab[2304 + tid] = bet[tid] - m * a;
    }
}

__global__ __launch_bounds__(256) void k_bn3(const float* __restrict__ out2,
                                             const float* __restrict__ ab,
                                             float* __restrict__ dout)
{
    size_t i4 = ((size_t)blockIdx.x * 256 + threadIdx.x) * 4;
    int c = (int)(i4 & 127);
    float4 v = *(const float4*)&out2[i4];
    float4 a = *(const float4*)&ab[2048 + c];
    float4 b = *(const float4*)&ab[2304 + c];
    v.x = v.x * a.x + b.x; v.y = v.y * a.y + b.y;
    v.z = v.z * a.z + b.z; v.w = v.w * a.w + b.w;
    *(float4*)&dout[i4] = v;
}

// ------------------------------- launch ------------------------------------
extern "C" void kernel_launch(void* const* d_in, const int* in_sizes, int n_in,
                              void* d_out, int out_size, void* d_ws, size_t ws_size,
                              hipStream_t stream)
{
    (void)in_sizes; (void)n_in; (void)out_size; (void)ws_size;
    const float* x      = (const float*)d_in[0];
    const int*   ei     = (const int*)d_in[1];
    // d_in[2] = batch (unused: equal-size sorted graphs == reshape)
    const float* W_root = (const float*)d_in[3];
    const float* W_rel  = (const float*)d_in[4];
    const float* b_rel  = (const float*)d_in[5];
    const float* n1_g = (const float*)d_in[6],  *n1_b = (const float*)d_in[7];
    const float* n2_g = (const float*)d_in[8],  *n2_b = (const float*)d_in[9];
    const float* n3_g = (const float*)d_in[10], *n3_b = (const float*)d_in[11];
    const float* m1_g = (const float*)d_in[12], *m1_b = (const float*)d_in[13];
    const float* W1   = (const float*)d_in[14], *b1   = (const float*)d_in[15];
    const float* m2_g = (const float*)d_in[16], *m2_b = (const float*)d_in[17];
    const float* W2   = (const float*)d_in[18], *b2   = (const float*)d_in[19];
    const float* in_W   = (const float*)d_in[20];
    const float* conv_w = (const float*)d_in[21], *conv_b = (const float*)d_in[22];
    const float* xproj_W= (const float*)d_in[23];
    const float* dt_W   = (const float*)d_in[24], *dt_b = (const float*)d_in[25];
    const float* A_log  = (const float*)d_in[26], *Dp   = (const float*)d_in[27];
    const float* out_W  = (const float*)d_in[28];

    float* ws = (float*)d_ws;
    // small region
    float* st  = ws;             // 2048 used (S1..S5 sums/sumsqs)
    float* ab  = ws + 4096;      // a/b affine params
    float* W1e = ws + 8192;      // 128*256
    float* b1e = W1e + 32768;    // 256
    float* W2e = ws + 41216;     // 256*128
    float* b2e = W2e + 32768;    // 128
    // big buffers (base aligned; ~194 MB total)
    float* big  = ws + 74752;
    float* agg  = big;                    // 4194304 (later reused as p2)
    float* p2   = agg;
    float* h1p  = big + 4194304;          // 4194304
    float* xz   = big + 8388608;          // 16777216 (later: g + out2)
    float* gbuf = xz;
    float* out2 = xz + 8388608;
    float* xc   = big + 25165824;         // 8388608
    float* proj = big + 33554432;         // 1310720
    float* dtb  = big + 34865152;         // 8388608 (yg aliases dtb)
    float* ygb  = dtb;
    float* Bc   = big + 43253760;         // 524288
    float* Cc   = big + 43778048;         // 524288
    float* outb = big + 44302336;         // 4194304

    // CSR scratch lives in the h1p region (dead until the h1 GEMM writes it):
    // gather (last CSR reader) completes before gemm h1 (first h1p writer).
    int* ideg   = (int*)h1p;              // 32768
    int* ibase  = ideg + 32768;           // 32769
    int* icur   = ideg + 65552;           // 32768 (16B-aligned)
    int* isrcs  = ideg + 98320;           // 524288

    hipMemsetAsync(st, 0, 2048 * sizeof(float), stream);
    hipMemsetAsync(ideg, 0, 32768 * sizeof(int), stream);

    // ---- CSR build + gather (replaces atomic scatter) ----
    k_hist<<<512, 256, 0, stream>>>(ei, ideg);
    k_scanidx<<<1, 1024, 0, stream>>>(ideg, ibase, icur);
    k_fill<<<512, 256, 0, stream>>>(ei, icur, isrcs);
    k_gather<<<8192, 256, 0, stream>>>(x, ibase, isrcs, agg);

    // h1_pre = agg@W_rel + b_rel + x@W_root + x  [S1]
    gemm_k<true, 0, true><<<dim3(512, 2), 256, 0, stream>>>(
        agg, W_rel, x, W_root, NROWS, 128, 128, 128, 128,
        b_rel, x, 128, h1p, st + 0, st + 128);
    // xz = x @ in_W
    gemm_k<false, 0, false><<<dim3(512, 8), 256, 0, stream>>>(
        x, in_W, nullptr, nullptr, NROWS, 512, 128, 512, 512,
        nullptr, nullptr, 0, xz, nullptr, nullptr);
    k_conv<<<32768, 256, 0, stream>>>(xz, conv_w, conv_b, xc);
    // proj = xc @ xproj_W (N=40)
    gemm_k<false, 0, false><<<dim3(512, 1), 256, 0, stream>>>(
        xc, xproj_W, nullptr, nullptr, NROWS, 40, 256, 40, 40,
        nullptr, nullptr, 0, proj, nullptr, nullptr);
    k_dtbc<<<1024, 256, 0, stream>>>(proj, dt_W, dt_b, dtb, Bc, Cc);
    k_scan<<<1024, 256, 0, stream>>>(dtb, xc, xz, Bc, Cc, A_log, Dp, ygb);
    // p2 = yg @ out_W + x  [S2]
    gemm_k<false, 0, true><<<dim3(512, 2), 256, 0, stream>>>(
        ygb, out_W, nullptr, nullptr, NROWS, 128, 256, 128, 128,
        nullptr, x, 128, p2, st + 256, st + 384);
    k_fin12<<<1, 256, 0, stream>>>(st, n1_g, n1_b, n2_g, n2_b, ab);
    // out = BN1(h1_pre) + BN2(p2)  [S3]
    k_add<<<512, 256, 0, stream>>>(h1p, p2, ab, outb, st + 512, st + 640);
    k_fin3_fold1<<<1, 256, 0, stream>>>(st + 512, st + 640, m1_g, m1_b, W1, b1, W1e, b1e);
    // g = gelu(out @ W1e + b1e)  [S4]
    gemm_k<false, 1, true><<<dim3(512, 4), 256, 0, stream>>>(
        outb, W1e, nullptr, nullptr, NROWS, 256, 128, 256, 256,
        b1e, nullptr, 0, gbuf, st + 768, st + 1024);
    k_fin4_fold2<<<1, 256, 0, stream>>>(st + 768, st + 1024, m2_g, m2_b, W2, b2, W2e, b2e);
    // out2 = g @ W2e + b2e + out  [S5]
    gemm_k<false, 0, true><<<dim3(512, 2), 256, 0, stream>>>(
        gbuf, W2e, nullptr, nullptr, NROWS, 128, 256, 128, 128,
        b2e, outb, 128, out2, st + 1280, st + 1408);
    k_fin5<<<1, 128, 0, stream>>>(st + 1280, st + 1408, n3_g, n3_b, ab);
    k_bn3<<<4096, 256, 0, stream>>>(out2, ab, (float*)d_out);
}

// Round 5
// 618.450 us; speedup vs baseline: 1.1628x; 1.1628x over previous
//
#include <hip/hip_runtime.h>

// ---------------------------------------------------------------------------
// GraphMambaConv: N=32768 nodes, C=128, G=64 graphs x L=512, E=524288 edges,
// D_INNER=256, D_STATE=16, DT_RANK=8, D_CONV=4.  All fp32.
//
// Round 5: k_scan was LDS-PIPE bound (9 DS ops/wave-step incl. 4 shfl; 880
// cyc/step/CU) + 5.5x partial-line write amplification. New k_scan:
//  - transposed LDS tiles (dtT[d][t] etc, pad 36): ds_read_b128 covers 4
//    steps; 16 state-lanes broadcast-read the same address (free).
//  - 16-lane y-reduction via 4x v_add_f32+DPP (quad_perm/row_mirror) - zero
//    DS-pipe ops.
//  - block = 32d x 16s = 512 thr; y staged in LDS, written out coalesced as
//    full 128B lines; z gating applied at writeout from registers.
// ---------------------------------------------------------------------------

#define NROWS 32768
#define CDIM  128
#define EDGES 524288
#define GL    512
#define SCH   32          // scan chunk (timesteps)
#define NCH   (GL / SCH)  // 16 chunks

// ------------------------- CSR build: histogram ----------------------------
__global__ __launch_bounds__(256) void k_hist(const int* __restrict__ ei,
                                              int* __restrict__ deg)
{
    const int e = blockIdx.x * 1024 + threadIdx.x * 4;
    const int4 d4 = *(const int4*)&ei[EDGES + e];
    atomicAdd(&deg[d4.x], 1);
    atomicAdd(&deg[d4.y], 1);
    atomicAdd(&deg[d4.z], 1);
    atomicAdd(&deg[d4.w], 1);
}

// ---------------- CSR build: exclusive prefix scan (1 block) ---------------
__global__ __launch_bounds__(1024) void k_scanidx(const int* __restrict__ deg,
                                                  int* __restrict__ base,
                                                  int* __restrict__ cursor)
{
    __shared__ int ps[1024];
    const int tid = threadIdx.x;
    int loc[32];
    int s = 0;
#pragma unroll
    for (int i = 0; i < 32; ++i) { loc[i] = deg[tid * 32 + i]; s += loc[i]; }
    ps[tid] = s;
    __syncthreads();
    for (int off = 1; off < 1024; off <<= 1) {
        int v = (tid >= off) ? ps[tid - off] : 0;
        __syncthreads();
        ps[tid] += v;
        __syncthreads();
    }
    int run = tid ? ps[tid - 1] : 0;
#pragma unroll
    for (int i = 0; i < 32; ++i) {
        base[tid * 32 + i] = run;
        cursor[tid * 32 + i] = run;
        run += loc[i];
    }
    if (tid == 0) base[32768] = EDGES;
}

// ------------------------- CSR build: fill src lists -----------------------
__global__ __launch_bounds__(256) void k_fill(const int* __restrict__ ei,
                                              int* __restrict__ cursor,
                                              int* __restrict__ srcs)
{
    const int e = blockIdx.x * 1024 + threadIdx.x * 4;
    const int4 s4 = *(const int4*)&ei[e];
    const int4 d4 = *(const int4*)&ei[EDGES + e];
    int p;
    p = atomicAdd(&cursor[d4.x], 1); srcs[p] = s4.x;
    p = atomicAdd(&cursor[d4.y], 1); srcs[p] = s4.y;
    p = atomicAdd(&cursor[d4.z], 1); srcs[p] = s4.z;
    p = atomicAdd(&cursor[d4.w], 1); srcs[p] = s4.w;
}

// ------------------------- gather: one wave per node ------------------------
__global__ __launch_bounds__(256) void k_gather(const float* __restrict__ x,
                                                const int* __restrict__ base,
                                                const int* __restrict__ srcs,
                                                float* __restrict__ agg)
{
    const int node = blockIdx.x * 4 + (threadIdx.x >> 6);
    const int lane = threadIdx.x & 63;
    const int b0 = base[node], b1 = base[node + 1];
    float2 a0 = make_float2(0.f, 0.f), a1 = make_float2(0.f, 0.f);
    int i = b0;
    for (; i + 2 <= b1; i += 2) {
        const int s0 = srcs[i], s1 = srcs[i + 1];
        const float2 v0 = *(const float2*)&x[(size_t)s0 * 128 + lane * 2];
        const float2 v1 = *(const float2*)&x[(size_t)s1 * 128 + lane * 2];
        a0.x += v0.x; a0.y += v0.y;
        a1.x += v1.x; a1.y += v1.y;
    }
    if (i < b1) {
        const int s0 = srcs[i];
        const float2 v0 = *(const float2*)&x[(size_t)s0 * 128 + lane * 2];
        a0.x += v0.x; a0.y += v0.y;
    }
    a0.x += a1.x; a0.y += a1.y;
    *(float2*)&agg[(size_t)node * 128 + lane * 2] = a0;
}

// ------------------------------ GEMM core ---------------------------------
// out = epi( A0@W0 [+ A1@W1] [+bias] [+resid] ), optional column stats.
// A is MxK row-major (lda=K), W is KxN row-major (ldw), tile 64x64, 4x4/thread.
#define TM 64
#define TN 64
#define KB 32

template<bool DUAL, int ACT, bool STAT>
__global__ __launch_bounds__(256)
void gemm_k(const float* __restrict__ A0, const float* __restrict__ W0,
            const float* __restrict__ A1p, const float* __restrict__ W1p,
            int M, int N, int K, int ldw, int ldo,
            const float* __restrict__ bias,
            const float* __restrict__ resid, int ldr,
            float* __restrict__ outp,
            float* __restrict__ sumP, float* __restrict__ sqP)
{
    __shared__ __align__(16) float As[KB][TM];
    __shared__ __align__(16) float Bs[KB][TN];
    __shared__ float sB[2][TN];

    const int m0 = blockIdx.x * TM;
    const int n0 = blockIdx.y * TN;
    const int tid = threadIdx.x;
    const int tx = tid & 15;         // -> 4 cols
    const int ty = tid >> 4;         // -> 4 rows

    float acc[4][4];
#pragma unroll
    for (int i = 0; i < 4; ++i)
#pragma unroll
        for (int j = 0; j < 4; ++j) acc[i][j] = 0.f;

    const int npass = DUAL ? 2 : 1;
    for (int pass = 0; pass < npass; ++pass) {
        const float* A = (DUAL && pass) ? A1p : A0;
        const float* W = (DUAL && pass) ? W1p : W0;
        for (int k0 = 0; k0 < K; k0 += KB) {
            {   // A tile: rows m0..+64, cols k0..+32 ; store transposed
                int m = tid & 63, kg = tid >> 6;
                const float* src = A + (size_t)(m0 + m) * K + k0 + kg * 8;
                float4 v0 = *(const float4*)(src);
                float4 v1 = *(const float4*)(src + 4);
                int kb = kg * 8;
                As[kb + 0][m] = v0.x; As[kb + 1][m] = v0.y;
                As[kb + 2][m] = v0.z; As[kb + 3][m] = v0.w;
                As[kb + 4][m] = v1.x; As[kb + 5][m] = v1.y;
                As[kb + 6][m] = v1.z; As[kb + 7][m] = v1.w;
            }
            {   // W tile: rows k0..+32, cols n0..+64 (zero-pad n>=N)
                int n = tid & 63, kg = tid >> 6;
                int nn = n0 + n;
#pragma unroll
                for (int j = 0; j < 8; ++j) {
                    int k = k0 + kg * 8 + j;
                    Bs[kg * 8 + j][n] = (nn < N) ? W[(size_t)k * ldw + nn] : 0.f;
                }
            }
            __syncthreads();
#pragma unroll
            for (int kb = 0; kb < KB; ++kb) {
                const float4 av = *(const float4*)&As[kb][ty * 4];
                const float4 bv = *(const float4*)&Bs[kb][tx * 4];
                const float aa[4] = {av.x, av.y, av.z, av.w};
                const float bb[4] = {bv.x, bv.y, bv.z, bv.w};
#pragma unroll
                for (int i = 0; i < 4; ++i)
#pragma unroll
                    for (int j = 0; j < 4; ++j) acc[i][j] += aa[i] * bb[j];
            }
            __syncthreads();
        }
    }

    // ------------------------------ epilogue ------------------------------
    const int r0 = m0 + ty * 4;
    const int c0 = n0 + tx * 4;
    const bool cok = (c0 + 4 <= N);
    float cs[4] = {0.f, 0.f, 0.f, 0.f}, cq[4] = {0.f, 0.f, 0.f, 0.f};
    if (cok) {
        float bv[4] = {0.f, 0.f, 0.f, 0.f};
        if (bias) { float4 t = *(const float4*)&bias[c0];
                    bv[0] = t.x; bv[1] = t.y; bv[2] = t.z; bv[3] = t.w; }
#pragma unroll
        for (int i = 0; i < 4; ++i) {
            float v[4];
#pragma unroll
            for (int j = 0; j < 4; ++j) v[j] = acc[i][j] + bv[j];
            if (resid) {
                float4 rv = *(const float4*)&resid[(size_t)(r0 + i) * ldr + c0];
                v[0] += rv.x; v[1] += rv.y; v[2] += rv.z; v[3] += rv.w;
            }
            if (ACT == 1) {   // exact GELU
#pragma unroll
                for (int j = 0; j < 4; ++j)
                    v[j] = 0.5f * v[j] * (1.f + erff(v[j] * 0.7071067811865475f));
            }
            *(float4*)&outp[(size_t)(r0 + i) * ldo + c0] =
                make_float4(v[0], v[1], v[2], v[3]);
            if (STAT) {
#pragma unroll
                for (int j = 0; j < 4; ++j) { cs[j] += v[j]; cq[j] += v[j] * v[j]; }
            }
        }
    }
    if (STAT) {
        if (tid < TN) { sB[0][tid] = 0.f; sB[1][tid] = 0.f; }
        __syncthreads();
        if (cok) {
#pragma unroll
            for (int j = 0; j < 4; ++j) {
                atomicAdd(&sB[0][tx * 4 + j], cs[j]);
                atomicAdd(&sB[1][tx * 4 + j], cq[j]);
            }
        }
        __syncthreads();
        if (tid < TN && (n0 + tid) < N) {
            atomicAdd(&sumP[n0 + tid], sB[0][tid]);
            atomicAdd(&sqP[n0 + tid],  sB[1][tid]);
        }
    }
}

// --------------------------- causal conv + SiLU ----------------------------
__global__ __launch_bounds__(256) void k_conv(const float* __restrict__ xz,
                                              const float* __restrict__ cw,
                                              const float* __restrict__ cb,
                                              float* __restrict__ xc)
{
    const int r = blockIdx.x;        // global row
    const int l = r & (GL - 1);      // position within graph
    const int d = threadIdx.x;       // 0..255
    float4 w4 = *(const float4*)&cw[d * 4];
    const float taps[4] = {w4.x, w4.y, w4.z, w4.w};
    float acc = cb[d];
#pragma unroll
    for (int k = 0; k < 4; ++k) {
        int ll = l - 3 + k;
        if (ll >= 0) acc += xz[(size_t)(r - 3 + k) * 512 + d] * taps[k];
    }
    float s = 1.f / (1.f + __expf(-acc));
    xc[(size_t)r * 256 + d] = acc * s;
}

// ---------------- dt = softplus(proj[:,:8] @ dt_W + dt_b); B,C slices ------
__global__ __launch_bounds__(256) void k_dtbc(const float* __restrict__ proj,
                                              const float* __restrict__ dt_W,
                                              const float* __restrict__ dt_b,
                                              float* __restrict__ dtb,
                                              float* __restrict__ Bc,
                                              float* __restrict__ Cc)
{
    __shared__ float dtWS[8 * 256];
    __shared__ float dt_bS[256];
    __shared__ float projS[32 * 8];
    const int tid = threadIdx.x;
    const int r0 = blockIdx.x * 32;
    for (int i = tid; i < 2048; i += 256) dtWS[i] = dt_W[i];
    dt_bS[tid] = dt_b[tid];
    projS[tid] = proj[(size_t)(r0 + (tid >> 3)) * 40 + (tid & 7)];
    __syncthreads();

    const int c = tid;
    for (int rr = 0; rr < 32; ++rr) {
        float acc = dt_bS[c];
        const float* pr = &projS[rr * 8];
#pragma unroll
        for (int q = 0; q < 8; ++q) acc += pr[q] * dtWS[q * 256 + c];
        float sp = fmaxf(acc, 0.f) + log1pf(__expf(-fabsf(acc)));
        dtb[(size_t)(r0 + rr) * 256 + c] = sp;
    }
    // B = proj[:, 8:24], C = proj[:, 24:40]
    for (int e = tid; e < 1024; e += 256) {
        int rr = e >> 5, cc = e & 31;
        float v = proj[(size_t)(r0 + rr) * 40 + 8 + cc];
        if (cc < 16) Bc[(size_t)(r0 + rr) * 16 + cc] = v;
        else         Cc[(size_t)(r0 + rr) * 16 + cc - 16] = v;
    }
}

// ---------------- 16-lane-group sum via DPP (zero DS-pipe ops) --------------
__device__ __forceinline__ float dpp_add16(float x)
{
    float y = x;
    int t;
    // quad_perm [1,0,3,2] : xor 1
    t = __builtin_amdgcn_update_dpp(0, __float_as_int(y), 0xB1, 0xF, 0xF, true);
    y += __int_as_float(t);
    // quad_perm [2,3,0,1] : xor 2
    t = __builtin_amdgcn_update_dpp(0, __float_as_int(y), 0x4E, 0xF, 0xF, true);
    y += __int_as_float(t);
    // row_half_mirror : pairs the two quads within each 8-lane half
    t = __builtin_amdgcn_update_dpp(0, __float_as_int(y), 0x141, 0xF, 0xF, true);
    y += __int_as_float(t);
    // row_mirror : pairs the two 8-lane halves within the 16-lane row
    t = __builtin_amdgcn_update_dpp(0, __float_as_int(y), 0x140, 0xF, 0xF, true);
    y += __int_as_float(t);
    return y;
}

// ------------------------------ selective scan -----------------------------
// Block = (g, dblk32): 32 d x 16 s = 512 thr (8 waves); 512 blocks ->
// 16 waves/CU (4/SIMD). Per 32-step chunk (double-buffered LDS, transposed):
//   dtT[32][36] | xcT[32][36] | BT[16][36] | CT[16][36]
// Compute lane (dl=tid>>4, s=tid&15): ds_read_b128 covers 4 steps; the 16
// s-lanes of a d broadcast-read the same dt/xc address (free). y-reduce over
// s = 4x DPP adds (VALU). y staged in ygL, written out coalesced (full 128B
// lines) with silu(z) applied from registers (z prefetched a chunk ahead).
// NOTE: yg aliases dtb - chunk c's dtb rows are consumed (LDS commit) and
// chunk c+1's are prefetched to regs before chunk c's yg writeout of those
// same rows; blocks touch disjoint (g, d-slice) row sets.
__global__ __launch_bounds__(512) void k_scan(const float* __restrict__ dtb,
                                              const float* __restrict__ xcb,
                                              const float* __restrict__ xzb,
                                              const float* __restrict__ Bb,
                                              const float* __restrict__ Cb,
                                              const float* __restrict__ A_log,
                                              const float* __restrict__ Dp,
                                              float* __restrict__ yg)
{
    // words: buf0 [0,3456) | buf1 [3456,6912) | ygL [6912, 6912+32*33)
    __shared__ __align__(16) float lds[2 * 3456 + 32 * 33];

    const int g    = blockIdx.x >> 3;
    const int dblk = blockIdx.x & 7;
    const int tid  = threadIdx.x;
    const int s    = tid & 15;          // state index (compute)
    const int dl   = tid >> 4;          // local d 0..31 (compute)
    const int d0   = dblk * 32;
    const int d    = d0 + dl;
    const size_t rbase = (size_t)g * GL;

    // staging/writeout coords
    const int st_t = tid >> 4;          // 0..31 (timestep within chunk)
    const int st_i = tid & 15;          // 0..15 (pair index / state)

    const float aA  = -__expf(A_log[d * 16 + s]);
    const float Dpd = Dp[d];
    float h = 0.f;

    float2 r_dt, r_xc, z_cur, z_nxt;
    float r_B, r_C;

    // ---- prologue: load chunk 0 into registers ----
    {
        const size_t r0 = rbase;
        r_dt  = *(const float2*)&dtb[(r0 + st_t) * 256 + d0 + st_i * 2];
        r_xc  = *(const float2*)&xcb[(r0 + st_t) * 256 + d0 + st_i * 2];
        z_cur = *(const float2*)&xzb[(r0 + st_t) * 512 + 256 + d0 + st_i * 2];
        r_B   = Bb[(r0 + st_t) * 16 + st_i];
        r_C   = Cb[(r0 + st_t) * 16 + st_i];
    }
    z_nxt = z_cur;

    float* ygL = lds + 2 * 3456;

    for (int c = 0; c < NCH; ++c) {
        float* buf = lds + (c & 1) * 3456;
        // ---- commit staged registers to LDS (transposed) ----
        buf[(st_i * 2    ) * 36 + st_t] = r_dt.x;
        buf[(st_i * 2 + 1) * 36 + st_t] = r_dt.y;
        buf[1152 + (st_i * 2    ) * 36 + st_t] = r_xc.x;
        buf[1152 + (st_i * 2 + 1) * 36 + st_t] = r_xc.y;
        buf[2304 + st_i * 36 + st_t] = r_B;
        buf[2880 + st_i * 36 + st_t] = r_C;
        __syncthreads();

        // ---- prefetch chunk c+1 (lands during the 32 steps below) ----
        if (c + 1 < NCH) {
            const size_t r0 = rbase + (size_t)(c + 1) * SCH;
            r_dt  = *(const float2*)&dtb[(r0 + st_t) * 256 + d0 + st_i * 2];
            r_xc  = *(const float2*)&xcb[(r0 + st_t) * 256 + d0 + st_i * 2];
            z_nxt = *(const float2*)&xzb[(r0 + st_t) * 512 + 256 + d0 + st_i * 2];
            r_B   = Bb[(r0 + st_t) * 16 + st_i];
            r_C   = Cb[(r0 + st_t) * 16 + st_i];
        }

        // ---- 32 scan steps from LDS (b128 = 4 steps per read) ----
        const float* pdt = buf + dl * 36;
        const float* pxc = buf + 1152 + dl * 36;
        const float* pB  = buf + 2304 + s * 36;
        const float* pC  = buf + 2880 + s * 36;
#pragma unroll
        for (int t4 = 0; t4 < 8; ++t4) {
            const float4 dt4 = *(const float4*)&pdt[t4 * 4];
            const float4 xc4 = *(const float4*)&pxc[t4 * 4];
            const float4 B4  = *(const float4*)&pB [t4 * 4];
            const float4 C4  = *(const float4*)&pC [t4 * 4];
#define SSTEP(DT, XC, BV, CV, J)                                          \
            {                                                             \
                h = h * __expf((DT) * aA) + (DT) * (XC) * (BV);           \
                float yv = dpp_add16(h * (CV));                           \
                if (s == 0)                                               \
                    ygL[(t4 * 4 + (J)) * 33 + dl] = yv + (XC) * Dpd;      \
            }
            SSTEP(dt4.x, xc4.x, B4.x, C4.x, 0)
            SSTEP(dt4.y, xc4.y, B4.y, C4.y, 1)
            SSTEP(dt4.z, xc4.z, B4.z, C4.z, 2)
            SSTEP(dt4.w, xc4.w, B4.w, C4.w, 3)
#undef SSTEP
        }
        __syncthreads();

        // ---- coalesced writeout with silu(z) from registers ----
        {
            const size_t rr0 = rbase + (size_t)c * SCH;
            const float y0 = ygL[st_t * 33 + st_i * 2];
            const float y1 = ygL[st_t * 33 + st_i * 2 + 1];
            const float s0 = z_cur.x / (1.f + __expf(-z_cur.x));
            const float s1 = z_cur.y / (1.f + __expf(-z_cur.y));
            *(float2*)&yg[(rr0 + st_t) * 256 + d0 + st_i * 2] =
                make_float2(y0 * s0, y1 * s1);
        }
        z_cur = z_nxt;
    }
}

// -------------------------- BN finalize / fold / add -----------------------
__global__ __launch_bounds__(256) void k_fin12(const float* __restrict__ st,
                                               const float* g1, const float* be1,
                                               const float* g2, const float* be2,
                                               float* __restrict__ ab)
{
    const int tid = threadIdx.x;
    const float inv = 1.f / 32768.f;
    if (tid < 128) {
        float m = st[tid] * inv, v = st[128 + tid] * inv - m * m;
        float a = g1[tid] * rsqrtf(v + 1e-5f);
        ab[tid] = a; ab[256 + tid] = be1[tid] - m * a;
    } else {
        int c = tid - 128;
        float m = st[256 + c] * inv, v = st[384 + c] * inv - m * m;
        float a = g2[c] * rsqrtf(v + 1e-5f);
        ab[512 + c] = a; ab[768 + c] = be2[c] - m * a;
    }
}

__global__ __launch_bounds__(256) void k_add(const float* __restrict__ h1p,
                                             const float* __restrict__ p2,
                                             const float* __restrict__ ab,
                                             float* __restrict__ outp,
                                             float* __restrict__ sumP,
                                             float* __restrict__ sqP)
{
    const int c = threadIdx.x & 127, half = threadIdx.x >> 7;
    const int rbase = blockIdx.x * 64 + half * 32;
    const float a1 = ab[c], b1 = ab[256 + c], a2 = ab[512 + c], b2 = ab[768 + c];
    float s = 0.f, q = 0.f;
    for (int i = 0; i < 32; ++i) {
        size_t idx = (size_t)(rbase + i) * 128 + c;
        float v = h1p[idx] * a1 + b1 + p2[idx] * a2 + b2;
        outp[idx] = v; s += v; q += v * v;
    }
    __shared__ float sh[2][2][128];
    sh[0][half][c] = s; sh[1][half][c] = q;
    __syncthreads();
    if (threadIdx.x < 128) {
        atomicAdd(&sumP[c], sh[0][0][c] + sh[0][1][c]);
        atomicAdd(&sqP[c],  sh[1][0][c] + sh[1][1][c]);
    }
}

__global__ __launch_bounds__(256) void k_fin3_fold1(
    const float* __restrict__ sumP, const float* __restrict__ sqP,
    const float* __restrict__ gam, const float* __restrict__ bet,
    const float* __restrict__ W1, const float* __restrict__ b1in,
    float* __restrict__ W1e, float* __restrict__ b1e)
{
    __shared__ float aS[128], bS[128];
    const int tid = threadIdx.x;
    const float inv = 1.f / 32768.f;
    if (tid < 128) {
        float m = sumP[tid] * inv, v = sqP[tid] * inv - m * m;
        float a = gam[tid] * rsqrtf(v + 1e-5f);
        aS[tid] = a; bS[tid] = bet[tid] - m * a;
    }
    __syncthreads();
    for (int e = tid; e < 128 * 256; e += 256) W1e[e] = aS[e >> 8] * W1[e];
    float acc = b1in[tid];
    for (int k = 0; k < 128; ++k) acc += bS[k] * W1[k * 256 + tid];
    b1e[tid] = acc;
}

__global__ __launch_bounds__(256) void k_fin4_fold2(
    const float* __restrict__ sumP, const float* __restrict__ sqP,
    const float* __restrict__ gam, const float* __restrict__ bet,
    const float* __restrict__ W2, const float* __restrict__ b2in,
    float* __restrict__ W2e, float* __restrict__ b2e)
{
    __shared__ float aS[256], bS[256];
    const int tid = threadIdx.x;
    const float inv = 1.f / 32768.f;
    {
        float m = sumP[tid] * inv, v = sqP[tid] * inv - m * m;
        float a = gam[tid] * rsqrtf(v + 1e-5f);
        aS[tid] = a; bS[tid] = bet[tid] - m * a;
    }
    __syncthreads();
    for (int e = tid; e < 256 * 128; e += 256) W2e[e] = aS[e >> 7] * W2[e];
    if (tid < 128) {
        float acc = b2in[tid];
        for (int k = 0; k < 256; ++k) acc += bS[k] * W2[k * 128 + tid];
        b2e[tid] = acc;
    }
}

__global__ __launch_bounds__(128) void k_fin5(const float* __restrict__ sumP,
                                              const float* __restrict__ sqP,
                                              const float* gam, const float* bet,
                                              float* __restrict__ ab)
{
    const int tid = threadIdx.x;
    if (tid < 128) {
        const float inv = 1.f / 32768.f;
        float m = sumP[tid] * inv, v = sqP[tid] * inv - m * m;
        float a = gam[tid] * rsqrtf(v + 1e-5f);
        ab[2048 + tid] = a; ab[2304 + tid] = bet[tid] - m * a;
    }
}

__global__ __launch_bounds__(256) void k_bn3(const float* __restrict__ out2,
                                             const float* __restrict__ ab,
                                             float* __restrict__ dout)
{
    size_t i4 = ((size_t)blockIdx.x * 256 + threadIdx.x) * 4;
    int c = (int)(i4 & 127);
    float4 v = *(const float4*)&out2[i4];
    float4 a = *(const float4*)&ab[2048 + c];
    float4 b = *(const float4*)&ab[2304 + c];
    v.x = v.x * a.x + b.x; v.y = v.y * a.y + b.y;
    v.z = v.z * a.z + b.z; v.w = v.w * a.w + b.w;
    *(float4*)&dout[i4] = v;
}

// ------------------------------- launch ------------------------------------
extern "C" void kernel_launch(void* const* d_in, const int* in_sizes, int n_in,
                              void* d_out, int out_size, void* d_ws, size_t ws_size,
                              hipStream_t stream)
{
    (void)in_sizes; (void)n_in; (void)out_size; (void)ws_size;
    const float* x      = (const float*)d_in[0];
    const int*   ei     = (const int*)d_in[1];
    // d_in[2] = batch (unused: equal-size sorted graphs == reshape)
    const float* W_root = (const float*)d_in[3];
    const float* W_rel  = (const float*)d_in[4];
    const float* b_rel  = (const float*)d_in[5];
    const float* n1_g = (const float*)d_in[6],  *n1_b = (const float*)d_in[7];
    const float* n2_g = (const float*)d_in[8],  *n2_b = (const float*)d_in[9];
    const float* n3_g = (const float*)d_in[10], *n3_b = (const float*)d_in[11];
    const float* m1_g = (const float*)d_in[12], *m1_b = (const float*)d_in[13];
    const float* W1   = (const float*)d_in[14], *b1   = (const float*)d_in[15];
    const float* m2_g = (const float*)d_in[16], *m2_b = (const float*)d_in[17];
    const float* W2   = (const float*)d_in[18], *b2   = (const float*)d_in[19];
    const float* in_W   = (const float*)d_in[20];
    const float* conv_w = (const float*)d_in[21], *conv_b = (const float*)d_in[22];
    const float* xproj_W= (const float*)d_in[23];
    const float* dt_W   = (const float*)d_in[24], *dt_b = (const float*)d_in[25];
    const float* A_log  = (const float*)d_in[26], *Dp   = (const float*)d_in[27];
    const float* out_W  = (const float*)d_in[28];

    float* ws = (float*)d_ws;
    // small region
    float* st  = ws;             // 2048 used (S1..S5 sums/sumsqs)
    float* ab  = ws + 4096;      // a/b affine params
    float* W1e = ws + 8192;      // 128*256
    float* b1e = W1e + 32768;    // 256
    float* W2e = ws + 41216;     // 256*128
    float* b2e = W2e + 32768;    // 128
    // big buffers (base aligned; ~194 MB total)
    float* big  = ws + 74752;
    float* agg  = big;                    // 4194304 (later reused as p2)
    float* p2   = agg;
    float* h1p  = big + 4194304;          // 4194304
    float* xz   = big + 8388608;          // 16777216 (later: g + out2)
    float* gbuf = xz;
    float* out2 = xz + 8388608;
    float* xc   = big + 25165824;         // 8388608
    float* proj = big + 33554432;         // 1310720
    float* dtb  = big + 34865152;         // 8388608 (yg aliases dtb)
    float* ygb  = dtb;
    float* Bc   = big + 43253760;         // 524288
    float* Cc   = big + 43778048;         // 524288
    float* outb = big + 44302336;         // 4194304

    // CSR scratch lives in the h1p region (dead until the h1 GEMM writes it):
    // gather (last CSR reader) completes before gemm h1 (first h1p writer).
    int* ideg   = (int*)h1p;              // 32768
    int* ibase  = ideg + 32768;           // 32769
    int* icur   = ideg + 65552;           // 32768 (16B-aligned)
    int* isrcs  = ideg + 98320;           // 524288

    hipMemsetAsync(st, 0, 2048 * sizeof(float), stream);
    hipMemsetAsync(ideg, 0, 32768 * sizeof(int), stream);

    // ---- CSR build + gather (replaces atomic scatter) ----
    k_hist<<<512, 256, 0, stream>>>(ei, ideg);
    k_scanidx<<<1, 1024, 0, stream>>>(ideg, ibase, icur);
    k_fill<<<512, 256, 0, stream>>>(ei, icur, isrcs);
    k_gather<<<8192, 256, 0, stream>>>(x, ibase, isrcs, agg);

    // h1_pre = agg@W_rel + b_rel + x@W_root + x  [S1]
    gemm_k<true, 0, true><<<dim3(512, 2), 256, 0, stream>>>(
        agg, W_rel, x, W_root, NROWS, 128, 128, 128, 128,
        b_rel, x, 128, h1p, st + 0, st + 128);
    // xz = x @ in_W
    gemm_k<false, 0, false><<<dim3(512, 8), 256, 0, stream>>>(
        x, in_W, nullptr, nullptr, NROWS, 512, 128, 512, 512,
        nullptr, nullptr, 0, xz, nullptr, nullptr);
    k_conv<<<32768, 256, 0, stream>>>(xz, conv_w, conv_b, xc);
    // proj = xc @ xproj_W (N=40)
    gemm_k<false, 0, false><<<dim3(512, 1), 256, 0, stream>>>(
        xc, xproj_W, nullptr, nullptr, NROWS, 40, 256, 40, 40,
        nullptr, nullptr, 0, proj, nullptr, nullptr);
    k_dtbc<<<1024, 256, 0, stream>>>(proj, dt_W, dt_b, dtb, Bc, Cc);
    k_scan<<<512, 512, 0, stream>>>(dtb, xc, xz, Bc, Cc, A_log, Dp, ygb);
    // p2 = yg @ out_W + x  [S2]
    gemm_k<false, 0, true><<<dim3(512, 2), 256, 0, stream>>>(
        ygb, out_W, nullptr, nullptr, NROWS, 128, 256, 128, 128,
        nullptr, x, 128, p2, st + 256, st + 384);
    k_fin12<<<1, 256, 0, stream>>>(st, n1_g, n1_b, n2_g, n2_b, ab);
    // out = BN1(h1_pre) + BN2(p2)  [S3]
    k_add<<<512, 256, 0, stream>>>(h1p, p2, ab, outb, st + 512, st + 640);
    k_fin3_fold1<<<1, 256, 0, stream>>>(st + 512, st + 640, m1_g, m1_b, W1, b1, W1e, b1e);
    // g = gelu(out @ W1e + b1e)  [S4]
    gemm_k<false, 1, true><<<dim3(512, 4), 256, 0, stream>>>(
        outb, W1e, nullptr, nullptr, NROWS, 256, 128, 256, 256,
        b1e, nullptr, 0, gbuf, st + 768, st + 1024);
    k_fin4_fold2<<<1, 256, 0, stream>>>(st + 768, st + 1024, m2_g, m2_b, W2, b2, W2e, b2e);
    // out2 = g @ W2e + b2e + out  [S5]
    gemm_k<false, 0, true><<<dim3(512, 2), 256, 0, stream>>>(
        gbuf, W2e, nullptr, nullptr, NROWS, 128, 256, 128, 128,
        b2e, outb, 128, out2, st + 1280, st + 1408);
    k_fin5<<<1, 128, 0, stream>>>(st + 1280, st + 1408, n3_g, n3_b, ab);
    k_bn3<<<4096, 256, 0, stream>>>(out2, ab, (float*)d_out);
}

// Round 6
// 481.071 us; speedup vs baseline: 1.4948x; 1.2856x over previous
//
#include <hip/hip_runtime.h>

// ---------------------------------------------------------------------------
// GraphMambaConv: N=32768 nodes, C=128, G=64 graphs x L=512, E=524288 edges,
// D_INNER=256, D_STATE=16, DT_RANK=8, D_CONV=4.
//
// Round 6: all six GEMMs -> bf16 MFMA (16x16x32, fp32 accumulate).
//  - weights pre-transposed to bf16 WT[n][k] (tiny prep kernels; BN-fold
//    kernels emit W1eT/W2eT bf16 directly)
//  - A staged fp32->bf16 in-register during LDS staging (no extra passes)
//  - As[m][k] / Bs[n][k] both k-contiguous (+8 pad): identical lane->k
//    addressing on both operands makes the internal k-permutation cancel;
//    C/D layout is the HW-verified col=lane&15, row=(lane>>4)*4+reg.
// Scan/conv/dtbc/add/bn stay fp32.
// ---------------------------------------------------------------------------

#define NROWS 32768
#define CDIM  128
#define EDGES 524288
#define GL    512
#define SCH   32          // scan chunk (timesteps)
#define NCH   (GL / SCH)  // 16 chunks

typedef short s16x8 __attribute__((ext_vector_type(8)));
typedef float f32x4 __attribute__((ext_vector_type(4)));

__device__ __forceinline__ unsigned short f2bf(float f)
{
    unsigned u = __float_as_uint(f);
    u += 0x7FFF + ((u >> 16) & 1);          // RNE
    return (unsigned short)(u >> 16);
}

// ------------------------- CSR build: histogram ----------------------------
__global__ __launch_bounds__(256) void k_hist(const int* __restrict__ ei,
                                              int* __restrict__ deg)
{
    const int e = blockIdx.x * 1024 + threadIdx.x * 4;
    const int4 d4 = *(const int4*)&ei[EDGES + e];
    atomicAdd(&deg[d4.x], 1);
    atomicAdd(&deg[d4.y], 1);
    atomicAdd(&deg[d4.z], 1);
    atomicAdd(&deg[d4.w], 1);
}

// ---------------- CSR build: exclusive prefix scan (1 block) ---------------
__global__ __launch_bounds__(1024) void k_scanidx(const int* __restrict__ deg,
                                                  int* __restrict__ base,
                                                  int* __restrict__ cursor)
{
    __shared__ int ps[1024];
    const int tid = threadIdx.x;
    int loc[32];
    int s = 0;
#pragma unroll
    for (int i = 0; i < 32; ++i) { loc[i] = deg[tid * 32 + i]; s += loc[i]; }
    ps[tid] = s;
    __syncthreads();
    for (int off = 1; off < 1024; off <<= 1) {
        int v = (tid >= off) ? ps[tid - off] : 0;
        __syncthreads();
        ps[tid] += v;
        __syncthreads();
    }
    int run = tid ? ps[tid - 1] : 0;
#pragma unroll
    for (int i = 0; i < 32; ++i) {
        base[tid * 32 + i] = run;
        cursor[tid * 32 + i] = run;
        run += loc[i];
    }
    if (tid == 0) base[32768] = EDGES;
}

// ------------------------- CSR build: fill src lists -----------------------
__global__ __launch_bounds__(256) void k_fill(const int* __restrict__ ei,
                                              int* __restrict__ cursor,
                                              int* __restrict__ srcs)
{
    const int e = blockIdx.x * 1024 + threadIdx.x * 4;
    const int4 s4 = *(const int4*)&ei[e];
    const int4 d4 = *(const int4*)&ei[EDGES + e];
    int p;
    p = atomicAdd(&cursor[d4.x], 1); srcs[p] = s4.x;
    p = atomicAdd(&cursor[d4.y], 1); srcs[p] = s4.y;
    p = atomicAdd(&cursor[d4.z], 1); srcs[p] = s4.z;
    p = atomicAdd(&cursor[d4.w], 1); srcs[p] = s4.w;
}

// ------------------------- gather: one wave per node ------------------------
__global__ __launch_bounds__(256) void k_gather(const float* __restrict__ x,
                                                const int* __restrict__ base,
                                                const int* __restrict__ srcs,
                                                float* __restrict__ agg)
{
    const int node = blockIdx.x * 4 + (threadIdx.x >> 6);
    const int lane = threadIdx.x & 63;
    const int b0 = base[node], b1 = base[node + 1];
    float2 a0 = make_float2(0.f, 0.f), a1 = make_float2(0.f, 0.f);
    int i = b0;
    for (; i + 2 <= b1; i += 2) {
        const int s0 = srcs[i], s1 = srcs[i + 1];
        const float2 v0 = *(const float2*)&x[(size_t)s0 * 128 + lane * 2];
        const float2 v1 = *(const float2*)&x[(size_t)s1 * 128 + lane * 2];
        a0.x += v0.x; a0.y += v0.y;
        a1.x += v1.x; a1.y += v1.y;
    }
    if (i < b1) {
        const int s0 = srcs[i];
        const float2 v0 = *(const float2*)&x[(size_t)s0 * 128 + lane * 2];
        a0.x += v0.x; a0.y += v0.y;
    }
    a0.x += a1.x; a0.y += a1.y;
    *(float2*)&agg[(size_t)node * 128 + lane * 2] = a0;
}

// --------------- weight prep: WT[n][k] = bf16(W[k][n]), K = 1<<kshift -------
__global__ __launch_bounds__(256) void k_prepw(const float* __restrict__ W,
                                               unsigned short* __restrict__ WT,
                                               int kshift, int total)
{
    const int idx = blockIdx.x * 256 + threadIdx.x;
    if (idx >= total) return;
    const int K = 1 << kshift;
    const int n = idx >> kshift, k = idx & (K - 1);
    const int N = total >> kshift;
    WT[idx] = f2bf(W[(size_t)k * N + n]);
}

// ------------------------- MFMA GEMM (bf16 in, fp32 acc) --------------------
// out = epi( A0@W0 [+ A1@W1] [+bias] [+resid] ), optional column stats.
// A: MxK fp32 row-major. WT: NxK bf16 row-major (pre-transposed weights).
// Tile 64x64, BK=64, 4 waves x (2x2 mfma_f32_16x16x32_bf16).
template<bool DUAL, int ACT, bool STAT>
__global__ __launch_bounds__(256)
void gemm_mfma(const float* __restrict__ A0, const unsigned short* __restrict__ W0T,
               const float* __restrict__ A1p, const unsigned short* __restrict__ W1Tp,
               int M, int N, int K, int ldo,
               const float* __restrict__ bias,
               const float* __restrict__ resid, int ldr,
               float* __restrict__ outp,
               float* __restrict__ sumP, float* __restrict__ sqP)
{
    __shared__ __align__(16) unsigned short As[64 * 72];  // [m][k], pad 8
    __shared__ __align__(16) unsigned short Bs[64 * 72];  // [n][k], pad 8
    __shared__ float sB[2][64];

    const int tid = threadIdx.x;
    const int m0 = blockIdx.x * 64;
    const int n0 = blockIdx.y * 64;

    const int sr = tid >> 2;             // staging row 0..63
    const int sk = (tid & 3) * 16;       // staging k base

    const int w  = tid >> 6, l = tid & 63;
    const int wr = (w >> 1) * 32, wc = (w & 1) * 32;
    const int fr = l & 15;               // frag row/col
    const int fk = (l >> 4) * 8;         // frag k base

    f32x4 acc[2][2];
#pragma unroll
    for (int i = 0; i < 2; ++i)
#pragma unroll
        for (int j = 0; j < 2; ++j) acc[i][j] = (f32x4){0.f, 0.f, 0.f, 0.f};

    const int npass = DUAL ? 2 : 1;
    for (int pass = 0; pass < npass; ++pass) {
        const float* A = (DUAL && pass) ? A1p : A0;
        const unsigned short* WT = (DUAL && pass) ? W1Tp : W0T;
        for (int k0 = 0; k0 < K; k0 += 64) {
            {   // stage A: fp32 -> bf16
                const float* ap = A + (size_t)(m0 + sr) * K + k0 + sk;
#pragma unroll
                for (int j = 0; j < 4; ++j) {
                    float4 v = *(const float4*)(ap + 4 * j);
                    ushort4 b = make_ushort4(f2bf(v.x), f2bf(v.y),
                                             f2bf(v.z), f2bf(v.w));
                    *(ushort4*)&As[sr * 72 + sk + 4 * j] = b;
                }
            }
            {   // stage B: straight bf16 copy from WT (zero-fill n >= N)
                const int nn = n0 + sr;
                if (nn < N) {
                    const unsigned short* wp = WT + (size_t)nn * K + k0 + sk;
                    uint4 w0 = *(const uint4*)(wp);
                    uint4 w1 = *(const uint4*)(wp + 8);
                    *(uint4*)&Bs[sr * 72 + sk]     = w0;
                    *(uint4*)&Bs[sr * 72 + sk + 8] = w1;
                } else {
                    uint4 z = make_uint4(0, 0, 0, 0);
                    *(uint4*)&Bs[sr * 72 + sk]     = z;
                    *(uint4*)&Bs[sr * 72 + sk + 8] = z;
                }
            }
            __syncthreads();
#pragma unroll
            for (int ks = 0; ks < 2; ++ks) {
                s16x8 a0 = *(const s16x8*)&As[(wr + fr     ) * 72 + ks * 32 + fk];
                s16x8 a1 = *(const s16x8*)&As[(wr + 16 + fr) * 72 + ks * 32 + fk];
                s16x8 b0 = *(const s16x8*)&Bs[(wc + fr     ) * 72 + ks * 32 + fk];
                s16x8 b1 = *(const s16x8*)&Bs[(wc + 16 + fr) * 72 + ks * 32 + fk];
                acc[0][0] = __builtin_amdgcn_mfma_f32_16x16x32_bf16(a0, b0, acc[0][0], 0, 0, 0);
                acc[0][1] = __builtin_amdgcn_mfma_f32_16x16x32_bf16(a0, b1, acc[0][1], 0, 0, 0);
                acc[1][0] = __builtin_amdgcn_mfma_f32_16x16x32_bf16(a1, b0, acc[1][0], 0, 0, 0);
                acc[1][1] = __builtin_amdgcn_mfma_f32_16x16x32_bf16(a1, b1, acc[1][1], 0, 0, 0);
            }
            __syncthreads();
        }
    }

    // ---- epilogue: C/D layout col=lane&15, row=(lane>>4)*4+reg ----
    const int orow = (l >> 4) * 4;
    float cs[2] = {0.f, 0.f}, cq[2] = {0.f, 0.f};
#pragma unroll
    for (int mt = 0; mt < 2; ++mt) {
#pragma unroll
        for (int nt = 0; nt < 2; ++nt) {
            const int cg = n0 + wc + nt * 16 + fr;
            if (cg < N) {
                const float bv = bias ? bias[cg] : 0.f;
#pragma unroll
                for (int r = 0; r < 4; ++r) {
                    const int rg = m0 + wr + mt * 16 + orow + r;
                    float v = acc[mt][nt][r] + bv;
                    if (resid) v += resid[(size_t)rg * ldr + cg];
                    if (ACT == 1)
                        v = 0.5f * v * (1.f + erff(v * 0.7071067811865475f));
                    outp[(size_t)rg * ldo + cg] = v;
                    if (STAT) { cs[nt] += v; cq[nt] += v * v; }
                }
            }
        }
    }
    if (STAT) {
        if (tid < 64) { sB[0][tid] = 0.f; sB[1][tid] = 0.f; }
        __syncthreads();
#pragma unroll
        for (int nt = 0; nt < 2; ++nt) {
            atomicAdd(&sB[0][wc + nt * 16 + fr], cs[nt]);
            atomicAdd(&sB[1][wc + nt * 16 + fr], cq[nt]);
        }
        __syncthreads();
        if (tid < 64 && (n0 + tid) < N) {
            atomicAdd(&sumP[n0 + tid], sB[0][tid]);
            atomicAdd(&sqP[n0 + tid],  sB[1][tid]);
        }
    }
}

// --------------------------- causal conv + SiLU ----------------------------
__global__ __launch_bounds__(256) void k_conv(const float* __restrict__ xz,
                                              const float* __restrict__ cw,
                                              const float* __restrict__ cb,
                                              float* __restrict__ xc)
{
    const int r = blockIdx.x;        // global row
    const int l = r & (GL - 1);      // position within graph
    const int d = threadIdx.x;       // 0..255
    float4 w4 = *(const float4*)&cw[d * 4];
    const float taps[4] = {w4.x, w4.y, w4.z, w4.w};
    float acc = cb[d];
#pragma unroll
    for (int k = 0; k < 4; ++k) {
        int ll = l - 3 + k;
        if (ll >= 0) acc += xz[(size_t)(r - 3 + k) * 512 + d] * taps[k];
    }
    float s = 1.f / (1.f + __expf(-acc));
    xc[(size_t)r * 256 + d] = acc * s;
}

// ---------------- dt = softplus(proj[:,:8] @ dt_W + dt_b); B,C slices ------
__global__ __launch_bounds__(256) void k_dtbc(const float* __restrict__ proj,
                                              const float* __restrict__ dt_W,
                                              const float* __restrict__ dt_b,
                                              float* __restrict__ dtb,
                                              float* __restrict__ Bc,
                                              float* __restrict__ Cc)
{
    __shared__ float dtWS[8 * 256];
    __shared__ float dt_bS[256];
    __shared__ float projS[32 * 8];
    const int tid = threadIdx.x;
    const int r0 = blockIdx.x * 32;
    for (int i = tid; i < 2048; i += 256) dtWS[i] = dt_W[i];
    dt_bS[tid] = dt_b[tid];
    projS[tid] = proj[(size_t)(r0 + (tid >> 3)) * 40 + (tid & 7)];
    __syncthreads();

    const int c = tid;
    for (int rr = 0; rr < 32; ++rr) {
        float acc = dt_bS[c];
        const float* pr = &projS[rr * 8];
#pragma unroll
        for (int q = 0; q < 8; ++q) acc += pr[q] * dtWS[q * 256 + c];
        float sp = fmaxf(acc, 0.f) + log1pf(__expf(-fabsf(acc)));
        dtb[(size_t)(r0 + rr) * 256 + c] = sp;
    }
    // B = proj[:, 8:24], C = proj[:, 24:40]
    for (int e = tid; e < 1024; e += 256) {
        int rr = e >> 5, cc = e & 31;
        float v = proj[(size_t)(r0 + rr) * 40 + 8 + cc];
        if (cc < 16) Bc[(size_t)(r0 + rr) * 16 + cc] = v;
        else         Cc[(size_t)(r0 + rr) * 16 + cc - 16] = v;
    }
}

// ---------------- 16-lane-group sum via DPP (zero DS-pipe ops) --------------
__device__ __forceinline__ float dpp_add16(float x)
{
    float y = x;
    int t;
    t = __builtin_amdgcn_update_dpp(0, __float_as_int(y), 0xB1, 0xF, 0xF, true);
    y += __int_as_float(t);
    t = __builtin_amdgcn_update_dpp(0, __float_as_int(y), 0x4E, 0xF, 0xF, true);
    y += __int_as_float(t);
    t = __builtin_amdgcn_update_dpp(0, __float_as_int(y), 0x141, 0xF, 0xF, true);
    y += __int_as_float(t);
    t = __builtin_amdgcn_update_dpp(0, __float_as_int(y), 0x140, 0xF, 0xF, true);
    y += __int_as_float(t);
    return y;
}

// ------------------------------ selective scan -----------------------------
// (unchanged from round 5: transposed LDS tiles, DPP reduce, coalesced out)
__global__ __launch_bounds__(512) void k_scan(const float* __restrict__ dtb,
                                              const float* __restrict__ xcb,
                                              const float* __restrict__ xzb,
                                              const float* __restrict__ Bb,
                                              const float* __restrict__ Cb,
                                              const float* __restrict__ A_log,
                                              const float* __restrict__ Dp,
                                              float* __restrict__ yg)
{
    __shared__ __align__(16) float lds[2 * 3456 + 32 * 33];

    const int g    = blockIdx.x >> 3;
    const int dblk = blockIdx.x & 7;
    const int tid  = threadIdx.x;
    const int s    = tid & 15;
    const int dl   = tid >> 4;
    const int d0   = dblk * 32;
    const int d    = d0 + dl;
    const size_t rbase = (size_t)g * GL;

    const int st_t = tid >> 4;
    const int st_i = tid & 15;

    const float aA  = -__expf(A_log[d * 16 + s]);
    const float Dpd = Dp[d];
    float h = 0.f;

    float2 r_dt, r_xc, z_cur, z_nxt;
    float r_B, r_C;

    {
        const size_t r0 = rbase;
        r_dt  = *(const float2*)&dtb[(r0 + st_t) * 256 + d0 + st_i * 2];
        r_xc  = *(const float2*)&xcb[(r0 + st_t) * 256 + d0 + st_i * 2];
        z_cur = *(const float2*)&xzb[(r0 + st_t) * 512 + 256 + d0 + st_i * 2];
        r_B   = Bb[(r0 + st_t) * 16 + st_i];
        r_C   = Cb[(r0 + st_t) * 16 + st_i];
    }
    z_nxt = z_cur;

    float* ygL = lds + 2 * 3456;

    for (int c = 0; c < NCH; ++c) {
        float* buf = lds + (c & 1) * 3456;
        buf[(st_i * 2    ) * 36 + st_t] = r_dt.x;
        buf[(st_i * 2 + 1) * 36 + st_t] = r_dt.y;
        buf[1152 + (st_i * 2    ) * 36 + st_t] = r_xc.x;
        buf[1152 + (st_i * 2 + 1) * 36 + st_t] = r_xc.y;
        buf[2304 + st_i * 36 + st_t] = r_B;
        buf[2880 + st_i * 36 + st_t] = r_C;
        __syncthreads();

        if (c + 1 < NCH) {
            const size_t r0 = rbase + (size_t)(c + 1) * SCH;
            r_dt  = *(const float2*)&dtb[(r0 + st_t) * 256 + d0 + st_i * 2];
            r_xc  = *(const float2*)&xcb[(r0 + st_t) * 256 + d0 + st_i * 2];
            z_nxt = *(const float2*)&xzb[(r0 + st_t) * 512 + 256 + d0 + st_i * 2];
            r_B   = Bb[(r0 + st_t) * 16 + st_i];
            r_C   = Cb[(r0 + st_t) * 16 + st_i];
        }

        const float* pdt = buf + dl * 36;
        const float* pxc = buf + 1152 + dl * 36;
        const float* pB  = buf + 2304 + s * 36;
        const float* pC  = buf + 2880 + s * 36;
        const size_t rr0 = rbase + (size_t)c * SCH;
#pragma unroll
        for (int t4 = 0; t4 < 8; ++t4) {
            const float4 dt4 = *(const float4*)&pdt[t4 * 4];
            const float4 xc4 = *(const float4*)&pxc[t4 * 4];
            const float4 B4  = *(const float4*)&pB [t4 * 4];
            const float4 C4  = *(const float4*)&pC [t4 * 4];
#define SSTEP(DT, XC, BV, CV, J)                                          \
            {                                                             \
                h = h * __expf((DT) * aA) + (DT) * (XC) * (BV);           \
                float yv = dpp_add16(h * (CV));                           \
                if (s == 0)                                               \
                    ygL[(t4 * 4 + (J)) * 33 + dl] = yv + (XC) * Dpd;      \
            }
            SSTEP(dt4.x, xc4.x, B4.x, C4.x, 0)
            SSTEP(dt4.y, xc4.y, B4.y, C4.y, 1)
            SSTEP(dt4.z, xc4.z, B4.z, C4.z, 2)
            SSTEP(dt4.w, xc4.w, B4.w, C4.w, 3)
#undef SSTEP
        }
        __syncthreads();

        {
            const size_t rr0w = rbase + (size_t)c * SCH;
            const float y0 = ygL[st_t * 33 + st_i * 2];
            const float y1 = ygL[st_t * 33 + st_i * 2 + 1];
            const float s0 = z_cur.x / (1.f + __expf(-z_cur.x));
            const float s1 = z_cur.y / (1.f + __expf(-z_cur.y));
            *(float2*)&yg[(rr0w + st_t) * 256 + d0 + st_i * 2] =
                make_float2(y0 * s0, y1 * s1);
        }
        z_cur = z_nxt;
        (void)rr0;
    }
}

// -------------------------- BN finalize / fold / add -----------------------
__global__ __launch_bounds__(256) void k_fin12(const float* __restrict__ st,
                                               const float* g1, const float* be1,
                                               const float* g2, const float* be2,
                                               float* __restrict__ ab)
{
    const int tid = threadIdx.x;
    const float inv = 1.f / 32768.f;
    if (tid < 128) {
        float m = st[tid] * inv, v = st[128 + tid] * inv - m * m;
        float a = g1[tid] * rsqrtf(v + 1e-5f);
        ab[tid] = a; ab[256 + tid] = be1[tid] - m * a;
    } else {
        int c = tid - 128;
        float m = st[256 + c] * inv, v = st[384 + c] * inv - m * m;
        float a = g2[c] * rsqrtf(v + 1e-5f);
        ab[512 + c] = a; ab[768 + c] = be2[c] - m * a;
    }
}

__global__ __launch_bounds__(256) void k_add(const float* __restrict__ h1p,
                                             const float* __restrict__ p2,
                                             const float* __restrict__ ab,
                                             float* __restrict__ outp,
                                             float* __restrict__ sumP,
                                             float* __restrict__ sqP)
{
    const int c = threadIdx.x & 127, half = threadIdx.x >> 7;
    const int rbase = blockIdx.x * 64 + half * 32;
    const float a1 = ab[c], b1 = ab[256 + c], a2 = ab[512 + c], b2 = ab[768 + c];
    float s = 0.f, q = 0.f;
    for (int i = 0; i < 32; ++i) {
        size_t idx = (size_t)(rbase + i) * 128 + c;
        float v = h1p[idx] * a1 + b1 + p2[idx] * a2 + b2;
        outp[idx] = v; s += v; q += v * v;
    }
    __shared__ float sh[2][2][128];
    sh[0][half][c] = s; sh[1][half][c] = q;
    __syncthreads();
    if (threadIdx.x < 128) {
        atomicAdd(&sumP[c], sh[0][0][c] + sh[0][1][c]);
        atomicAdd(&sqP[c],  sh[1][0][c] + sh[1][1][c]);
    }
}

// fold1: emits W1eT bf16 [256][128] + b1e fp32
__global__ __launch_bounds__(256) void k_fin3_fold1(
    const float* __restrict__ sumP, const float* __restrict__ sqP,
    const float* __restrict__ gam, const float* __restrict__ bet,
    const float* __restrict__ W1, const float* __restrict__ b1in,
    unsigned short* __restrict__ W1eT, float* __restrict__ b1e)
{
    __shared__ float aS[128], bS[128];
    const int tid = threadIdx.x;
    const float inv = 1.f / 32768.f;
    if (tid < 128) {
        float m = sumP[tid] * inv, v = sqP[tid] * inv - m * m;
        float a = gam[tid] * rsqrtf(v + 1e-5f);
        aS[tid] = a; bS[tid] = bet[tid] - m * a;
    }
    __syncthreads();
    const int n = tid;                       // output column 0..255
    float acc = b1in[n];
    for (int k = 0; k < 128; ++k) {
        float wv = W1[k * 256 + n];
        W1eT[n * 128 + k] = f2bf(aS[k] * wv);
        acc += bS[k] * wv;
    }
    b1e[n] = acc;
}

// fold2: emits W2eT bf16 [128][256] + b2e fp32
__global__ __launch_bounds__(256) void k_fin4_fold2(
    const float* __restrict__ sumP, const float* __restrict__ sqP,
    const float* __restrict__ gam, const float* __restrict__ bet,
    const float* __restrict__ W2, const float* __restrict__ b2in,
    unsigned short* __restrict__ W2eT, float* __restrict__ b2e)
{
    __shared__ float aS[256], bS[256];
    const int tid = threadIdx.x;
    const float inv = 1.f / 32768.f;
    {
        float m = sumP[tid] * inv, v = sqP[tid] * inv - m * m;
        float a = gam[tid] * rsqrtf(v + 1e-5f);
        aS[tid] = a; bS[tid] = bet[tid] - m * a;
    }
    __syncthreads();
    if (tid < 128) {
        const int n = tid;                   // output column 0..127
        float acc = b2in[n];
        for (int k = 0; k < 256; ++k) {
            float wv = W2[k * 128 + n];
            W2eT[n * 256 + k] = f2bf(aS[k] * wv);
            acc += bS[k] * wv;
        }
        b2e[n] = acc;
    }
}

__global__ __launch_bounds__(128) void k_fin5(const float* __restrict__ sumP,
                                              const float* __restrict__ sqP,
                                              const float* gam, const float* bet,
                                              float* __restrict__ ab)
{
    const int tid = threadIdx.x;
    if (tid < 128) {
        const float inv = 1.f / 32768.f;
        float m = sumP[tid] * inv, v = sqP[tid] * inv - m * m;
        float a = gam[tid] * rsqrtf(v + 1e-5f);
        ab[2048 + tid] = a; ab[2304 + tid] = bet[tid] - m * a;
    }
}

__global__ __launch_bounds__(256) void k_bn3(const float* __restrict__ out2,
                                             const float* __restrict__ ab,
                                             float* __restrict__ dout)
{
    size_t i4 = ((size_t)blockIdx.x * 256 + threadIdx.x) * 4;
    int c = (int)(i4 & 127);
    float4 v = *(const float4*)&out2[i4];
    float4 a = *(const float4*)&ab[2048 + c];
    float4 b = *(const float4*)&ab[2304 + c];
    v.x = v.x * a.x + b.x; v.y = v.y * a.y + b.y;
    v.z = v.z * a.z + b.z; v.w = v.w * a.w + b.w;
    *(float4*)&dout[i4] = v;
}

// ------------------------------- launch ------------------------------------
extern "C" void kernel_launch(void* const* d_in, const int* in_sizes, int n_in,
                              void* d_out, int out_size, void* d_ws, size_t ws_size,
                              hipStream_t stream)
{
    (void)in_sizes; (void)n_in; (void)out_size; (void)ws_size;
    const float* x      = (const float*)d_in[0];
    const int*   ei     = (const int*)d_in[1];
    // d_in[2] = batch (unused: equal-size sorted graphs == reshape)
    const float* W_root = (const float*)d_in[3];
    const float* W_rel  = (const float*)d_in[4];
    const float* b_rel  = (const float*)d_in[5];
    const float* n1_g = (const float*)d_in[6],  *n1_b = (const float*)d_in[7];
    const float* n2_g = (const float*)d_in[8],  *n2_b = (const float*)d_in[9];
    const float* n3_g = (const float*)d_in[10], *n3_b = (const float*)d_in[11];
    const float* m1_g = (const float*)d_in[12], *m1_b = (const float*)d_in[13];
    const float* W1   = (const float*)d_in[14], *b1   = (const float*)d_in[15];
    const float* m2_g = (const float*)d_in[16], *m2_b = (const float*)d_in[17];
    const float* W2   = (const float*)d_in[18], *b2   = (const float*)d_in[19];
    const float* in_W   = (const float*)d_in[20];
    const float* conv_w = (const float*)d_in[21], *conv_b = (const float*)d_in[22];
    const float* xproj_W= (const float*)d_in[23];
    const float* dt_W   = (const float*)d_in[24], *dt_b = (const float*)d_in[25];
    const float* A_log  = (const float*)d_in[26], *Dp   = (const float*)d_in[27];
    const float* out_W  = (const float*)d_in[28];

    float* ws = (float*)d_ws;
    // small region
    float* st  = ws;             // 2048 used (S1..S5 sums/sumsqs)
    float* ab  = ws + 4096;      // a/b affine params
    float* b1e = ws + 8192;      // 256
    float* b2e = ws + 8448;      // 128
    // bf16 transposed weights (shorts)
    unsigned short* wsh   = (unsigned short*)(ws + 8704);
    unsigned short* WrelT  = wsh;            // 128x128 = 16384
    unsigned short* WrootT = wsh + 16384;    // 16384
    unsigned short* inWT   = wsh + 32768;    // 512x128 = 65536
    unsigned short* xprojT = wsh + 98304;    // 40x256  = 10240
    unsigned short* outWT  = wsh + 108544;   // 128x256 = 32768
    unsigned short* W1eT   = wsh + 141312;   // 256x128 = 32768
    unsigned short* W2eT   = wsh + 174080;   // 128x256 = 32768 (end 206848)
    // big buffers
    float* big  = ws + 112640;
    float* agg  = big;                    // 4194304 (later reused as p2)
    float* p2   = agg;
    float* h1p  = big + 4194304;          // 4194304
    float* xz   = big + 8388608;          // 16777216 (later: g + out2)
    float* gbuf = xz;
    float* out2 = xz + 8388608;
    float* xc   = big + 25165824;         // 8388608
    float* proj = big + 33554432;         // 1310720
    float* dtb  = big + 34865152;         // 8388608 (yg aliases dtb)
    float* ygb  = dtb;
    float* Bc   = big + 43253760;         // 524288
    float* Cc   = big + 43778048;         // 524288
    float* outb = big + 44302336;         // 4194304

    // CSR scratch lives in the h1p region (dead until the h1 GEMM writes it)
    int* ideg   = (int*)h1p;              // 32768
    int* ibase  = ideg + 32768;           // 32769
    int* icur   = ideg + 65552;           // 32768 (16B-aligned)
    int* isrcs  = ideg + 98320;           // 524288

    hipMemsetAsync(st, 0, 2048 * sizeof(float), stream);
    hipMemsetAsync(ideg, 0, 32768 * sizeof(int), stream);

    // ---- weight prep (bf16 transposes; independent of everything else) ----
    k_prepw<<<64, 256, 0, stream>>>(W_rel,   WrelT,  7, 16384);
    k_prepw<<<64, 256, 0, stream>>>(W_root,  WrootT, 7, 16384);
    k_prepw<<<256, 256, 0, stream>>>(in_W,   inWT,   7, 65536);
    k_prepw<<<40, 256, 0, stream>>>(xproj_W, xprojT, 8, 10240);
    k_prepw<<<128, 256, 0, stream>>>(out_W,  outWT,  8, 32768);

    // ---- CSR build + gather ----
    k_hist<<<512, 256, 0, stream>>>(ei, ideg);
    k_scanidx<<<1, 1024, 0, stream>>>(ideg, ibase, icur);
    k_fill<<<512, 256, 0, stream>>>(ei, icur, isrcs);
    k_gather<<<8192, 256, 0, stream>>>(x, ibase, isrcs, agg);

    // h1_pre = agg@W_rel + b_rel + x@W_root + x  [S1]
    gemm_mfma<true, 0, true><<<dim3(512, 2), 256, 0, stream>>>(
        agg, WrelT, x, WrootT, NROWS, 128, 128, 128,
        b_rel, x, 128, h1p, st + 0, st + 128);
    // xz = x @ in_W
    gemm_mfma<false, 0, false><<<dim3(512, 8), 256, 0, stream>>>(
        x, inWT, nullptr, nullptr, NROWS, 512, 128, 512,
        nullptr, nullptr, 0, xz, nullptr, nullptr);
    k_conv<<<32768, 256, 0, stream>>>(xz, conv_w, conv_b, xc);
    // proj = xc @ xproj_W (N=40)
    gemm_mfma<false, 0, false><<<dim3(512, 1), 256, 0, stream>>>(
        xc, xprojT, nullptr, nullptr, NROWS, 40, 256, 40,
        nullptr, nullptr, 0, proj, nullptr, nullptr);
    k_dtbc<<<1024, 256, 0, stream>>>(proj, dt_W, dt_b, dtb, Bc, Cc);
    k_scan<<<512, 512, 0, stream>>>(dtb, xc, xz, Bc, Cc, A_log, Dp, ygb);
    // p2 = yg @ out_W + x  [S2]
    gemm_mfma<false, 0, true><<<dim3(512, 2), 256, 0, stream>>>(
        ygb, outWT, nullptr, nullptr, NROWS, 128, 256, 128,
        nullptr, x, 128, p2, st + 256, st + 384);
    k_fin12<<<1, 256, 0, stream>>>(st, n1_g, n1_b, n2_g, n2_b, ab);
    // out = BN1(h1_pre) + BN2(p2)  [S3]
    k_add<<<512, 256, 0, stream>>>(h1p, p2, ab, outb, st + 512, st + 640);
    k_fin3_fold1<<<1, 256, 0, stream>>>(st + 512, st + 640, m1_g, m1_b, W1, b1, W1eT, b1e);
    // g = gelu(out @ W1e + b1e)  [S4]
    gemm_mfma<false, 1, true><<<dim3(512, 4), 256, 0, stream>>>(
        outb, W1eT, nullptr, nullptr, NROWS, 256, 128, 256,
        b1e, nullptr, 0, gbuf, st + 768, st + 1024);
    k_fin4_fold2<<<1, 256, 0, stream>>>(st + 768, st + 1024, m2_g, m2_b, W2, b2, W2eT, b2e);
    // out2 = g @ W2e + b2e + out  [S5]
    gemm_mfma<false, 0, true><<<dim3(512, 2), 256, 0, stream>>>(
        gbuf, W2eT, nullptr, nullptr, NROWS, 128, 256, 128,
        b2e, outb, 128, out2, st + 1280, st + 1408);
    k_fin5<<<1, 128, 0, stream>>>(st + 1280, st + 1408, n3_g, n3_b, ab);
    k_bn3<<<4096, 256, 0, stream>>>(out2, ab, (float*)d_out);
}

// Round 7
// 468.010 us; speedup vs baseline: 1.5366x; 1.0279x over previous
//
#include <hip/hip_runtime.h>

// ---------------------------------------------------------------------------
// GraphMambaConv: N=32768 nodes, C=128, G=64 graphs x L=512, E=524288 edges,
// D_INNER=256, D_STATE=16, DT_RANK=8, D_CONV=4.
//
// Round 7:
//  - gemm_mfma A-staging: manual f2bf (64 VALU/thread/ktile) ->
//    v_cvt_pk_bf16_f32 inline asm (8 instr) — staging was VALU-bound.
//  - k_scan remap: 2 states/lane, 8 lanes/d (wave = 8d x 8sp), 3-stage DPP
//    reduce, register-capture (cndmask) instead of per-step predicated
//    writes, chunk-end coalesced writeout. 256 blocks x 512 thr = 2 w/SIMD.
// ---------------------------------------------------------------------------

#define NROWS 32768
#define CDIM  128
#define EDGES 524288
#define GL    512
#define SCH   32          // scan chunk (timesteps)
#define NCH   (GL / SCH)  // 16 chunks

typedef short s16x8 __attribute__((ext_vector_type(8)));
typedef float f32x4 __attribute__((ext_vector_type(4)));

__device__ __forceinline__ unsigned short f2bf(float f)
{
    unsigned u = __float_as_uint(f);
    u += 0x7FFF + ((u >> 16) & 1);          // RNE
    return (unsigned short)(u >> 16);
}

__device__ __forceinline__ unsigned cvt_pk_bf16(float lo, float hi)
{
    unsigned r;
    asm("v_cvt_pk_bf16_f32 %0, %1, %2" : "=v"(r) : "v"(lo), "v"(hi));
    return r;
}

// ------------------------- CSR build: histogram ----------------------------
__global__ __launch_bounds__(256) void k_hist(const int* __restrict__ ei,
                                              int* __restrict__ deg)
{
    const int e = blockIdx.x * 1024 + threadIdx.x * 4;
    const int4 d4 = *(const int4*)&ei[EDGES + e];
    atomicAdd(&deg[d4.x], 1);
    atomicAdd(&deg[d4.y], 1);
    atomicAdd(&deg[d4.z], 1);
    atomicAdd(&deg[d4.w], 1);
}

// ---------------- CSR build: exclusive prefix scan (1 block) ---------------
__global__ __launch_bounds__(1024) void k_scanidx(const int* __restrict__ deg,
                                                  int* __restrict__ base,
                                                  int* __restrict__ cursor)
{
    __shared__ int ps[1024];
    const int tid = threadIdx.x;
    int loc[32];
    int s = 0;
#pragma unroll
    for (int i = 0; i < 32; ++i) { loc[i] = deg[tid * 32 + i]; s += loc[i]; }
    ps[tid] = s;
    __syncthreads();
    for (int off = 1; off < 1024; off <<= 1) {
        int v = (tid >= off) ? ps[tid - off] : 0;
        __syncthreads();
        ps[tid] += v;
        __syncthreads();
    }
    int run = tid ? ps[tid - 1] : 0;
#pragma unroll
    for (int i = 0; i < 32; ++i) {
        base[tid * 32 + i] = run;
        cursor[tid * 32 + i] = run;
        run += loc[i];
    }
    if (tid == 0) base[32768] = EDGES;
}

// ------------------------- CSR build: fill src lists -----------------------
__global__ __launch_bounds__(256) void k_fill(const int* __restrict__ ei,
                                              int* __restrict__ cursor,
                                              int* __restrict__ srcs)
{
    const int e = blockIdx.x * 1024 + threadIdx.x * 4;
    const int4 s4 = *(const int4*)&ei[e];
    const int4 d4 = *(const int4*)&ei[EDGES + e];
    int p;
    p = atomicAdd(&cursor[d4.x], 1); srcs[p] = s4.x;
    p = atomicAdd(&cursor[d4.y], 1); srcs[p] = s4.y;
    p = atomicAdd(&cursor[d4.z], 1); srcs[p] = s4.z;
    p = atomicAdd(&cursor[d4.w], 1); srcs[p] = s4.w;
}

// ------------------------- gather: one wave per node ------------------------
__global__ __launch_bounds__(256) void k_gather(const float* __restrict__ x,
                                                const int* __restrict__ base,
                                                const int* __restrict__ srcs,
                                                float* __restrict__ agg)
{
    const int node = blockIdx.x * 4 + (threadIdx.x >> 6);
    const int lane = threadIdx.x & 63;
    const int b0 = base[node], b1 = base[node + 1];
    float2 a0 = make_float2(0.f, 0.f), a1 = make_float2(0.f, 0.f);
    int i = b0;
    for (; i + 2 <= b1; i += 2) {
        const int s0 = srcs[i], s1 = srcs[i + 1];
        const float2 v0 = *(const float2*)&x[(size_t)s0 * 128 + lane * 2];
        const float2 v1 = *(const float2*)&x[(size_t)s1 * 128 + lane * 2];
        a0.x += v0.x; a0.y += v0.y;
        a1.x += v1.x; a1.y += v1.y;
    }
    if (i < b1) {
        const int s0 = srcs[i];
        const float2 v0 = *(const float2*)&x[(size_t)s0 * 128 + lane * 2];
        a0.x += v0.x; a0.y += v0.y;
    }
    a0.x += a1.x; a0.y += a1.y;
    *(float2*)&agg[(size_t)node * 128 + lane * 2] = a0;
}

// --------------- weight prep: WT[n][k] = bf16(W[k][n]), K = 1<<kshift -------
__global__ __launch_bounds__(256) void k_prepw(const float* __restrict__ W,
                                               unsigned short* __restrict__ WT,
                                               int kshift, int total)
{
    const int idx = blockIdx.x * 256 + threadIdx.x;
    if (idx >= total) return;
    const int K = 1 << kshift;
    const int n = idx >> kshift, k = idx & (K - 1);
    const int N = total >> kshift;
    WT[idx] = f2bf(W[(size_t)k * N + n]);
}

// ------------------------- MFMA GEMM (bf16 in, fp32 acc) --------------------
// out = epi( A0@W0 [+ A1@W1] [+bias] [+resid] ), optional column stats.
// A: MxK fp32 row-major. WT: NxK bf16 row-major (pre-transposed weights).
// Tile 64x64, BK=64, 4 waves x (2x2 mfma_f32_16x16x32_bf16).
template<bool DUAL, int ACT, bool STAT>
__global__ __launch_bounds__(256)
void gemm_mfma(const float* __restrict__ A0, const unsigned short* __restrict__ W0T,
               const float* __restrict__ A1p, const unsigned short* __restrict__ W1Tp,
               int M, int N, int K, int ldo,
               const float* __restrict__ bias,
               const float* __restrict__ resid, int ldr,
               float* __restrict__ outp,
               float* __restrict__ sumP, float* __restrict__ sqP)
{
    __shared__ __align__(16) unsigned short As[64 * 72];  // [m][k], pad 8
    __shared__ __align__(16) unsigned short Bs[64 * 72];  // [n][k], pad 8
    __shared__ float sB[2][64];

    const int tid = threadIdx.x;
    const int m0 = blockIdx.x * 64;
    const int n0 = blockIdx.y * 64;

    const int sr = tid >> 2;             // staging row 0..63
    const int sk = (tid & 3) * 16;       // staging k base

    const int w  = tid >> 6, l = tid & 63;
    const int wr = (w >> 1) * 32, wc = (w & 1) * 32;
    const int fr = l & 15;               // frag row/col
    const int fk = (l >> 4) * 8;         // frag k base

    f32x4 acc[2][2];
#pragma unroll
    for (int i = 0; i < 2; ++i)
#pragma unroll
        for (int j = 0; j < 2; ++j) acc[i][j] = (f32x4){0.f, 0.f, 0.f, 0.f};

    const int npass = DUAL ? 2 : 1;
    for (int pass = 0; pass < npass; ++pass) {
        const float* A = (DUAL && pass) ? A1p : A0;
        const unsigned short* WT = (DUAL && pass) ? W1Tp : W0T;
        for (int k0 = 0; k0 < K; k0 += 64) {
            {   // stage A: fp32 -> bf16 via v_cvt_pk_bf16_f32 (8 instr)
                const float* ap = A + (size_t)(m0 + sr) * K + k0 + sk;
                float4 v0 = *(const float4*)(ap);
                float4 v1 = *(const float4*)(ap + 4);
                float4 v2 = *(const float4*)(ap + 8);
                float4 v3 = *(const float4*)(ap + 12);
                uint4 pa, pb;
                pa.x = cvt_pk_bf16(v0.x, v0.y); pa.y = cvt_pk_bf16(v0.z, v0.w);
                pa.z = cvt_pk_bf16(v1.x, v1.y); pa.w = cvt_pk_bf16(v1.z, v1.w);
                pb.x = cvt_pk_bf16(v2.x, v2.y); pb.y = cvt_pk_bf16(v2.z, v2.w);
                pb.z = cvt_pk_bf16(v3.x, v3.y); pb.w = cvt_pk_bf16(v3.z, v3.w);
                *(uint4*)&As[sr * 72 + sk]     = pa;
                *(uint4*)&As[sr * 72 + sk + 8] = pb;
            }
            {   // stage B: straight bf16 copy from WT (zero-fill n >= N)
                const int nn = n0 + sr;
                if (nn < N) {
                    const unsigned short* wp = WT + (size_t)nn * K + k0 + sk;
                    uint4 w0 = *(const uint4*)(wp);
                    uint4 w1 = *(const uint4*)(wp + 8);
                    *(uint4*)&Bs[sr * 72 + sk]     = w0;
                    *(uint4*)&Bs[sr * 72 + sk + 8] = w1;
                } else {
                    uint4 z = make_uint4(0, 0, 0, 0);
                    *(uint4*)&Bs[sr * 72 + sk]     = z;
                    *(uint4*)&Bs[sr * 72 + sk + 8] = z;
                }
            }
            __syncthreads();
#pragma unroll
            for (int ks = 0; ks < 2; ++ks) {
                s16x8 a0 = *(const s16x8*)&As[(wr + fr     ) * 72 + ks * 32 + fk];
                s16x8 a1 = *(const s16x8*)&As[(wr + 16 + fr) * 72 + ks * 32 + fk];
                s16x8 b0 = *(const s16x8*)&Bs[(wc + fr     ) * 72 + ks * 32 + fk];
                s16x8 b1 = *(const s16x8*)&Bs[(wc + 16 + fr) * 72 + ks * 32 + fk];
                acc[0][0] = __builtin_amdgcn_mfma_f32_16x16x32_bf16(a0, b0, acc[0][0], 0, 0, 0);
                acc[0][1] = __builtin_amdgcn_mfma_f32_16x16x32_bf16(a0, b1, acc[0][1], 0, 0, 0);
                acc[1][0] = __builtin_amdgcn_mfma_f32_16x16x32_bf16(a1, b0, acc[1][0], 0, 0, 0);
                acc[1][1] = __builtin_amdgcn_mfma_f32_16x16x32_bf16(a1, b1, acc[1][1], 0, 0, 0);
            }
            __syncthreads();
        }
    }

    // ---- epilogue: C/D layout col=lane&15, row=(lane>>4)*4+reg ----
    const int orow = (l >> 4) * 4;
    float cs[2] = {0.f, 0.f}, cq[2] = {0.f, 0.f};
#pragma unroll
    for (int mt = 0; mt < 2; ++mt) {
#pragma unroll
        for (int nt = 0; nt < 2; ++nt) {
            const int cg = n0 + wc + nt * 16 + fr;
            if (cg < N) {
                const float bv = bias ? bias[cg] : 0.f;
#pragma unroll
                for (int r = 0; r < 4; ++r) {
                    const int rg = m0 + wr + mt * 16 + orow + r;
                    float v = acc[mt][nt][r] + bv;
                    if (resid) v += resid[(size_t)rg * ldr + cg];
                    if (ACT == 1)
                        v = 0.5f * v * (1.f + erff(v * 0.7071067811865475f));
                    outp[(size_t)rg * ldo + cg] = v;
                    if (STAT) { cs[nt] += v; cq[nt] += v * v; }
                }
            }
        }
    }
    if (STAT) {
        if (tid < 64) { sB[0][tid] = 0.f; sB[1][tid] = 0.f; }
        __syncthreads();
#pragma unroll
        for (int nt = 0; nt < 2; ++nt) {
            atomicAdd(&sB[0][wc + nt * 16 + fr], cs[nt]);
            atomicAdd(&sB[1][wc + nt * 16 + fr], cq[nt]);
        }
        __syncthreads();
        if (tid < 64 && (n0 + tid) < N) {
            atomicAdd(&sumP[n0 + tid], sB[0][tid]);
            atomicAdd(&sqP[n0 + tid],  sB[1][tid]);
        }
    }
}

// --------------------------- causal conv + SiLU ----------------------------
__global__ __launch_bounds__(256) void k_conv(const float* __restrict__ xz,
                                              const float* __restrict__ cw,
                                              const float* __restrict__ cb,
                                              float* __restrict__ xc)
{
    const int r = blockIdx.x;        // global row
    const int l = r & (GL - 1);      // position within graph
    const int d = threadIdx.x;       // 0..255
    float4 w4 = *(const float4*)&cw[d * 4];
    const float taps[4] = {w4.x, w4.y, w4.z, w4.w};
    float acc = cb[d];
#pragma unroll
    for (int k = 0; k < 4; ++k) {
        int ll = l - 3 + k;
        if (ll >= 0) acc += xz[(size_t)(r - 3 + k) * 512 + d] * taps[k];
    }
    float s = 1.f / (1.f + __expf(-acc));
    xc[(size_t)r * 256 + d] = acc * s;
}

// ---------------- dt = softplus(proj[:,:8] @ dt_W + dt_b); B,C slices ------
__global__ __launch_bounds__(256) void k_dtbc(const float* __restrict__ proj,
                                              const float* __restrict__ dt_W,
                                              const float* __restrict__ dt_b,
                                              float* __restrict__ dtb,
                                              float* __restrict__ Bc,
                                              float* __restrict__ Cc)
{
    __shared__ float dtWS[8 * 256];
    __shared__ float dt_bS[256];
    __shared__ float projS[32 * 8];
    const int tid = threadIdx.x;
    const int r0 = blockIdx.x * 32;
    for (int i = tid; i < 2048; i += 256) dtWS[i] = dt_W[i];
    dt_bS[tid] = dt_b[tid];
    projS[tid] = proj[(size_t)(r0 + (tid >> 3)) * 40 + (tid & 7)];
    __syncthreads();

    const int c = tid;
    for (int rr = 0; rr < 32; ++rr) {
        float acc = dt_bS[c];
        const float* pr = &projS[rr * 8];
#pragma unroll
        for (int q = 0; q < 8; ++q) acc += pr[q] * dtWS[q * 256 + c];
        float sp = fmaxf(acc, 0.f) + log1pf(__expf(-fabsf(acc)));
        dtb[(size_t)(r0 + rr) * 256 + c] = sp;
    }
    // B = proj[:, 8:24], C = proj[:, 24:40]
    for (int e = tid; e < 1024; e += 256) {
        int rr = e >> 5, cc = e & 31;
        float v = proj[(size_t)(r0 + rr) * 40 + 8 + cc];
        if (cc < 16) Bc[(size_t)(r0 + rr) * 16 + cc] = v;
        else         Cc[(size_t)(r0 + rr) * 16 + cc - 16] = v;
    }
}

// ---------------- 8-lane-group sum via DPP (zero DS-pipe ops) ---------------
__device__ __forceinline__ float dpp_add8(float x)
{
    float y = x;
    int t;
    // quad_perm [1,0,3,2] : xor 1
    t = __builtin_amdgcn_update_dpp(0, __float_as_int(y), 0xB1, 0xF, 0xF, true);
    y += __int_as_float(t);
    // quad_perm [2,3,0,1] : xor 2
    t = __builtin_amdgcn_update_dpp(0, __float_as_int(y), 0x4E, 0xF, 0xF, true);
    y += __int_as_float(t);
    // row_half_mirror : pairs the two quads within each 8-lane half
    t = __builtin_amdgcn_update_dpp(0, __float_as_int(y), 0x141, 0xF, 0xF, true);
    y += __int_as_float(t);
    return y;
}

// ------------------------------ selective scan -----------------------------
// Block = (g, dblk64): 64 d-channels, 512 thr = 8 waves; 256 blocks = 1/CU,
// 2 waves/SIMD. Wave = 8 d x 8 sp-lanes; each lane holds states {2sp, 2sp+1}
// in registers. Per 32-step chunk (double-buffered transposed LDS):
//   dtT[64][36] (t-quads XOR-swizzled by d&7) | xcT[64][36] | BT[16][36] | CT[16][36]
// 8 sp-lanes of a d broadcast-read the same dt/xc address. y-reduce = 3 DPP
// adds; per-step result captured into registers via cndmask (lane sp keeps
// t = 8k+sp), staged to ygL at chunk end, written out coalesced with silu(z)
// from registers (z prefetched a chunk ahead; never in LDS).
// NOTE: yg aliases dtb - chunk c+1's dtb rows are prefetched to regs before
// chunk c's yg writeout; blocks touch disjoint (g, d-slice) columns.
__global__ __launch_bounds__(512) void k_scan(const float* __restrict__ dtb,
                                              const float* __restrict__ xcb,
                                              const float* __restrict__ xzb,
                                              const float* __restrict__ Bb,
                                              const float* __restrict__ Cb,
                                              const float* __restrict__ A_log,
                                              const float* __restrict__ Dp,
                                              float* __restrict__ yg)
{
    // floats: buf0 [0,5760) | buf1 [5760,11520) | ygL [11520, 11520+32*68)
    __shared__ __align__(16) float lds[2 * 5760 + 32 * 68];

    const int g    = blockIdx.x >> 2;
    const int dblk = blockIdx.x & 3;
    const int tid  = threadIdx.x;
    const int w    = tid >> 6, lane = tid & 63;
    const int dl   = w * 8 + (lane >> 3);    // local d 0..63
    const int sp   = lane & 7;               // state-pair index
    const int d0   = dblk * 64;
    const int d    = d0 + dl;
    const size_t rbase = (size_t)g * GL;

    // staging coords
    const int sdd = tid & 63, stq = tid >> 6;          // dt/xc: d-col, t-quad
    const int sbt = tid >> 4, sbi = tid & 15;          // B/C, z, writeout

    const float aA0 = -__expf(A_log[d * 16 + 2 * sp]);
    const float aA1 = -__expf(A_log[d * 16 + 2 * sp + 1]);
    const float Dpd = Dp[d];
    float h0 = 0.f, h1 = 0.f;

    float4 r_dt, r_xc, r_z, z_cur;
    float r_B, r_C;

    // ---- prologue: load chunk 0 into registers ----
    {
        const size_t r0 = rbase;
#pragma unroll
        for (int j = 0; j < 4; ++j) {
            ((float*)&r_dt)[j] = dtb[(r0 + stq * 4 + j) * 256 + d0 + sdd];
            ((float*)&r_xc)[j] = xcb[(r0 + stq * 4 + j) * 256 + d0 + sdd];
        }
        r_z = *(const float4*)&xzb[(r0 + sbt) * 512 + 256 + d0 + sbi * 4];
        r_B = Bb[(r0 + sbt) * 16 + sbi];
        r_C = Cb[(r0 + sbt) * 16 + sbi];
    }

    float* ygL = lds + 2 * 5760;

    for (int c = 0; c < NCH; ++c) {
        float* buf = lds + (c & 1) * 5760;
        // ---- commit staged registers to LDS (transposed, swizzled quads) --
        const int tqs = (stq ^ (sdd & 7)) << 2;
        *(float4*)&buf[sdd * 36 + tqs]        = r_dt;
        *(float4*)&buf[2304 + sdd * 36 + tqs] = r_xc;
        buf[4608 + sbi * 36 + sbt] = r_B;
        buf[5184 + sbi * 36 + sbt] = r_C;
        z_cur = r_z;
        __syncthreads();

        // ---- prefetch chunk c+1 (lands during the 32 steps below) ----
        if (c + 1 < NCH) {
            const size_t r0 = rbase + (size_t)(c + 1) * SCH;
#pragma unroll
            for (int j = 0; j < 4; ++j) {
                ((float*)&r_dt)[j] = dtb[(r0 + stq * 4 + j) * 256 + d0 + sdd];
                ((float*)&r_xc)[j] = xcb[(r0 + stq * 4 + j) * 256 + d0 + sdd];
            }
            r_z = *(const float4*)&xzb[(r0 + sbt) * 512 + 256 + d0 + sbi * 4];
            r_B = Bb[(r0 + sbt) * 16 + sbi];
            r_C = Cb[(r0 + sbt) * 16 + sbi];
        }

        // ---- 32 scan steps from LDS ----
        const int dsw = dl & 7;
        const float* pdt = buf + dl * 36;
        const float* pxc = buf + 2304 + dl * 36;
        const float* pB0 = buf + 4608 + (2 * sp) * 36;
        const float* pB1 = buf + 4608 + (2 * sp + 1) * 36;
        const float* pC0 = buf + 5184 + (2 * sp) * 36;
        const float* pC1 = buf + 5184 + (2 * sp + 1) * 36;
        float yk[4] = {0.f, 0.f, 0.f, 0.f};
#pragma unroll
        for (int t4 = 0; t4 < 8; ++t4) {
            const int tq = (t4 ^ dsw) << 2;
            const float4 dt4 = *(const float4*)&pdt[tq];
            const float4 xc4 = *(const float4*)&pxc[tq];
            const float4 B04 = *(const float4*)&pB0[t4 * 4];
            const float4 B14 = *(const float4*)&pB1[t4 * 4];
            const float4 C04 = *(const float4*)&pC0[t4 * 4];
            const float4 C14 = *(const float4*)&pC1[t4 * 4];
#define SSTEP(J)                                                            \
            {                                                               \
                const float dt = ((const float*)&dt4)[J];                   \
                const float xc = ((const float*)&xc4)[J];                   \
                const float dtx = dt * xc;                                  \
                h0 = h0 * __expf(dt * aA0) + dtx * ((const float*)&B04)[J]; \
                h1 = h1 * __expf(dt * aA1) + dtx * ((const float*)&B14)[J]; \
                float yv = h0 * ((const float*)&C04)[J]                     \
                         + h1 * ((const float*)&C14)[J];                    \
                yv = dpp_add8(yv);                                          \
                yv = fmaf(xc, Dpd, yv);                                     \
                const int tt = t4 * 4 + (J);                                \
                yk[t4 >> 1] = (sp == (tt & 7)) ? yv : yk[t4 >> 1];          \
            }
            SSTEP(0) SSTEP(1) SSTEP(2) SSTEP(3)
#undef SSTEP
        }
        // stage captured y to LDS: lane sp holds t = 8k+sp for its d
#pragma unroll
        for (int k = 0; k < 4; ++k)
            ygL[(k * 8 + sp) * 68 + dl] = yk[k];
        __syncthreads();

        // ---- coalesced writeout with silu(z) from registers ----
        {
            const size_t rr0 = rbase + (size_t)c * SCH;
            float4 y4 = *(const float4*)&ygL[sbt * 68 + sbi * 4];
            float4 o;
            o.x = y4.x * (z_cur.x / (1.f + __expf(-z_cur.x)));
            o.y = y4.y * (z_cur.y / (1.f + __expf(-z_cur.y)));
            o.z = y4.z * (z_cur.z / (1.f + __expf(-z_cur.z)));
            o.w = y4.w * (z_cur.w / (1.f + __expf(-z_cur.w)));
            *(float4*)&yg[(rr0 + sbt) * 256 + d0 + sbi * 4] = o;
        }
    }
}

// -------------------------- BN finalize / fold / add -----------------------
__global__ __launch_bounds__(256) void k_fin12(const float* __restrict__ st,
                                               const float* g1, const float* be1,
                                               const float* g2, const float* be2,
                                               float* __restrict__ ab)
{
    const int tid = threadIdx.x;
    const float inv = 1.f / 32768.f;
    if (tid < 128) {
        float m = st[tid] * inv, v = st[128 + tid] * inv - m * m;
        float a = g1[tid] * rsqrtf(v + 1e-5f);
        ab[tid] = a; ab[256 + tid] = be1[tid] - m * a;
    } else {
        int c = tid - 128;
        float m = st[256 + c] * inv, v = st[384 + c] * inv - m * m;
        float a = g2[c] * rsqrtf(v + 1e-5f);
        ab[512 + c] = a; ab[768 + c] = be2[c] - m * a;
    }
}

__global__ __launch_bounds__(256) void k_add(const float* __restrict__ h1p,
                                             const float* __restrict__ p2,
                                             const float* __restrict__ ab,
                                             float* __restrict__ outp,
                                             float* __restrict__ sumP,
                                             float* __restrict__ sqP)
{
    const int c = threadIdx.x & 127, half = threadIdx.x >> 7;
    const int rbase = blockIdx.x * 64 + half * 32;
    const float a1 = ab[c], b1 = ab[256 + c], a2 = ab[512 + c], b2 = ab[768 + c];
    float s = 0.f, q = 0.f;
    for (int i = 0; i < 32; ++i) {
        size_t idx = (size_t)(rbase + i) * 128 + c;
        float v = h1p[idx] * a1 + b1 + p2[idx] * a2 + b2;
        outp[idx] = v; s += v; q += v * v;
    }
    __shared__ float sh[2][2][128];
    sh[0][half][c] = s; sh[1][half][c] = q;
    __syncthreads();
    if (threadIdx.x < 128) {
        atomicAdd(&sumP[c], sh[0][0][c] + sh[0][1][c]);
        atomicAdd(&sqP[c],  sh[1][0][c] + sh[1][1][c]);
    }
}

// fold1: emits W1eT bf16 [256][128] + b1e fp32
__global__ __launch_bounds__(256) void k_fin3_fold1(
    const float* __restrict__ sumP, const float* __restrict__ sqP,
    const float* __restrict__ gam, const float* __restrict__ bet,
    const float* __restrict__ W1, const float* __restrict__ b1in,
    unsigned short* __restrict__ W1eT, float* __restrict__ b1e)
{
    __shared__ float aS[128], bS[128];
    const int tid = threadIdx.x;
    const float inv = 1.f / 32768.f;
    if (tid < 128) {
        float m = sumP[tid] * inv, v = sqP[tid] * inv - m * m;
        float a = gam[tid] * rsqrtf(v + 1e-5f);
        aS[tid] = a; bS[tid] = bet[tid] - m * a;
    }
    __syncthreads();
    const int n = tid;                       // output column 0..255
    float acc = b1in[n];
    for (int k = 0; k < 128; ++k) {
        float wv = W1[k * 256 + n];
        W1eT[n * 128 + k] = f2bf(aS[k] * wv);
        acc += bS[k] * wv;
    }
    b1e[n] = acc;
}

// fold2: emits W2eT bf16 [128][256] + b2e fp32
__global__ __launch_bounds__(256) void k_fin4_fold2(
    const float* __restrict__ sumP, const float* __restrict__ sqP,
    const float* __restrict__ gam, const float* __restrict__ bet,
    const float* __restrict__ W2, const float* __restrict__ b2in,
    unsigned short* __restrict__ W2eT, float* __restrict__ b2e)
{
    __shared__ float aS[256], bS[256];
    const int tid = threadIdx.x;
    const float inv = 1.f / 32768.f;
    {
        float m = sumP[tid] * inv, v = sqP[tid] * inv - m * m;
        float a = gam[tid] * rsqrtf(v + 1e-5f);
        aS[tid] = a; bS[tid] = bet[tid] - m * a;
    }
    __syncthreads();
    if (tid < 128) {
        const int n = tid;                   // output column 0..127
        float acc = b2in[n];
        for (int k = 0; k < 256; ++k) {
            float wv = W2[k * 128 + n];
            W2eT[n * 256 + k] = f2bf(aS[k] * wv);
            acc += bS[k] * wv;
        }
        b2e[n] = acc;
    }
}

__global__ __launch_bounds__(128) void k_fin5(const float* __restrict__ sumP,
                                              const float* __restrict__ sqP,
                                              const float* gam, const float* bet,
                                              float* __restrict__ ab)
{
    const int tid = threadIdx.x;
    if (tid < 128) {
        const float inv = 1.f / 32768.f;
        float m = sumP[tid] * inv, v = sqP[tid] * inv - m * m;
        float a = gam[tid] * rsqrtf(v + 1e-5f);
        ab[2048 + tid] = a; ab[2304 + tid] = bet[tid] - m * a;
    }
}

__global__ __launch_bounds__(256) void k_bn3(const float* __restrict__ out2,
                                             const float* __restrict__ ab,
                                             float* __restrict__ dout)
{
    size_t i4 = ((size_t)blockIdx.x * 256 + threadIdx.x) * 4;
    int c = (int)(i4 & 127);
    float4 v = *(const float4*)&out2[i4];
    float4 a = *(const float4*)&ab[2048 + c];
    float4 b = *(const float4*)&ab[2304 + c];
    v.x = v.x * a.x + b.x; v.y = v.y * a.y + b.y;
    v.z = v.z * a.z + b.z; v.w = v.w * a.w + b.w;
    *(float4*)&dout[i4] = v;
}

// ------------------------------- launch ------------------------------------
extern "C" void kernel_launch(void* const* d_in, const int* in_sizes, int n_in,
                              void* d_out, int out_size, void* d_ws, size_t ws_size,
                              hipStream_t stream)
{
    (void)in_sizes; (void)n_in; (void)out_size; (void)ws_size;
    const float* x      = (const float*)d_in[0];
    const int*   ei     = (const int*)d_in[1];
    // d_in[2] = batch (unused: equal-size sorted graphs == reshape)
    const float* W_root = (const float*)d_in[3];
    const float* W_rel  = (const float*)d_in[4];
    const float* b_rel  = (const float*)d_in[5];
    const float* n1_g = (const float*)d_in[6],  *n1_b = (const float*)d_in[7];
    const float* n2_g = (const float*)d_in[8],  *n2_b = (const float*)d_in[9];
    const float* n3_g = (const float*)d_in[10], *n3_b = (const float*)d_in[11];
    const float* m1_g = (const float*)d_in[12], *m1_b = (const float*)d_in[13];
    const float* W1   = (const float*)d_in[14], *b1   = (const float*)d_in[15];
    const float* m2_g = (const float*)d_in[16], *m2_b = (const float*)d_in[17];
    const float* W2   = (const float*)d_in[18], *b2   = (const float*)d_in[19];
    const float* in_W   = (const float*)d_in[20];
    const float* conv_w = (const float*)d_in[21], *conv_b = (const float*)d_in[22];
    const float* xproj_W= (const float*)d_in[23];
    const float* dt_W   = (const float*)d_in[24], *dt_b = (const float*)d_in[25];
    const float* A_log  = (const float*)d_in[26], *Dp   = (const float*)d_in[27];
    const float* out_W  = (const float*)d_in[28];

    float* ws = (float*)d_ws;
    // small region
    float* st  = ws;             // 2048 used (S1..S5 sums/sumsqs)
    float* ab  = ws + 4096;      // a/b affine params
    float* b1e = ws + 8192;      // 256
    float* b2e = ws + 8448;      // 128
    // bf16 transposed weights (shorts)
    unsigned short* wsh   = (unsigned short*)(ws + 8704);
    unsigned short* WrelT  = wsh;            // 128x128 = 16384
    unsigned short* WrootT = wsh + 16384;    // 16384
    unsigned short* inWT   = wsh + 32768;    // 512x128 = 65536
    unsigned short* xprojT = wsh + 98304;    // 40x256  = 10240
    unsigned short* outWT  = wsh + 108544;   // 128x256 = 32768
    unsigned short* W1eT   = wsh + 141312;   // 256x128 = 32768
    unsigned short* W2eT   = wsh + 174080;   // 128x256 = 32768 (end 206848)
    // big buffers
    float* big  = ws + 112640;
    float* agg  = big;                    // 4194304 (later reused as p2)
    float* p2   = agg;
    float* h1p  = big + 4194304;          // 4194304
    float* xz   = big + 8388608;          // 16777216 (later: g + out2)
    float* gbuf = xz;
    float* out2 = xz + 8388608;
    float* xc   = big + 25165824;         // 8388608
    float* proj = big + 33554432;         // 1310720
    float* dtb  = big + 34865152;         // 8388608 (yg aliases dtb)
    float* ygb  = dtb;
    float* Bc   = big + 43253760;         // 524288
    float* Cc   = big + 43778048;         // 524288
    float* outb = big + 44302336;         // 4194304

    // CSR scratch lives in the h1p region (dead until the h1 GEMM writes it)
    int* ideg   = (int*)h1p;              // 32768
    int* ibase  = ideg + 32768;           // 32769
    int* icur   = ideg + 65552;           // 32768 (16B-aligned)
    int* isrcs  = ideg + 98320;           // 524288

    hipMemsetAsync(st, 0, 2048 * sizeof(float), stream);
    hipMemsetAsync(ideg, 0, 32768 * sizeof(int), stream);

    // ---- weight prep (bf16 transposes; independent of everything else) ----
    k_prepw<<<64, 256, 0, stream>>>(W_rel,   WrelT,  7, 16384);
    k_prepw<<<64, 256, 0, stream>>>(W_root,  WrootT, 7, 16384);
    k_prepw<<<256, 256, 0, stream>>>(in_W,   inWT,   7, 65536);
    k_prepw<<<40, 256, 0, stream>>>(xproj_W, xprojT, 8, 10240);
    k_prepw<<<128, 256, 0, stream>>>(out_W,  outWT,  8, 32768);

    // ---- CSR build + gather ----
    k_hist<<<512, 256, 0, stream>>>(ei, ideg);
    k_scanidx<<<1, 1024, 0, stream>>>(ideg, ibase, icur);
    k_fill<<<512, 256, 0, stream>>>(ei, icur, isrcs);
    k_gather<<<8192, 256, 0, stream>>>(x, ibase, isrcs, agg);

    // h1_pre = agg@W_rel + b_rel + x@W_root + x  [S1]
    gemm_mfma<true, 0, true><<<dim3(512, 2), 256, 0, stream>>>(
        agg, WrelT, x, WrootT, NROWS, 128, 128, 128,
        b_rel, x, 128, h1p, st + 0, st + 128);
    // xz = x @ in_W
    gemm_mfma<false, 0, false><<<dim3(512, 8), 256, 0, stream>>>(
        x, inWT, nullptr, nullptr, NROWS, 512, 128, 512,
        nullptr, nullptr, 0, xz, nullptr, nullptr);
    k_conv<<<32768, 256, 0, stream>>>(xz, conv_w, conv_b, xc);
    // proj = xc @ xproj_W (N=40)
    gemm_mfma<false, 0, false><<<dim3(512, 1), 256, 0, stream>>>(
        xc, xprojT, nullptr, nullptr, NROWS, 40, 256, 40,
        nullptr, nullptr, 0, proj, nullptr, nullptr);
    k_dtbc<<<1024, 256, 0, stream>>>(proj, dt_W, dt_b, dtb, Bc, Cc);
    k_scan<<<256, 512, 0, stream>>>(dtb, xc, xz, Bc, Cc, A_log, Dp, ygb);
    // p2 = yg @ out_W + x  [S2]
    gemm_mfma<false, 0, true><<<dim3(512, 2), 256, 0, stream>>>(
        ygb, outWT, nullptr, nullptr, NROWS, 128, 256, 128,
        nullptr, x, 128, p2, st + 256, st + 384);
    k_fin12<<<1, 256, 0, stream>>>(st, n1_g, n1_b, n2_g, n2_b, ab);
    // out = BN1(h1_pre) + BN2(p2)  [S3]
    k_add<<<512, 256, 0, stream>>>(h1p, p2, ab, outb, st + 512, st + 640);
    k_fin3_fold1<<<1, 256, 0, stream>>>(st + 512, st + 640, m1_g, m1_b, W1, b1, W1eT, b1e);
    // g = gelu(out @ W1e + b1e)  [S4]
    gemm_mfma<false, 1, true><<<dim3(512, 4), 256, 0, stream>>>(
        outb, W1eT, nullptr, nullptr, NROWS, 256, 128, 256,
        b1e, nullptr, 0, gbuf, st + 768, st + 1024);
    k_fin4_fold2<<<1, 256, 0, stream>>>(st + 768, st + 1024, m2_g, m2_b, W2, b2, W2eT, b2e);
    // out2 = g @ W2e + b2e + out  [S5]
    gemm_mfma<false, 0, true><<<dim3(512, 2), 256, 0, stream>>>(
        gbuf, W2eT, nullptr, nullptr, NROWS, 128, 256, 128,
        b2e, outb, 128, out2, st + 1280, st + 1408);
    k_fin5<<<1, 128, 0, stream>>>(st + 1280, st + 1408, n3_g, n3_b, ab);
    k_bn3<<<4096, 256, 0, stream>>>(out2, ab, (float*)d_out);
}

// Round 8
// 425.821 us; speedup vs baseline: 1.6888x; 1.0991x over previous
//
#include <hip/hip_runtime.h>

// ---------------------------------------------------------------------------
// GraphMambaConv: N=32768 nodes, C=128, G=64 graphs x L=512, E=524288 edges,
// D_INNER=256, D_STATE=16, DT_RANK=8, D_CONV=4.
//
// Round 8:
//  - k_scan: REMOVE the XOR swizzle (it created 2x write serialization; the
//    plain [d][36] layout is conflict-free) + fold log2e into aA so the decay
//    is one raw v_exp_f32 (2^x) instead of mul+exp.
//  - kill 1-block serial kernels: fin12 fused into k_add (per-thread param
//    calc), fin5 fused into k_bn3, fold1/fold2 parallelized block-per-column,
//    5x k_prepw merged into one launch.
// ---------------------------------------------------------------------------

#define NROWS 32768
#define CDIM  128
#define EDGES 524288
#define GL    512
#define SCH   32          // scan chunk (timesteps)
#define NCH   (GL / SCH)  // 16 chunks

typedef short s16x8 __attribute__((ext_vector_type(8)));
typedef float f32x4 __attribute__((ext_vector_type(4)));

__device__ __forceinline__ unsigned short f2bf(float f)
{
    unsigned u = __float_as_uint(f);
    u += 0x7FFF + ((u >> 16) & 1);          // RNE
    return (unsigned short)(u >> 16);
}

__device__ __forceinline__ unsigned cvt_pk_bf16(float lo, float hi)
{
    unsigned r;
    asm("v_cvt_pk_bf16_f32 %0, %1, %2" : "=v"(r) : "v"(lo), "v"(hi));
    return r;
}

__device__ __forceinline__ float exp2_fast(float x)
{
    float r;
    asm("v_exp_f32 %0, %1" : "=v"(r) : "v"(x));   // v_exp_f32 computes 2^x
    return r;
}

// ------------------------- CSR build: histogram ----------------------------
__global__ __launch_bounds__(256) void k_hist(const int* __restrict__ ei,
                                              int* __restrict__ deg)
{
    const int e = blockIdx.x * 1024 + threadIdx.x * 4;
    const int4 d4 = *(const int4*)&ei[EDGES + e];
    atomicAdd(&deg[d4.x], 1);
    atomicAdd(&deg[d4.y], 1);
    atomicAdd(&deg[d4.z], 1);
    atomicAdd(&deg[d4.w], 1);
}

// ---------------- CSR build: exclusive prefix scan (1 block) ---------------
__global__ __launch_bounds__(1024) void k_scanidx(const int* __restrict__ deg,
                                                  int* __restrict__ base,
                                                  int* __restrict__ cursor)
{
    __shared__ int ps[1024];
    const int tid = threadIdx.x;
    int loc[32];
    int s = 0;
#pragma unroll
    for (int i = 0; i < 32; ++i) { loc[i] = deg[tid * 32 + i]; s += loc[i]; }
    ps[tid] = s;
    __syncthreads();
    for (int off = 1; off < 1024; off <<= 1) {
        int v = (tid >= off) ? ps[tid - off] : 0;
        __syncthreads();
        ps[tid] += v;
        __syncthreads();
    }
    int run = tid ? ps[tid - 1] : 0;
#pragma unroll
    for (int i = 0; i < 32; ++i) {
        base[tid * 32 + i] = run;
        cursor[tid * 32 + i] = run;
        run += loc[i];
    }
    if (tid == 0) base[32768] = EDGES;
}

// ------------------------- CSR build: fill src lists -----------------------
__global__ __launch_bounds__(256) void k_fill(const int* __restrict__ ei,
                                              int* __restrict__ cursor,
                                              int* __restrict__ srcs)
{
    const int e = blockIdx.x * 1024 + threadIdx.x * 4;
    const int4 s4 = *(const int4*)&ei[e];
    const int4 d4 = *(const int4*)&ei[EDGES + e];
    int p;
    p = atomicAdd(&cursor[d4.x], 1); srcs[p] = s4.x;
    p = atomicAdd(&cursor[d4.y], 1); srcs[p] = s4.y;
    p = atomicAdd(&cursor[d4.z], 1); srcs[p] = s4.z;
    p = atomicAdd(&cursor[d4.w], 1); srcs[p] = s4.w;
}

// ------------------------- gather: one wave per node ------------------------
__global__ __launch_bounds__(256) void k_gather(const float* __restrict__ x,
                                                const int* __restrict__ base,
                                                const int* __restrict__ srcs,
                                                float* __restrict__ agg)
{
    const int node = blockIdx.x * 4 + (threadIdx.x >> 6);
    const int lane = threadIdx.x & 63;
    const int b0 = base[node], b1 = base[node + 1];
    float2 a0 = make_float2(0.f, 0.f), a1 = make_float2(0.f, 0.f);
    int i = b0;
    for (; i + 2 <= b1; i += 2) {
        const int s0 = srcs[i], s1 = srcs[i + 1];
        const float2 v0 = *(const float2*)&x[(size_t)s0 * 128 + lane * 2];
        const float2 v1 = *(const float2*)&x[(size_t)s1 * 128 + lane * 2];
        a0.x += v0.x; a0.y += v0.y;
        a1.x += v1.x; a1.y += v1.y;
    }
    if (i < b1) {
        const int s0 = srcs[i];
        const float2 v0 = *(const float2*)&x[(size_t)s0 * 128 + lane * 2];
        a0.x += v0.x; a0.y += v0.y;
    }
    a0.x += a1.x; a0.y += a1.y;
    *(float2*)&agg[(size_t)node * 128 + lane * 2] = a0;
}

// ---- merged weight prep: 5 transposes (bf16) in one launch, 552 blocks ----
__global__ __launch_bounds__(256) void k_prepw5(
    const float* __restrict__ Wa, unsigned short* __restrict__ Ta,
    const float* __restrict__ Wb, unsigned short* __restrict__ Tb,
    const float* __restrict__ Wc, unsigned short* __restrict__ Tc,
    const float* __restrict__ Wd, unsigned short* __restrict__ Td,
    const float* __restrict__ We, unsigned short* __restrict__ Te)
{
    const int idx = blockIdx.x * 256 + threadIdx.x;
    const float* W; unsigned short* T; int rel, ks, N;
    if (idx < 16384)       { W = Wa; T = Ta; rel = idx;          ks = 7; N = 128; }
    else if (idx < 32768)  { W = Wb; T = Tb; rel = idx - 16384;  ks = 7; N = 128; }
    else if (idx < 98304)  { W = Wc; T = Tc; rel = idx - 32768;  ks = 7; N = 512; }
    else if (idx < 108544) { W = Wd; T = Td; rel = idx - 98304;  ks = 8; N = 40;  }
    else                   { W = We; T = Te; rel = idx - 108544; ks = 8; N = 128; }
    const int K = 1 << ks;
    const int n = rel >> ks, k = rel & (K - 1);
    T[rel] = f2bf(W[(size_t)k * N + n]);
}

// ------------------------- MFMA GEMM (bf16 in, fp32 acc) --------------------
// out = epi( A0@W0 [+ A1@W1] [+bias] [+resid] ), optional column stats.
// A: MxK fp32 row-major. WT: NxK bf16 row-major (pre-transposed weights).
// Tile 64x64, BK=64, 4 waves x (2x2 mfma_f32_16x16x32_bf16).
template<bool DUAL, int ACT, bool STAT>
__global__ __launch_bounds__(256)
void gemm_mfma(const float* __restrict__ A0, const unsigned short* __restrict__ W0T,
               const float* __restrict__ A1p, const unsigned short* __restrict__ W1Tp,
               int M, int N, int K, int ldo,
               const float* __restrict__ bias,
               const float* __restrict__ resid, int ldr,
               float* __restrict__ outp,
               float* __restrict__ sumP, float* __restrict__ sqP)
{
    __shared__ __align__(16) unsigned short As[64 * 72];  // [m][k], pad 8
    __shared__ __align__(16) unsigned short Bs[64 * 72];  // [n][k], pad 8
    __shared__ float sB[2][64];

    const int tid = threadIdx.x;
    const int m0 = blockIdx.x * 64;
    const int n0 = blockIdx.y * 64;

    const int sr = tid >> 2;             // staging row 0..63
    const int sk = (tid & 3) * 16;       // staging k base

    const int w  = tid >> 6, l = tid & 63;
    const int wr = (w >> 1) * 32, wc = (w & 1) * 32;
    const int fr = l & 15;               // frag row/col
    const int fk = (l >> 4) * 8;         // frag k base

    f32x4 acc[2][2];
#pragma unroll
    for (int i = 0; i < 2; ++i)
#pragma unroll
        for (int j = 0; j < 2; ++j) acc[i][j] = (f32x4){0.f, 0.f, 0.f, 0.f};

    const int npass = DUAL ? 2 : 1;
    for (int pass = 0; pass < npass; ++pass) {
        const float* A = (DUAL && pass) ? A1p : A0;
        const unsigned short* WT = (DUAL && pass) ? W1Tp : W0T;
        for (int k0 = 0; k0 < K; k0 += 64) {
            {   // stage A: fp32 -> bf16 via v_cvt_pk_bf16_f32 (8 instr)
                const float* ap = A + (size_t)(m0 + sr) * K + k0 + sk;
                float4 v0 = *(const float4*)(ap);
                float4 v1 = *(const float4*)(ap + 4);
                float4 v2 = *(const float4*)(ap + 8);
                float4 v3 = *(const float4*)(ap + 12);
                uint4 pa, pb;
                pa.x = cvt_pk_bf16(v0.x, v0.y); pa.y = cvt_pk_bf16(v0.z, v0.w);
                pa.z = cvt_pk_bf16(v1.x, v1.y); pa.w = cvt_pk_bf16(v1.z, v1.w);
                pb.x = cvt_pk_bf16(v2.x, v2.y); pb.y = cvt_pk_bf16(v2.z, v2.w);
                pb.z = cvt_pk_bf16(v3.x, v3.y); pb.w = cvt_pk_bf16(v3.z, v3.w);
                *(uint4*)&As[sr * 72 + sk]     = pa;
                *(uint4*)&As[sr * 72 + sk + 8] = pb;
            }
            {   // stage B: straight bf16 copy from WT (zero-fill n >= N)
                const int nn = n0 + sr;
                if (nn < N) {
                    const unsigned short* wp = WT + (size_t)nn * K + k0 + sk;
                    uint4 w0 = *(const uint4*)(wp);
                    uint4 w1 = *(const uint4*)(wp + 8);
                    *(uint4*)&Bs[sr * 72 + sk]     = w0;
                    *(uint4*)&Bs[sr * 72 + sk + 8] = w1;
                } else {
                    uint4 z = make_uint4(0, 0, 0, 0);
                    *(uint4*)&Bs[sr * 72 + sk]     = z;
                    *(uint4*)&Bs[sr * 72 + sk + 8] = z;
                }
            }
            __syncthreads();
#pragma unroll
            for (int ks = 0; ks < 2; ++ks) {
                s16x8 a0 = *(const s16x8*)&As[(wr + fr     ) * 72 + ks * 32 + fk];
                s16x8 a1 = *(const s16x8*)&As[(wr + 16 + fr) * 72 + ks * 32 + fk];
                s16x8 b0 = *(const s16x8*)&Bs[(wc + fr     ) * 72 + ks * 32 + fk];
                s16x8 b1 = *(const s16x8*)&Bs[(wc + 16 + fr) * 72 + ks * 32 + fk];
                acc[0][0] = __builtin_amdgcn_mfma_f32_16x16x32_bf16(a0, b0, acc[0][0], 0, 0, 0);
                acc[0][1] = __builtin_amdgcn_mfma_f32_16x16x32_bf16(a0, b1, acc[0][1], 0, 0, 0);
                acc[1][0] = __builtin_amdgcn_mfma_f32_16x16x32_bf16(a1, b0, acc[1][0], 0, 0, 0);
                acc[1][1] = __builtin_amdgcn_mfma_f32_16x16x32_bf16(a1, b1, acc[1][1], 0, 0, 0);
            }
            __syncthreads();
        }
    }

    // ---- epilogue: C/D layout col=lane&15, row=(lane>>4)*4+reg ----
    const int orow = (l >> 4) * 4;
    float cs[2] = {0.f, 0.f}, cq[2] = {0.f, 0.f};
#pragma unroll
    for (int mt = 0; mt < 2; ++mt) {
#pragma unroll
        for (int nt = 0; nt < 2; ++nt) {
            const int cg = n0 + wc + nt * 16 + fr;
            if (cg < N) {
                const float bv = bias ? bias[cg] : 0.f;
#pragma unroll
                for (int r = 0; r < 4; ++r) {
                    const int rg = m0 + wr + mt * 16 + orow + r;
                    float v = acc[mt][nt][r] + bv;
                    if (resid) v += resid[(size_t)rg * ldr + cg];
                    if (ACT == 1)
                        v = 0.5f * v * (1.f + erff(v * 0.7071067811865475f));
                    outp[(size_t)rg * ldo + cg] = v;
                    if (STAT) { cs[nt] += v; cq[nt] += v * v; }
                }
            }
        }
    }
    if (STAT) {
        if (tid < 64) { sB[0][tid] = 0.f; sB[1][tid] = 0.f; }
        __syncthreads();
#pragma unroll
        for (int nt = 0; nt < 2; ++nt) {
            atomicAdd(&sB[0][wc + nt * 16 + fr], cs[nt]);
            atomicAdd(&sB[1][wc + nt * 16 + fr], cq[nt]);
        }
        __syncthreads();
        if (tid < 64 && (n0 + tid) < N) {
            atomicAdd(&sumP[n0 + tid], sB[0][tid]);
            atomicAdd(&sqP[n0 + tid],  sB[1][tid]);
        }
    }
}

// --------------------------- causal conv + SiLU ----------------------------
__global__ __launch_bounds__(256) void k_conv(const float* __restrict__ xz,
                                              const float* __restrict__ cw,
                                              const float* __restrict__ cb,
                                              float* __restrict__ xc)
{
    const int r = blockIdx.x;        // global row
    const int l = r & (GL - 1);      // position within graph
    const int d = threadIdx.x;       // 0..255
    float4 w4 = *(const float4*)&cw[d * 4];
    const float taps[4] = {w4.x, w4.y, w4.z, w4.w};
    float acc = cb[d];
#pragma unroll
    for (int k = 0; k < 4; ++k) {
        int ll = l - 3 + k;
        if (ll >= 0) acc += xz[(size_t)(r - 3 + k) * 512 + d] * taps[k];
    }
    float s = 1.f / (1.f + __expf(-acc));
    xc[(size_t)r * 256 + d] = acc * s;
}

// ---------------- dt = softplus(proj[:,:8] @ dt_W + dt_b); B,C slices ------
__global__ __launch_bounds__(256) void k_dtbc(const float* __restrict__ proj,
                                              const float* __restrict__ dt_W,
                                              const float* __restrict__ dt_b,
                                              float* __restrict__ dtb,
                                              float* __restrict__ Bc,
                                              float* __restrict__ Cc)
{
    __shared__ float dtWS[8 * 256];
    __shared__ float dt_bS[256];
    __shared__ float projS[32 * 8];
    const int tid = threadIdx.x;
    const int r0 = blockIdx.x * 32;
    for (int i = tid; i < 2048; i += 256) dtWS[i] = dt_W[i];
    dt_bS[tid] = dt_b[tid];
    projS[tid] = proj[(size_t)(r0 + (tid >> 3)) * 40 + (tid & 7)];
    __syncthreads();

    const int c = tid;
    for (int rr = 0; rr < 32; ++rr) {
        float acc = dt_bS[c];
        const float* pr = &projS[rr * 8];
#pragma unroll
        for (int q = 0; q < 8; ++q) acc += pr[q] * dtWS[q * 256 + c];
        float sp = fmaxf(acc, 0.f) + log1pf(__expf(-fabsf(acc)));
        dtb[(size_t)(r0 + rr) * 256 + c] = sp;
    }
    // B = proj[:, 8:24], C = proj[:, 24:40]
    for (int e = tid; e < 1024; e += 256) {
        int rr = e >> 5, cc = e & 31;
        float v = proj[(size_t)(r0 + rr) * 40 + 8 + cc];
        if (cc < 16) Bc[(size_t)(r0 + rr) * 16 + cc] = v;
        else         Cc[(size_t)(r0 + rr) * 16 + cc - 16] = v;
    }
}

// ---------------- 8-lane-group sum via DPP (zero DS-pipe ops) ---------------
__device__ __forceinline__ float dpp_add8(float x)
{
    float y = x;
    int t;
    // quad_perm [1,0,3,2] : xor 1
    t = __builtin_amdgcn_update_dpp(0, __float_as_int(y), 0xB1, 0xF, 0xF, true);
    y += __int_as_float(t);
    // quad_perm [2,3,0,1] : xor 2
    t = __builtin_amdgcn_update_dpp(0, __float_as_int(y), 0x4E, 0xF, 0xF, true);
    y += __int_as_float(t);
    // row_half_mirror : pairs the two quads within each 8-lane half
    t = __builtin_amdgcn_update_dpp(0, __float_as_int(y), 0x141, 0xF, 0xF, true);
    y += __int_as_float(t);
    return y;
}

// ------------------------------ selective scan -----------------------------
// Block = (g, dblk64): 64 d-channels, 512 thr = 8 waves; 256 blocks = 1/CU.
// Wave = 8 d x 8 sp-lanes; each lane holds states {2sp, 2sp+1} in registers.
// Per 32-step chunk (double-buffered transposed LDS, NO swizzle — plain
// [d][36] is conflict-free: write quad-groups = sdd mod 8, read groups =
// (dl + t4) mod 8 with 8-lane broadcast):
//   dtT[64][36] | xcT[64][36] | BT[16][36] | CT[16][36]
// Decay uses one raw v_exp_f32 (2^x): log2e folded into precomputed aA.
// y-reduce = 3 DPP adds; per-step capture via cndmask; chunk-end coalesced
// writeout with silu(z) from registers (z prefetched a chunk ahead).
// NOTE: yg aliases dtb - chunk c+1's dtb rows are prefetched to regs before
// chunk c's yg writeout; blocks touch disjoint (g, d-slice) columns.
__global__ __launch_bounds__(512) void k_scan(const float* __restrict__ dtb,
                                              const float* __restrict__ xcb,
                                              const float* __restrict__ xzb,
                                              const float* __restrict__ Bb,
                                              const float* __restrict__ Cb,
                                              const float* __restrict__ A_log,
                                              const float* __restrict__ Dp,
                                              float* __restrict__ yg)
{
    // floats: buf0 [0,5760) | buf1 [5760,11520) | ygL [11520, 11520+32*68)
    __shared__ __align__(16) float lds[2 * 5760 + 32 * 68];

    const int g    = blockIdx.x >> 2;
    const int dblk = blockIdx.x & 3;
    const int tid  = threadIdx.x;
    const int w    = tid >> 6, lane = tid & 63;
    const int dl   = w * 8 + (lane >> 3);    // local d 0..63
    const int sp   = lane & 7;               // state-pair index
    const int d0   = dblk * 64;
    const int d    = d0 + dl;
    const size_t rbase = (size_t)g * GL;

    // staging coords
    const int sdd = tid & 63, stq = tid >> 6;          // dt/xc: d-col, t-quad
    const int sbt = tid >> 4, sbi = tid & 15;          // B/C, z, writeout

    const float L2E = 1.44269504088896f;
    const float aA0 = -__expf(A_log[d * 16 + 2 * sp]) * L2E;
    const float aA1 = -__expf(A_log[d * 16 + 2 * sp + 1]) * L2E;
    const float Dpd = Dp[d];
    float h0 = 0.f, h1 = 0.f;

    float4 r_dt, r_xc, r_z, z_cur;
    float r_B, r_C;

    // ---- prologue: load chunk 0 into registers ----
    {
        const size_t r0 = rbase;
#pragma unroll
        for (int j = 0; j < 4; ++j) {
            ((float*)&r_dt)[j] = dtb[(r0 + stq * 4 + j) * 256 + d0 + sdd];
            ((float*)&r_xc)[j] = xcb[(r0 + stq * 4 + j) * 256 + d0 + sdd];
        }
        r_z = *(const float4*)&xzb[(r0 + sbt) * 512 + 256 + d0 + sbi * 4];
        r_B = Bb[(r0 + sbt) * 16 + sbi];
        r_C = Cb[(r0 + sbt) * 16 + sbi];
    }

    float* ygL = lds + 2 * 5760;

    for (int c = 0; c < NCH; ++c) {
        float* buf = lds + (c & 1) * 5760;
        // ---- commit staged registers to LDS (transposed, no swizzle) ----
        *(float4*)&buf[sdd * 36 + stq * 4]        = r_dt;
        *(float4*)&buf[2304 + sdd * 36 + stq * 4] = r_xc;
        buf[4608 + sbi * 36 + sbt] = r_B;
        buf[5184 + sbi * 36 + sbt] = r_C;
        z_cur = r_z;
        __syncthreads();

        // ---- prefetch chunk c+1 (lands during the 32 steps below) ----
        if (c + 1 < NCH) {
            const size_t r0 = rbase + (size_t)(c + 1) * SCH;
#pragma unroll
            for (int j = 0; j < 4; ++j) {
                ((float*)&r_dt)[j] = dtb[(r0 + stq * 4 + j) * 256 + d0 + sdd];
                ((float*)&r_xc)[j] = xcb[(r0 + stq * 4 + j) * 256 + d0 + sdd];
            }
            r_z = *(const float4*)&xzb[(r0 + sbt) * 512 + 256 + d0 + sbi * 4];
            r_B = Bb[(r0 + sbt) * 16 + sbi];
            r_C = Cb[(r0 + sbt) * 16 + sbi];
        }

        // ---- 32 scan steps from LDS ----
        const float* pdt = buf + dl * 36;
        const float* pxc = buf + 2304 + dl * 36;
        const float* pB0 = buf + 4608 + (2 * sp) * 36;
        const float* pB1 = buf + 4608 + (2 * sp + 1) * 36;
        const float* pC0 = buf + 5184 + (2 * sp) * 36;
        const float* pC1 = buf + 5184 + (2 * sp + 1) * 36;
        float yk[4] = {0.f, 0.f, 0.f, 0.f};
#pragma unroll
        for (int t4 = 0; t4 < 8; ++t4) {
            const float4 dt4 = *(const float4*)&pdt[t4 * 4];
            const float4 xc4 = *(const float4*)&pxc[t4 * 4];
            const float4 B04 = *(const float4*)&pB0[t4 * 4];
            const float4 B14 = *(const float4*)&pB1[t4 * 4];
            const float4 C04 = *(const float4*)&pC0[t4 * 4];
            const float4 C14 = *(const float4*)&pC1[t4 * 4];
#define SSTEP(J)                                                            \
            {                                                               \
                const float dt = ((const float*)&dt4)[J];                   \
                const float xc = ((const float*)&xc4)[J];                   \
                const float dtx = dt * xc;                                  \
                h0 = h0 * exp2_fast(dt * aA0) + dtx * ((const float*)&B04)[J]; \
                h1 = h1 * exp2_fast(dt * aA1) + dtx * ((const float*)&B14)[J]; \
                float yv = h0 * ((const float*)&C04)[J]                     \
                         + h1 * ((const float*)&C14)[J];                    \
                yv = dpp_add8(yv);                                          \
                yv = fmaf(xc, Dpd, yv);                                     \
                const int tt = t4 * 4 + (J);                                \
                yk[t4 >> 1] = (sp == (tt & 7)) ? yv : yk[t4 >> 1];          \
            }
            SSTEP(0) SSTEP(1) SSTEP(2) SSTEP(3)
#undef SSTEP
        }
        // stage captured y to LDS: lane sp holds t = 8k+sp for its d
#pragma unroll
        for (int k = 0; k < 4; ++k)
            ygL[(k * 8 + sp) * 68 + dl] = yk[k];
        __syncthreads();

        // ---- coalesced writeout with silu(z) from registers ----
        {
            const size_t rr0 = rbase + (size_t)c * SCH;
            float4 y4 = *(const float4*)&ygL[sbt * 68 + sbi * 4];
            float4 o;
            o.x = y4.x * (z_cur.x / (1.f + __expf(-z_cur.x)));
            o.y = y4.y * (z_cur.y / (1.f + __expf(-z_cur.y)));
            o.z = y4.z * (z_cur.z / (1.f + __expf(-z_cur.z)));
            o.w = y4.w * (z_cur.w / (1.f + __expf(-z_cur.w)));
            *(float4*)&yg[(rr0 + sbt) * 256 + d0 + sbi * 4] = o;
        }
    }
}

// ---------------- add + BN1/BN2 (params computed per-thread) ---------------
__global__ __launch_bounds__(256) void k_add(const float* __restrict__ h1p,
                                             const float* __restrict__ p2,
                                             const float* __restrict__ st,
                                             const float* __restrict__ g1,
                                             const float* __restrict__ be1,
                                             const float* __restrict__ g2,
                                             const float* __restrict__ be2,
                                             float* __restrict__ outp,
                                             float* __restrict__ sumP,
                                             float* __restrict__ sqP)
{
    const int c = threadIdx.x & 127, half = threadIdx.x >> 7;
    const float inv = 1.f / 32768.f;
    const float m1 = st[c] * inv, v1 = st[128 + c] * inv - m1 * m1;
    const float a1 = g1[c] * rsqrtf(v1 + 1e-5f), b1 = be1[c] - m1 * a1;
    const float m2 = st[256 + c] * inv, v2 = st[384 + c] * inv - m2 * m2;
    const float a2 = g2[c] * rsqrtf(v2 + 1e-5f), b2 = be2[c] - m2 * a2;

    const int rbase = blockIdx.x * 64 + half * 32;
    float s = 0.f, q = 0.f;
    for (int i = 0; i < 32; ++i) {
        size_t idx = (size_t)(rbase + i) * 128 + c;
        float v = h1p[idx] * a1 + b1 + p2[idx] * a2 + b2;
        outp[idx] = v; s += v; q += v * v;
    }
    __shared__ float sh[2][2][128];
    sh[0][half][c] = s; sh[1][half][c] = q;
    __syncthreads();
    if (threadIdx.x < 128) {
        atomicAdd(&sumP[c], sh[0][0][c] + sh[0][1][c]);
        atomicAdd(&sqP[c],  sh[1][0][c] + sh[1][1][c]);
    }
}

// ---- fold1: block-per-column; W1eT bf16 [256][128] + b1e fp32 -------------
__global__ __launch_bounds__(128) void k_fold1(
    const float* __restrict__ sumP, const float* __restrict__ sqP,
    const float* __restrict__ gam, const float* __restrict__ bet,
    const float* __restrict__ W1, const float* __restrict__ b1in,
    unsigned short* __restrict__ W1eT, float* __restrict__ b1e)
{
    __shared__ float red[128];
    const int n = blockIdx.x, k = threadIdx.x;
    const float inv = 1.f / 32768.f;
    const float m = sumP[k] * inv, v = sqP[k] * inv - m * m;
    const float a = gam[k] * rsqrtf(v + 1e-5f), bs = bet[k] - m * a;
    const float wv = W1[k * 256 + n];
    W1eT[n * 128 + k] = f2bf(a * wv);
    red[k] = bs * wv;
    __syncthreads();
    for (int s = 64; s > 0; s >>= 1) {
        if (k < s) red[k] += red[k + s];
        __syncthreads();
    }
    if (k == 0) b1e[n] = red[0] + b1in[n];
}

// ---- fold2: block-per-column; W2eT bf16 [128][256] + b2e fp32 -------------
__global__ __launch_bounds__(256) void k_fold2(
    const float* __restrict__ sumP, const float* __restrict__ sqP,
    const float* __restrict__ gam, const float* __restrict__ bet,
    const float* __restrict__ W2, const float* __restrict__ b2in,
    unsigned short* __restrict__ W2eT, float* __restrict__ b2e)
{
    __shared__ float red[256];
    const int n = blockIdx.x, k = threadIdx.x;
    const float inv = 1.f / 32768.f;
    const float m = sumP[k] * inv, v = sqP[k] * inv - m * m;
    const float a = gam[k] * rsqrtf(v + 1e-5f), bs = bet[k] - m * a;
    const float wv = W2[k * 128 + n];
    W2eT[n * 256 + k] = f2bf(a * wv);
    red[k] = bs * wv;
    __syncthreads();
    for (int s = 128; s > 0; s >>= 1) {
        if (k < s) red[k] += red[k + s];
        __syncthreads();
    }
    if (k == 0) b2e[n] = red[0] + b2in[n];
}

// ---------------- BN3 (params computed per-thread, amortized) ---------------
__global__ __launch_bounds__(256) void k_bn3(const float* __restrict__ out2,
                                             const float* __restrict__ sumP,
                                             const float* __restrict__ sqP,
                                             const float* __restrict__ gam,
                                             const float* __restrict__ bet,
                                             float* __restrict__ dout)
{
    const int cq = (threadIdx.x & 31) * 4;     // column quad
    const int rw = threadIdx.x >> 5;           // 0..7
    const float inv = 1.f / 32768.f;
    float a[4], b[4];
#pragma unroll
    for (int j = 0; j < 4; ++j) {
        float m = sumP[cq + j] * inv, v = sqP[cq + j] * inv - m * m;
        a[j] = gam[cq + j] * rsqrtf(v + 1e-5f);
        b[j] = bet[cq + j] - m * a[j];
    }
    const int r0 = blockIdx.x * 128 + rw;
#pragma unroll 4
    for (int k = 0; k < 16; ++k) {
        const size_t r = r0 + k * 8;
        float4 v = *(const float4*)&out2[r * 128 + cq];
        v.x = v.x * a[0] + b[0]; v.y = v.y * a[1] + b[1];
        v.z = v.z * a[2] + b[2]; v.w = v.w * a[3] + b[3];
        *(float4*)&dout[r * 128 + cq] = v;
    }
}

// ------------------------------- launch ------------------------------------
extern "C" void kernel_launch(void* const* d_in, const int* in_sizes, int n_in,
                              void* d_out, int out_size, void* d_ws, size_t ws_size,
                              hipStream_t stream)
{
    (void)in_sizes; (void)n_in; (void)out_size; (void)ws_size;
    const float* x      = (const float*)d_in[0];
    const int*   ei     = (const int*)d_in[1];
    // d_in[2] = batch (unused: equal-size sorted graphs == reshape)
    const float* W_root = (const float*)d_in[3];
    const float* W_rel  = (const float*)d_in[4];
    const float* b_rel  = (const float*)d_in[5];
    const float* n1_g = (const float*)d_in[6],  *n1_b = (const float*)d_in[7];
    const float* n2_g = (const float*)d_in[8],  *n2_b = (const float*)d_in[9];
    const float* n3_g = (const float*)d_in[10], *n3_b = (const float*)d_in[11];
    const float* m1_g = (const float*)d_in[12], *m1_b = (const float*)d_in[13];
    const float* W1   = (const float*)d_in[14], *b1   = (const float*)d_in[15];
    const float* m2_g = (const float*)d_in[16], *m2_b = (const float*)d_in[17];
    const float* W2   = (const float*)d_in[18], *b2   = (const float*)d_in[19];
    const float* in_W   = (const float*)d_in[20];
    const float* conv_w = (const float*)d_in[21], *conv_b = (const float*)d_in[22];
    const float* xproj_W= (const float*)d_in[23];
    const float* dt_W   = (const float*)d_in[24], *dt_b = (const float*)d_in[25];
    const float* A_log  = (const float*)d_in[26], *Dp   = (const float*)d_in[27];
    const float* out_W  = (const float*)d_in[28];

    float* ws = (float*)d_ws;
    // small region
    float* st  = ws;             // 2048 used (S1..S5 sums/sumsqs)
    float* b1e = ws + 8192;      // 256
    float* b2e = ws + 8448;      // 128
    // bf16 transposed weights (shorts)
    unsigned short* wsh   = (unsigned short*)(ws + 8704);
    unsigned short* WrelT  = wsh;            // 128x128 = 16384
    unsigned short* WrootT = wsh + 16384;    // 16384
    unsigned short* inWT   = wsh + 32768;    // 512x128 = 65536
    unsigned short* xprojT = wsh + 98304;    // 40x256  = 10240
    unsigned short* outWT  = wsh + 108544;   // 128x256 = 32768
    unsigned short* W1eT   = wsh + 141312;   // 256x128 = 32768
    unsigned short* W2eT   = wsh + 174080;   // 128x256 = 32768 (end 206848)
    // big buffers
    float* big  = ws + 112640;
    float* agg  = big;                    // 4194304 (later reused as p2)
    float* p2   = agg;
    float* h1p  = big + 4194304;          // 4194304
    float* xz   = big + 8388608;          // 16777216 (later: g + out2)
    float* gbuf = xz;
    float* out2 = xz + 8388608;
    float* xc   = big + 25165824;         // 8388608
    float* proj = big + 33554432;         // 1310720
    float* dtb  = big + 34865152;         // 8388608 (yg aliases dtb)
    float* ygb  = dtb;
    float* Bc   = big + 43253760;         // 524288
    float* Cc   = big + 43778048;         // 524288
    float* outb = big + 44302336;         // 4194304

    // CSR scratch lives in the h1p region (dead until the h1 GEMM writes it)
    int* ideg   = (int*)h1p;              // 32768
    int* ibase  = ideg + 32768;           // 32769
    int* icur   = ideg + 65552;           // 32768 (16B-aligned)
    int* isrcs  = ideg + 98320;           // 524288

    hipMemsetAsync(st, 0, 2048 * sizeof(float), stream);
    hipMemsetAsync(ideg, 0, 32768 * sizeof(int), stream);

    // ---- weight prep: 5 bf16 transposes in ONE launch ----
    k_prepw5<<<552, 256, 0, stream>>>(W_rel, WrelT, W_root, WrootT,
                                      in_W, inWT, xproj_W, xprojT,
                                      out_W, outWT);

    // ---- CSR build + gather ----
    k_hist<<<512, 256, 0, stream>>>(ei, ideg);
    k_scanidx<<<1, 1024, 0, stream>>>(ideg, ibase, icur);
    k_fill<<<512, 256, 0, stream>>>(ei, icur, isrcs);
    k_gather<<<8192, 256, 0, stream>>>(x, ibase, isrcs, agg);

    // h1_pre = agg@W_rel + b_rel + x@W_root + x  [S1]
    gemm_mfma<true, 0, true><<<dim3(512, 2), 256, 0, stream>>>(
        agg, WrelT, x, WrootT, NROWS, 128, 128, 128,
        b_rel, x, 128, h1p, st + 0, st + 128);
    // xz = x @ in_W
    gemm_mfma<false, 0, false><<<dim3(512, 8), 256, 0, stream>>>(
        x, inWT, nullptr, nullptr, NROWS, 512, 128, 512,
        nullptr, nullptr, 0, xz, nullptr, nullptr);
    k_conv<<<32768, 256, 0, stream>>>(xz, conv_w, conv_b, xc);
    // proj = xc @ xproj_W (N=40)
    gemm_mfma<false, 0, false><<<dim3(512, 1), 256, 0, stream>>>(
        xc, xprojT, nullptr, nullptr, NROWS, 40, 256, 40,
        nullptr, nullptr, 0, proj, nullptr, nullptr);
    k_dtbc<<<1024, 256, 0, stream>>>(proj, dt_W, dt_b, dtb, Bc, Cc);
    k_scan<<<256, 512, 0, stream>>>(dtb, xc, xz, Bc, Cc, A_log, Dp, ygb);
    // p2 = yg @ out_W + x  [S2]
    gemm_mfma<false, 0, true><<<dim3(512, 2), 256, 0, stream>>>(
        ygb, outWT, nullptr, nullptr, NROWS, 128, 256, 128,
        nullptr, x, 128, p2, st + 256, st + 384);
    // out = BN1(h1_pre) + BN2(p2)  [S3]  (BN params computed in-kernel)
    k_add<<<512, 256, 0, stream>>>(h1p, p2, st, n1_g, n1_b, n2_g, n2_b,
                                   outb, st + 512, st + 640);
    k_fold1<<<256, 128, 0, stream>>>(st + 512, st + 640, m1_g, m1_b, W1, b1, W1eT, b1e);
    // g = gelu(out @ W1e + b1e)  [S4]
    gemm_mfma<false, 1, true><<<dim3(512, 4), 256, 0, stream>>>(
        outb, W1eT, nullptr, nullptr, NROWS, 256, 128, 256,
        b1e, nullptr, 0, gbuf, st + 768, st + 1024);
    k_fold2<<<128, 256, 0, stream>>>(st + 768, st + 1024, m2_g, m2_b, W2, b2, W2eT, b2e);
    // out2 = g @ W2e + b2e + out  [S5]
    gemm_mfma<false, 0, true><<<dim3(512, 2), 256, 0, stream>>>(
        gbuf, W2eT, nullptr, nullptr, NROWS, 128, 256, 128,
        b2e, outb, 128, out2, st + 1280, st + 1408);
    // d_out = BN3(out2)  (params computed in-kernel from S5)
    k_bn3<<<256, 256, 0, stream>>>(out2, st + 1280, st + 1408, n3_g, n3_b,
                                   (float*)d_out);
}

// Round 9
// 393.440 us; speedup vs baseline: 1.8278x; 1.0823x over previous
//
#include <hip/hip_runtime.h>

// ---------------------------------------------------------------------------
// GraphMambaConv: N=32768 nodes, C=128, G=64 graphs x L=512, E=524288 edges,
// D_INNER=256, D_STATE=16, DT_RANK=8, D_CONV=4.
//
// Round 9: cut intermediate bytes + scan barrier-overlap.
//  - bf16 storage for xz, xc, dtb/yg, g (the 4 biggest streams, ~176MB saved).
//    GEMMs with bf16 A-operand stage by straight copy (no cvt). All
//    accumulation, stats, BN, B/C, h-recurrence stay fp32.
//  - k_scan: 512 blocks x 256 thr (32 d/block) -> 2 independent barrier
//    groups per CU (was 1 block/CU, 8-wave single group); bf16 global I/O.
//  - dtbc softplus via v_exp/v_log (no libm log1pf).
// ---------------------------------------------------------------------------

#define NROWS 32768
#define CDIM  128
#define EDGES 524288
#define GL    512
#define SCH   32          // scan chunk (timesteps)
#define NCH   (GL / SCH)  // 16 chunks

typedef short s16x8 __attribute__((ext_vector_type(8)));
typedef float f32x4 __attribute__((ext_vector_type(4)));

__device__ __forceinline__ unsigned short f2bf(float f)
{
    unsigned u = __float_as_uint(f);
    u += 0x7FFF + ((u >> 16) & 1);          // RNE
    return (unsigned short)(u >> 16);
}

__device__ __forceinline__ float bf2f(unsigned short u)
{
    return __uint_as_float((unsigned)u << 16);
}

__device__ __forceinline__ unsigned cvt_pk_bf16(float lo, float hi)
{
    unsigned r;
    asm("v_cvt_pk_bf16_f32 %0, %1, %2" : "=v"(r) : "v"(lo), "v"(hi));
    return r;
}

__device__ __forceinline__ float exp2_fast(float x)
{
    float r;
    asm("v_exp_f32 %0, %1" : "=v"(r) : "v"(x));   // v_exp_f32 computes 2^x
    return r;
}

// ------------------------- CSR build: histogram ----------------------------
__global__ __launch_bounds__(256) void k_hist(const int* __restrict__ ei,
                                              int* __restrict__ deg)
{
    const int e = blockIdx.x * 1024 + threadIdx.x * 4;
    const int4 d4 = *(const int4*)&ei[EDGES + e];
    atomicAdd(&deg[d4.x], 1);
    atomicAdd(&deg[d4.y], 1);
    atomicAdd(&deg[d4.z], 1);
    atomicAdd(&deg[d4.w], 1);
}

// ---------------- CSR build: exclusive prefix scan (1 block) ---------------
__global__ __launch_bounds__(1024) void k_scanidx(const int* __restrict__ deg,
                                                  int* __restrict__ base,
                                                  int* __restrict__ cursor)
{
    __shared__ int ps[1024];
    const int tid = threadIdx.x;
    int loc[32];
    int s = 0;
#pragma unroll
    for (int i = 0; i < 32; ++i) { loc[i] = deg[tid * 32 + i]; s += loc[i]; }
    ps[tid] = s;
    __syncthreads();
    for (int off = 1; off < 1024; off <<= 1) {
        int v = (tid >= off) ? ps[tid - off] : 0;
        __syncthreads();
        ps[tid] += v;
        __syncthreads();
    }
    int run = tid ? ps[tid - 1] : 0;
#pragma unroll
    for (int i = 0; i < 32; ++i) {
        base[tid * 32 + i] = run;
        cursor[tid * 32 + i] = run;
        run += loc[i];
    }
    if (tid == 0) base[32768] = EDGES;
}

// ------------------------- CSR build: fill src lists -----------------------
__global__ __launch_bounds__(256) void k_fill(const int* __restrict__ ei,
                                              int* __restrict__ cursor,
                                              int* __restrict__ srcs)
{
    const int e = blockIdx.x * 1024 + threadIdx.x * 4;
    const int4 s4 = *(const int4*)&ei[e];
    const int4 d4 = *(const int4*)&ei[EDGES + e];
    int p;
    p = atomicAdd(&cursor[d4.x], 1); srcs[p] = s4.x;
    p = atomicAdd(&cursor[d4.y], 1); srcs[p] = s4.y;
    p = atomicAdd(&cursor[d4.z], 1); srcs[p] = s4.z;
    p = atomicAdd(&cursor[d4.w], 1); srcs[p] = s4.w;
}

// ------------------------- gather: one wave per node ------------------------
__global__ __launch_bounds__(256) void k_gather(const float* __restrict__ x,
                                                const int* __restrict__ base,
                                                const int* __restrict__ srcs,
                                                float* __restrict__ agg)
{
    const int node = blockIdx.x * 4 + (threadIdx.x >> 6);
    const int lane = threadIdx.x & 63;
    const int b0 = base[node], b1 = base[node + 1];
    float2 a0 = make_float2(0.f, 0.f), a1 = make_float2(0.f, 0.f);
    int i = b0;
    for (; i + 2 <= b1; i += 2) {
        const int s0 = srcs[i], s1 = srcs[i + 1];
        const float2 v0 = *(const float2*)&x[(size_t)s0 * 128 + lane * 2];
        const float2 v1 = *(const float2*)&x[(size_t)s1 * 128 + lane * 2];
        a0.x += v0.x; a0.y += v0.y;
        a1.x += v1.x; a1.y += v1.y;
    }
    if (i < b1) {
        const int s0 = srcs[i];
        const float2 v0 = *(const float2*)&x[(size_t)s0 * 128 + lane * 2];
        a0.x += v0.x; a0.y += v0.y;
    }
    a0.x += a1.x; a0.y += a1.y;
    *(float2*)&agg[(size_t)node * 128 + lane * 2] = a0;
}

// ---- merged weight prep: 5 transposes (bf16) in one launch, 552 blocks ----
__global__ __launch_bounds__(256) void k_prepw5(
    const float* __restrict__ Wa, unsigned short* __restrict__ Ta,
    const float* __restrict__ Wb, unsigned short* __restrict__ Tb,
    const float* __restrict__ Wc, unsigned short* __restrict__ Tc,
    const float* __restrict__ Wd, unsigned short* __restrict__ Td,
    const float* __restrict__ We, unsigned short* __restrict__ Te)
{
    const int idx = blockIdx.x * 256 + threadIdx.x;
    const float* W; unsigned short* T; int rel, ks, N;
    if (idx < 16384)       { W = Wa; T = Ta; rel = idx;          ks = 7; N = 128; }
    else if (idx < 32768)  { W = Wb; T = Tb; rel = idx - 16384;  ks = 7; N = 128; }
    else if (idx < 98304)  { W = Wc; T = Tc; rel = idx - 32768;  ks = 7; N = 512; }
    else if (idx < 108544) { W = Wd; T = Td; rel = idx - 98304;  ks = 8; N = 40;  }
    else                   { W = We; T = Te; rel = idx - 108544; ks = 8; N = 128; }
    const int K = 1 << ks;
    const int n = rel >> ks, k = rel & (K - 1);
    T[rel] = f2bf(W[(size_t)k * N + n]);
}

// ------------------------- MFMA GEMM (bf16 in, fp32 acc) --------------------
// out = epi( A0@W0 [+ A1@W1] [+bias] [+resid] ), optional column stats.
// A: MxK row-major, fp32 (ABF=0, cvt-staged) or bf16 (ABF=1, copy-staged).
// WT: NxK bf16 row-major. Out fp32 (OBF=0) or bf16 (OBF=1); stats/resid fp32.
// Tile 64x64, BK=64, 4 waves x (2x2 mfma_f32_16x16x32_bf16).
template<bool DUAL, int ACT, bool STAT, bool ABF, bool OBF>
__global__ __launch_bounds__(256)
void gemm_mfma(const void* __restrict__ A0, const unsigned short* __restrict__ W0T,
               const void* __restrict__ A1p, const unsigned short* __restrict__ W1Tp,
               int M, int N, int K, int ldo,
               const float* __restrict__ bias,
               const float* __restrict__ resid, int ldr,
               void* __restrict__ outp,
               float* __restrict__ sumP, float* __restrict__ sqP)
{
    __shared__ __align__(16) unsigned short As[64 * 72];  // [m][k], pad 8
    __shared__ __align__(16) unsigned short Bs[64 * 72];  // [n][k], pad 8
    __shared__ float sB[2][64];

    const int tid = threadIdx.x;
    const int m0 = blockIdx.x * 64;
    const int n0 = blockIdx.y * 64;

    const int sr = tid >> 2;             // staging row 0..63
    const int sk = (tid & 3) * 16;       // staging k base

    const int w  = tid >> 6, l = tid & 63;
    const int wr = (w >> 1) * 32, wc = (w & 1) * 32;
    const int fr = l & 15;               // frag row/col
    const int fk = (l >> 4) * 8;         // frag k base

    f32x4 acc[2][2];
#pragma unroll
    for (int i = 0; i < 2; ++i)
#pragma unroll
        for (int j = 0; j < 2; ++j) acc[i][j] = (f32x4){0.f, 0.f, 0.f, 0.f};

    const int npass = DUAL ? 2 : 1;
    for (int pass = 0; pass < npass; ++pass) {
        const void* A = (DUAL && pass) ? A1p : A0;
        const unsigned short* WT = (DUAL && pass) ? W1Tp : W0T;
        for (int k0 = 0; k0 < K; k0 += 64) {
            if (ABF) {   // stage A: straight bf16 copy
                const unsigned short* ap =
                    (const unsigned short*)A + (size_t)(m0 + sr) * K + k0 + sk;
                *(uint4*)&As[sr * 72 + sk]     = *(const uint4*)(ap);
                *(uint4*)&As[sr * 72 + sk + 8] = *(const uint4*)(ap + 8);
            } else {     // stage A: fp32 -> bf16 via v_cvt_pk_bf16_f32
                const float* ap = (const float*)A + (size_t)(m0 + sr) * K + k0 + sk;
                float4 v0 = *(const float4*)(ap);
                float4 v1 = *(const float4*)(ap + 4);
                float4 v2 = *(const float4*)(ap + 8);
                float4 v3 = *(const float4*)(ap + 12);
                uint4 pa, pb;
                pa.x = cvt_pk_bf16(v0.x, v0.y); pa.y = cvt_pk_bf16(v0.z, v0.w);
                pa.z = cvt_pk_bf16(v1.x, v1.y); pa.w = cvt_pk_bf16(v1.z, v1.w);
                pb.x = cvt_pk_bf16(v2.x, v2.y); pb.y = cvt_pk_bf16(v2.z, v2.w);
                pb.z = cvt_pk_bf16(v3.x, v3.y); pb.w = cvt_pk_bf16(v3.z, v3.w);
                *(uint4*)&As[sr * 72 + sk]     = pa;
                *(uint4*)&As[sr * 72 + sk + 8] = pb;
            }
            {   // stage B: straight bf16 copy from WT (zero-fill n >= N)
                const int nn = n0 + sr;
                if (nn < N) {
                    const unsigned short* wp = WT + (size_t)nn * K + k0 + sk;
                    uint4 w0 = *(const uint4*)(wp);
                    uint4 w1 = *(const uint4*)(wp + 8);
                    *(uint4*)&Bs[sr * 72 + sk]     = w0;
                    *(uint4*)&Bs[sr * 72 + sk + 8] = w1;
                } else {
                    uint4 z = make_uint4(0, 0, 0, 0);
                    *(uint4*)&Bs[sr * 72 + sk]     = z;
                    *(uint4*)&Bs[sr * 72 + sk + 8] = z;
                }
            }
            __syncthreads();
#pragma unroll
            for (int ks = 0; ks < 2; ++ks) {
                s16x8 a0 = *(const s16x8*)&As[(wr + fr     ) * 72 + ks * 32 + fk];
                s16x8 a1 = *(const s16x8*)&As[(wr + 16 + fr) * 72 + ks * 32 + fk];
                s16x8 b0 = *(const s16x8*)&Bs[(wc + fr     ) * 72 + ks * 32 + fk];
                s16x8 b1 = *(const s16x8*)&Bs[(wc + 16 + fr) * 72 + ks * 32 + fk];
                acc[0][0] = __builtin_amdgcn_mfma_f32_16x16x32_bf16(a0, b0, acc[0][0], 0, 0, 0);
                acc[0][1] = __builtin_amdgcn_mfma_f32_16x16x32_bf16(a0, b1, acc[0][1], 0, 0, 0);
                acc[1][0] = __builtin_amdgcn_mfma_f32_16x16x32_bf16(a1, b0, acc[1][0], 0, 0, 0);
                acc[1][1] = __builtin_amdgcn_mfma_f32_16x16x32_bf16(a1, b1, acc[1][1], 0, 0, 0);
            }
            __syncthreads();
        }
    }

    // ---- epilogue: C/D layout col=lane&15, row=(lane>>4)*4+reg ----
    const int orow = (l >> 4) * 4;
    float cs[2] = {0.f, 0.f}, cq[2] = {0.f, 0.f};
#pragma unroll
    for (int mt = 0; mt < 2; ++mt) {
#pragma unroll
        for (int nt = 0; nt < 2; ++nt) {
            const int cg = n0 + wc + nt * 16 + fr;
            if (cg < N) {
                const float bv = bias ? bias[cg] : 0.f;
#pragma unroll
                for (int r = 0; r < 4; ++r) {
                    const int rg = m0 + wr + mt * 16 + orow + r;
                    float v = acc[mt][nt][r] + bv;
                    if (resid) v += resid[(size_t)rg * ldr + cg];
                    if (ACT == 1)
                        v = 0.5f * v * (1.f + erff(v * 0.7071067811865475f));
                    if (OBF)
                        ((unsigned short*)outp)[(size_t)rg * ldo + cg] = f2bf(v);
                    else
                        ((float*)outp)[(size_t)rg * ldo + cg] = v;
                    if (STAT) { cs[nt] += v; cq[nt] += v * v; }
                }
            }
        }
    }
    if (STAT) {
        if (tid < 64) { sB[0][tid] = 0.f; sB[1][tid] = 0.f; }
        __syncthreads();
#pragma unroll
        for (int nt = 0; nt < 2; ++nt) {
            atomicAdd(&sB[0][wc + nt * 16 + fr], cs[nt]);
            atomicAdd(&sB[1][wc + nt * 16 + fr], cq[nt]);
        }
        __syncthreads();
        if (tid < 64 && (n0 + tid) < N) {
            atomicAdd(&sumP[n0 + tid], sB[0][tid]);
            atomicAdd(&sqP[n0 + tid],  sB[1][tid]);
        }
    }
}

// --------------------- causal conv + SiLU (bf16 in/out) --------------------
__global__ __launch_bounds__(256) void k_conv(const unsigned short* __restrict__ xz,
                                              const float* __restrict__ cw,
                                              const float* __restrict__ cb,
                                              unsigned short* __restrict__ xc)
{
    const int r = blockIdx.x;        // global row
    const int l = r & (GL - 1);      // position within graph
    const int d = threadIdx.x;       // 0..255
    float4 w4 = *(const float4*)&cw[d * 4];
    const float taps[4] = {w4.x, w4.y, w4.z, w4.w};
    float acc = cb[d];
#pragma unroll
    for (int k = 0; k < 4; ++k) {
        int ll = l - 3 + k;
        if (ll >= 0) acc += bf2f(xz[(size_t)(r - 3 + k) * 512 + d]) * taps[k];
    }
    float s = 1.f / (1.f + __expf(-acc));
    xc[(size_t)r * 256 + d] = f2bf(acc * s);
}

// ---------------- dt = softplus(proj[:,:8] @ dt_W + dt_b); B,C slices ------
__global__ __launch_bounds__(256) void k_dtbc(const float* __restrict__ proj,
                                              const float* __restrict__ dt_W,
                                              const float* __restrict__ dt_b,
                                              unsigned short* __restrict__ dtb,
                                              float* __restrict__ Bc,
                                              float* __restrict__ Cc)
{
    __shared__ float dtWS[8 * 256];
    __shared__ float dt_bS[256];
    __shared__ float projS[32 * 8];
    const int tid = threadIdx.x;
    const int r0 = blockIdx.x * 32;
    for (int i = tid; i < 2048; i += 256) dtWS[i] = dt_W[i];
    dt_bS[tid] = dt_b[tid];
    projS[tid] = proj[(size_t)(r0 + (tid >> 3)) * 40 + (tid & 7)];
    __syncthreads();

    const int c = tid;
    for (int rr = 0; rr < 32; ++rr) {
        float acc = dt_bS[c];
        const float* pr = &projS[rr * 8];
#pragma unroll
        for (int q = 0; q < 8; ++q) acc += pr[q] * dtWS[q * 256 + c];
        float e  = exp2_fast(-fabsf(acc) * 1.4426950408f);
        float sp = fmaxf(acc, 0.f) + 0.6931471806f * __log2f(1.f + e);
        dtb[(size_t)(r0 + rr) * 256 + c] = f2bf(sp);
    }
    // B = proj[:, 8:24], C = proj[:, 24:40]
    for (int e2 = tid; e2 < 1024; e2 += 256) {
        int rr = e2 >> 5, cc = e2 & 31;
        float v = proj[(size_t)(r0 + rr) * 40 + 8 + cc];
        if (cc < 16) Bc[(size_t)(r0 + rr) * 16 + cc] = v;
        else         Cc[(size_t)(r0 + rr) * 16 + cc - 16] = v;
    }
}

// ---------------- 8-lane-group sum via DPP (zero DS-pipe ops) ---------------
__device__ __forceinline__ float dpp_add8(float x)
{
    float y = x;
    int t;
    t = __builtin_amdgcn_update_dpp(0, __float_as_int(y), 0xB1, 0xF, 0xF, true);
    y += __int_as_float(t);
    t = __builtin_amdgcn_update_dpp(0, __float_as_int(y), 0x4E, 0xF, 0xF, true);
    y += __int_as_float(t);
    t = __builtin_amdgcn_update_dpp(0, __float_as_int(y), 0x141, 0xF, 0xF, true);
    y += __int_as_float(t);
    return y;
}

// ------------------------------ selective scan -----------------------------
// Block = (g, dblk32): 32 d x 16 states = 256 thr (4 waves); 512 blocks ->
// 2 independent barrier groups per CU (overlap each other's stalls).
// Wave = 8 d x 8 sp-lanes; lane holds states {2sp, 2sp+1} in registers.
// LDS (fp32, converted at stage time): dtT[32][36] | xcT[32][36] | BT[16][36]
// | CT[16][36], double-buffered; ygL[32][36]. Global dt/xc/z/yg are bf16.
// Decay: one raw v_exp_f32 (2^x), log2e folded into aA. y-reduce = 3 DPP
// adds; per-step capture via cndmask; chunk-end coalesced bf16 writeout.
// NOTE: yg aliases dtb - chunk c+1's dtb rows are prefetched to regs before
// chunk c's yg writeout; blocks touch disjoint (g, d-slice) columns.
__global__ __launch_bounds__(256) void k_scan(
    const unsigned short* __restrict__ dtb,
    const unsigned short* __restrict__ xcb,
    const unsigned short* __restrict__ xzb,
    const float* __restrict__ Bb, const float* __restrict__ Cb,
    const float* __restrict__ A_log, const float* __restrict__ Dp,
    unsigned short* __restrict__ yg)
{
    // floats: buf0 [0,3456) | buf1 [3456,6912) | ygL [6912, 6912+32*36)
    __shared__ __align__(16) float lds[2 * 3456 + 32 * 36];

    const int g    = blockIdx.x >> 3;
    const int dblk = blockIdx.x & 7;
    const int tid  = threadIdx.x;
    const int lane = tid & 63;
    const int dl   = (tid >> 6) * 8 + (lane >> 3);   // local d 0..31
    const int sp   = lane & 7;                       // state-pair index
    const int d0   = dblk * 32;
    const int d    = d0 + dl;
    const size_t rbase = (size_t)g * GL;

    // staging coords
    const int sdd = tid & 31, stq = tid >> 5;        // dt/xc: d-col, t-quad
    const int sbt = tid >> 4, sbi = tid & 15;        // B/C: t-row, state
    const int szt = tid >> 3, szi = tid & 7;         // z / writeout

    const float L2E = 1.44269504088896f;
    const float aA0 = -__expf(A_log[d * 16 + 2 * sp]) * L2E;
    const float aA1 = -__expf(A_log[d * 16 + 2 * sp + 1]) * L2E;
    const float Dpd = Dp[d];
    float h0 = 0.f, h1 = 0.f;

    float rdt[4], rxc[4];
    float rB0, rB1, rC0, rC1;
    ushort4 rz, zcur;

    // ---- prologue: load chunk 0 into registers ----
    {
        const size_t r0 = rbase;
#pragma unroll
        for (int j = 0; j < 4; ++j) {
            rdt[j] = bf2f(dtb[(r0 + stq * 4 + j) * 256 + d0 + sdd]);
            rxc[j] = bf2f(xcb[(r0 + stq * 4 + j) * 256 + d0 + sdd]);
        }
        rz  = *(const ushort4*)&xzb[(r0 + szt) * 512 + 256 + d0 + szi * 4];
        rB0 = Bb[(r0 + sbt) * 16 + sbi];
        rB1 = Bb[(r0 + sbt + 16) * 16 + sbi];
        rC0 = Cb[(r0 + sbt) * 16 + sbi];
        rC1 = Cb[(r0 + sbt + 16) * 16 + sbi];
    }
    zcur = rz;

    float* ygL = lds + 2 * 3456;

    for (int c = 0; c < NCH; ++c) {
        float* buf = lds + (c & 1) * 3456;
        // ---- commit staged registers to LDS (transposed fp32 tiles) ----
        *(float4*)&buf[sdd * 36 + stq * 4] =
            make_float4(rdt[0], rdt[1], rdt[2], rdt[3]);
        *(float4*)&buf[1152 + sdd * 36 + stq * 4] =
            make_float4(rxc[0], rxc[1], rxc[2], rxc[3]);
        buf[2304 + sbi * 36 + sbt]      = rB0;
        buf[2304 + sbi * 36 + sbt + 16] = rB1;
        buf[2880 + sbi * 36 + sbt]      = rC0;
        buf[2880 + sbi * 36 + sbt + 16] = rC1;
        zcur = rz;
        __syncthreads();

        // ---- prefetch chunk c+1 (lands during the 32 steps below) ----
        if (c + 1 < NCH) {
            const size_t r0 = rbase + (size_t)(c + 1) * SCH;
#pragma unroll
            for (int j = 0; j < 4; ++j) {
                rdt[j] = bf2f(dtb[(r0 + stq * 4 + j) * 256 + d0 + sdd]);
                rxc[j] = bf2f(xcb[(r0 + stq * 4 + j) * 256 + d0 + sdd]);
            }
            rz  = *(const ushort4*)&xzb[(r0 + szt) * 512 + 256 + d0 + szi * 4];
            rB0 = Bb[(r0 + sbt) * 16 + sbi];
            rB1 = Bb[(r0 + sbt + 16) * 16 + sbi];
            rC0 = Cb[(r0 + sbt) * 16 + sbi];
            rC1 = Cb[(r0 + sbt + 16) * 16 + sbi];
        }

        // ---- 32 scan steps from LDS ----
        const float* pdt = buf + dl * 36;
        const float* pxc = buf + 1152 + dl * 36;
        const float* pB0 = buf + 2304 + (2 * sp) * 36;
        const float* pB1 = buf + 2304 + (2 * sp + 1) * 36;
        const float* pC0 = buf + 2880 + (2 * sp) * 36;
        const float* pC1 = buf + 2880 + (2 * sp + 1) * 36;
        float yk[4] = {0.f, 0.f, 0.f, 0.f};
#pragma unroll
        for (int t4 = 0; t4 < 8; ++t4) {
            const float4 dt4 = *(const float4*)&pdt[t4 * 4];
            const float4 xc4 = *(const float4*)&pxc[t4 * 4];
            const float4 B04 = *(const float4*)&pB0[t4 * 4];
            const float4 B14 = *(const float4*)&pB1[t4 * 4];
            const float4 C04 = *(const float4*)&pC0[t4 * 4];
            const float4 C14 = *(const float4*)&pC1[t4 * 4];
#define SSTEP(J)                                                            \
            {                                                               \
                const float dt = ((const float*)&dt4)[J];                   \
                const float xc = ((const float*)&xc4)[J];                   \
                const float dtx = dt * xc;                                  \
                h0 = h0 * exp2_fast(dt * aA0) + dtx * ((const float*)&B04)[J]; \
                h1 = h1 * exp2_fast(dt * aA1) + dtx * ((const float*)&B14)[J]; \
                float yv = h0 * ((const float*)&C04)[J]                     \
                         + h1 * ((const float*)&C14)[J];                    \
                yv = dpp_add8(yv);                                          \
                yv = fmaf(xc, Dpd, yv);                                     \
                const int tt = t4 * 4 + (J);                                \
                yk[t4 >> 1] = (sp == (tt & 7)) ? yv : yk[t4 >> 1];          \
            }
            SSTEP(0) SSTEP(1) SSTEP(2) SSTEP(3)
#undef SSTEP
        }
        // stage captured y to LDS: lane sp holds t = 8k+sp for its d
#pragma unroll
        for (int k = 0; k < 4; ++k)
            ygL[(k * 8 + sp) * 36 + dl] = yk[k];
        __syncthreads();

        // ---- coalesced bf16 writeout with silu(z) from registers ----
        {
            const size_t rr0 = rbase + (size_t)c * SCH;
            float4 y4 = *(const float4*)&ygL[szt * 36 + szi * 4];
            float z0 = bf2f(zcur.x), z1 = bf2f(zcur.y);
            float z2 = bf2f(zcur.z), z3 = bf2f(zcur.w);
            float o0 = y4.x * (z0 / (1.f + __expf(-z0)));
            float o1 = y4.y * (z1 / (1.f + __expf(-z1)));
            float o2 = y4.z * (z2 / (1.f + __expf(-z2)));
            float o3 = y4.w * (z3 / (1.f + __expf(-z3)));
            uint2 packed;
            packed.x = cvt_pk_bf16(o0, o1);
            packed.y = cvt_pk_bf16(o2, o3);
            *(uint2*)&yg[(rr0 + szt) * 256 + d0 + szi * 4] = packed;
        }
    }
}

// ---------------- add + BN1/BN2 (params computed per-thread) ---------------
__global__ __launch_bounds__(256) void k_add(const float* __restrict__ h1p,
                                             const float* __restrict__ p2,
                                             const float* __restrict__ st,
                                             const float* __restrict__ g1,
                                             const float* __restrict__ be1,
                                             const float* __restrict__ g2,
                                             const float* __restrict__ be2,
                                             float* __restrict__ outp,
                                             float* __restrict__ sumP,
                                             float* __restrict__ sqP)
{
    const int c = threadIdx.x & 127, half = threadIdx.x >> 7;
    const float inv = 1.f / 32768.f;
    const float m1 = st[c] * inv, v1 = st[128 + c] * inv - m1 * m1;
    const float a1 = g1[c] * rsqrtf(v1 + 1e-5f), b1 = be1[c] - m1 * a1;
    const float m2 = st[256 + c] * inv, v2 = st[384 + c] * inv - m2 * m2;
    const float a2 = g2[c] * rsqrtf(v2 + 1e-5f), b2 = be2[c] - m2 * a2;

    const int rbase = blockIdx.x * 64 + half * 32;
    float s = 0.f, q = 0.f;
    for (int i = 0; i < 32; ++i) {
        size_t idx = (size_t)(rbase + i) * 128 + c;
        float v = h1p[idx] * a1 + b1 + p2[idx] * a2 + b2;
        outp[idx] = v; s += v; q += v * v;
    }
    __shared__ float sh[2][2][128];
    sh[0][half][c] = s; sh[1][half][c] = q;
    __syncthreads();
    if (threadIdx.x < 128) {
        atomicAdd(&sumP[c], sh[0][0][c] + sh[0][1][c]);
        atomicAdd(&sqP[c],  sh[1][0][c] + sh[1][1][c]);
    }
}

// ---- fold1: block-per-column; W1eT bf16 [256][128] + b1e fp32 -------------
__global__ __launch_bounds__(128) void k_fold1(
    const float* __restrict__ sumP, const float* __restrict__ sqP,
    const float* __restrict__ gam, const float* __restrict__ bet,
    const float* __restrict__ W1, const float* __restrict__ b1in,
    unsigned short* __restrict__ W1eT, float* __restrict__ b1e)
{
    __shared__ float red[128];
    const int n = blockIdx.x, k = threadIdx.x;
    const float inv = 1.f / 32768.f;
    const float m = sumP[k] * inv, v = sqP[k] * inv - m * m;
    const float a = gam[k] * rsqrtf(v + 1e-5f), bs = bet[k] - m * a;
    const float wv = W1[k * 256 + n];
    W1eT[n * 128 + k] = f2bf(a * wv);
    red[k] = bs * wv;
    __syncthreads();
    for (int s = 64; s > 0; s >>= 1) {
        if (k < s) red[k] += red[k + s];
        __syncthreads();
    }
    if (k == 0) b1e[n] = red[0] + b1in[n];
}

// ---- fold2: block-per-column; W2eT bf16 [128][256] + b2e fp32 -------------
__global__ __launch_bounds__(256) void k_fold2(
    const float* __restrict__ sumP, const float* __restrict__ sqP,
    const float* __restrict__ gam, const float* __restrict__ bet,
    const float* __restrict__ W2, const float* __restrict__ b2in,
    unsigned short* __restrict__ W2eT, float* __restrict__ b2e)
{
    __shared__ float red[256];
    const int n = blockIdx.x, k = threadIdx.x;
    const float inv = 1.f / 32768.f;
    const float m = sumP[k] * inv, v = sqP[k] * inv - m * m;
    const float a = gam[k] * rsqrtf(v + 1e-5f), bs = bet[k] - m * a;
    const float wv = W2[k * 128 + n];
    W2eT[n * 256 + k] = f2bf(a * wv);
    red[k] = bs * wv;
    __syncthreads();
    for (int s = 128; s > 0; s >>= 1) {
        if (k < s) red[k] += red[k + s];
        __syncthreads();
    }
    if (k == 0) b2e[n] = red[0] + b2in[n];
}

// ---------------- BN3 (params computed per-thread, amortized) ---------------
__global__ __launch_bounds__(256) void k_bn3(const float* __restrict__ out2,
                                             const float* __restrict__ sumP,
                                             const float* __restrict__ sqP,
                                             const float* __restrict__ gam,
                                             const float* __restrict__ bet,
                                             float* __restrict__ dout)
{
    const int cq = (threadIdx.x & 31) * 4;     // column quad
    const int rw = threadIdx.x >> 5;           // 0..7
    const float inv = 1.f / 32768.f;
    float a[4], b[4];
#pragma unroll
    for (int j = 0; j < 4; ++j) {
        float m = sumP[cq + j] * inv, v = sqP[cq + j] * inv - m * m;
        a[j] = gam[cq + j] * rsqrtf(v + 1e-5f);
        b[j] = bet[cq + j] - m * a[j];
    }
    const int r0 = blockIdx.x * 128 + rw;
#pragma unroll 4
    for (int k = 0; k < 16; ++k) {
        const size_t r = r0 + k * 8;
        float4 v = *(const float4*)&out2[r * 128 + cq];
        v.x = v.x * a[0] + b[0]; v.y = v.y * a[1] + b[1];
        v.z = v.z * a[2] + b[2]; v.w = v.w * a[3] + b[3];
        *(float4*)&dout[r * 128 + cq] = v;
    }
}

// ------------------------------- launch ------------------------------------
extern "C" void kernel_launch(void* const* d_in, const int* in_sizes, int n_in,
                              void* d_out, int out_size, void* d_ws, size_t ws_size,
                              hipStream_t stream)
{
    (void)in_sizes; (void)n_in; (void)out_size; (void)ws_size;
    const float* x      = (const float*)d_in[0];
    const int*   ei     = (const int*)d_in[1];
    // d_in[2] = batch (unused: equal-size sorted graphs == reshape)
    const float* W_root = (const float*)d_in[3];
    const float* W_rel  = (const float*)d_in[4];
    const float* b_rel  = (const float*)d_in[5];
    const float* n1_g = (const float*)d_in[6],  *n1_b = (const float*)d_in[7];
    const float* n2_g = (const float*)d_in[8],  *n2_b = (const float*)d_in[9];
    const float* n3_g = (const float*)d_in[10], *n3_b = (const float*)d_in[11];
    const float* m1_g = (const float*)d_in[12], *m1_b = (const float*)d_in[13];
    const float* W1   = (const float*)d_in[14], *b1   = (const float*)d_in[15];
    const float* m2_g = (const float*)d_in[16], *m2_b = (const float*)d_in[17];
    const float* W2   = (const float*)d_in[18], *b2   = (const float*)d_in[19];
    const float* in_W   = (const float*)d_in[20];
    const float* conv_w = (const float*)d_in[21], *conv_b = (const float*)d_in[22];
    const float* xproj_W= (const float*)d_in[23];
    const float* dt_W   = (const float*)d_in[24], *dt_b = (const float*)d_in[25];
    const float* A_log  = (const float*)d_in[26], *Dp   = (const float*)d_in[27];
    const float* out_W  = (const float*)d_in[28];

    float* ws = (float*)d_ws;
    // small region
    float* st  = ws;             // 2048 used (S1..S5 sums/sumsqs)
    float* b1e = ws + 8192;      // 256
    float* b2e = ws + 8448;      // 128
    // bf16 transposed weights (shorts)
    unsigned short* wsh   = (unsigned short*)(ws + 8704);
    unsigned short* WrelT  = wsh;            // 128x128 = 16384
    unsigned short* WrootT = wsh + 16384;    // 16384
    unsigned short* inWT   = wsh + 32768;    // 512x128 = 65536
    unsigned short* xprojT = wsh + 98304;    // 40x256  = 10240
    unsigned short* outWT  = wsh + 108544;   // 128x256 = 32768
    unsigned short* W1eT   = wsh + 141312;   // 256x128 = 32768
    unsigned short* W2eT   = wsh + 174080;   // 128x256 = 32768 (end 206848)
    // big buffers (float-unit offsets; bf16 buffers occupy half the floats)
    float* big  = ws + 112640;
    float* agg  = big;                                   // fp32 4.19M
    float* p2   = agg;                                   // reuse
    float* h1p  = big + 4194304;                         // fp32 4.19M
    unsigned short* xz16  = (unsigned short*)(big + 8388608);   // 16.78M sh
    unsigned short* xc16  = (unsigned short*)(big + 16777216);  // 8.39M sh
    float* proj = big + 20971520;                        // fp32 1.31M
    unsigned short* dtb16 = (unsigned short*)(big + 22282240);  // 8.39M sh (yg alias)
    unsigned short* yg16  = dtb16;
    float* Bc   = big + 26476544;                        // 524288
    float* Cc   = big + 27000832;                        // 524288
    float* outb = big + 27525120;                        // fp32 4.19M
    float* out2 = big + 31719424;                        // fp32 4.19M
    unsigned short* g16   = (unsigned short*)(big + 35913728);  // 8.39M sh

    // CSR scratch lives in the h1p region (dead until the h1 GEMM writes it)
    int* ideg   = (int*)h1p;              // 32768
    int* ibase  = ideg + 32768;           // 32769
    int* icur   = ideg + 65552;           // 32768 (16B-aligned)
    int* isrcs  = ideg + 98320;           // 524288

    hipMemsetAsync(st, 0, 2048 * sizeof(float), stream);
    hipMemsetAsync(ideg, 0, 32768 * sizeof(int), stream);

    // ---- weight prep: 5 bf16 transposes in ONE launch ----
    k_prepw5<<<552, 256, 0, stream>>>(W_rel, WrelT, W_root, WrootT,
                                      in_W, inWT, xproj_W, xprojT,
                                      out_W, outWT);

    // ---- CSR build + gather ----
    k_hist<<<512, 256, 0, stream>>>(ei, ideg);
    k_scanidx<<<1, 1024, 0, stream>>>(ideg, ibase, icur);
    k_fill<<<512, 256, 0, stream>>>(ei, icur, isrcs);
    k_gather<<<8192, 256, 0, stream>>>(x, ibase, isrcs, agg);

    // h1_pre = agg@W_rel + b_rel + x@W_root + x  [S1]  (fp32 out)
    gemm_mfma<true, 0, true, false, false><<<dim3(512, 2), 256, 0, stream>>>(
        agg, WrelT, x, WrootT, NROWS, 128, 128, 128,
        b_rel, x, 128, h1p, st + 0, st + 128);
    // xz = x @ in_W  (bf16 out)
    gemm_mfma<false, 0, false, false, true><<<dim3(512, 8), 256, 0, stream>>>(
        x, inWT, nullptr, nullptr, NROWS, 512, 128, 512,
        nullptr, nullptr, 0, xz16, nullptr, nullptr);
    k_conv<<<32768, 256, 0, stream>>>(xz16, conv_w, conv_b, xc16);
    // proj = xc @ xproj_W (bf16 A, fp32 out, N=40)
    gemm_mfma<false, 0, false, true, false><<<dim3(512, 1), 256, 0, stream>>>(
        xc16, xprojT, nullptr, nullptr, NROWS, 40, 256, 40,
        nullptr, nullptr, 0, proj, nullptr, nullptr);
    k_dtbc<<<1024, 256, 0, stream>>>(proj, dt_W, dt_b, dtb16, Bc, Cc);
    k_scan<<<512, 256, 0, stream>>>(dtb16, xc16, xz16, Bc, Cc, A_log, Dp, yg16);
    // p2 = yg @ out_W + x  [S2]  (bf16 A, fp32 out)
    gemm_mfma<false, 0, true, true, false><<<dim3(512, 2), 256, 0, stream>>>(
        yg16, outWT, nullptr, nullptr, NROWS, 128, 256, 128,
        nullptr, x, 128, p2, st + 256, st + 384);
    // out = BN1(h1_pre) + BN2(p2)  [S3]  (BN params computed in-kernel)
    k_add<<<512, 256, 0, stream>>>(h1p, p2, st, n1_g, n1_b, n2_g, n2_b,
                                   outb, st + 512, st + 640);
    k_fold1<<<256, 128, 0, stream>>>(st + 512, st + 640, m1_g, m1_b, W1, b1, W1eT, b1e);
    // g = gelu(out @ W1e + b1e)  [S4]  (bf16 out)
    gemm_mfma<false, 1, true, false, true><<<dim3(512, 4), 256, 0, stream>>>(
        outb, W1eT, nullptr, nullptr, NROWS, 256, 128, 256,
        b1e, nullptr, 0, g16, st + 768, st + 1024);
    k_fold2<<<128, 256, 0, stream>>>(st + 768, st + 1024, m2_g, m2_b, W2, b2, W2eT, b2e);
    // out2 = g @ W2e + b2e + out  [S5]  (bf16 A, fp32 out)
    gemm_mfma<false, 0, true, true, false><<<dim3(512, 2), 256, 0, stream>>>(
        g16, W2eT, nullptr, nullptr, NROWS, 128, 256, 128,
        b2e, outb, 128, out2, st + 1280, st + 1408);
    // d_out = BN3(out2)  (params computed in-kernel from S5)
    k_bn3<<<256, 256, 0, stream>>>(out2, st + 1280, st + 1408, n3_g, n3_b,
                                   (float*)d_out);
}